// Round 1
// baseline (5792.445 us; speedup 1.0000x reference)
//
#include <hip/hip_runtime.h>
#include <math.h>

// Problem dims
#define B_    64
#define LQ    512
#define LC    513          // with CLS
#define DD    512
#define HH    4
#define DH    128
#define DRr   128
#define NKEYS 10000
#define PP    96
#define TOPK  5
#define MROWS (B_*LC)      // 32832

static __device__ __forceinline__ float gelu_exact(float x) {
    return 0.5f * x * (1.0f + erff(x * 0.70710678118654752440f));
}

// ---------------- concat cls + query -> h ----------------
__global__ __launch_bounds__(128)
void concat_cls(const float* __restrict__ query, const float* __restrict__ cls,
                float* __restrict__ h)
{
    int row = blockIdx.x;
    int t = threadIdx.x;
    int b = row / LC, r = row - b * LC;
    const float* src = (r == 0) ? cls : (query + ((size_t)b * LQ + (r - 1)) * DD);
    *(float4*)(h + (size_t)row * DD + t * 4) = *(const float4*)(src + t * 4);
}

// ---------------- SGEMM: C[M,N] = A[M,K] @ W[N,K]^T + bias (+res) (+gelu) ----
#define GT 128
#define GK 16
__global__ __launch_bounds__(256)
void sgemm(const float* __restrict__ A, const float* __restrict__ W,
           const float* __restrict__ bias, const float* __restrict__ res,
           float* __restrict__ C, int M, int N, int K, int act)
{
    __shared__ float As[GK][GT + 4];
    __shared__ float Bs[GK][GT + 4];
    const int t = threadIdx.x;
    const int bm = blockIdx.x, bn = blockIdx.y;
    const int row0 = bm * GT, col0 = bn * GT;
    const int tm8 = (t >> 4) * 8, tn8 = (t & 15) * 8;
    const int lr = t >> 1;             // 0..127
    const int lk = (t & 1) * 8;        // 0 or 8

    float acc[8][8];
    #pragma unroll
    for (int i = 0; i < 8; i++)
        #pragma unroll
        for (int j = 0; j < 8; j++) acc[i][j] = 0.f;

    const bool arow_ok = (row0 + lr) < M;
    const float* Arow = A + (size_t)(arow_ok ? (row0 + lr) : (M - 1)) * K;
    const float* Wrow = W + (size_t)(col0 + lr) * K;

    for (int k0 = 0; k0 < K; k0 += GK) {
        float4 a0 = make_float4(0.f, 0.f, 0.f, 0.f), a1 = a0;
        if (arow_ok) {
            a0 = *(const float4*)(Arow + k0 + lk);
            a1 = *(const float4*)(Arow + k0 + lk + 4);
        }
        float4 b0 = *(const float4*)(Wrow + k0 + lk);
        float4 b1 = *(const float4*)(Wrow + k0 + lk + 4);
        float av[8] = {a0.x,a0.y,a0.z,a0.w,a1.x,a1.y,a1.z,a1.w};
        float bv[8] = {b0.x,b0.y,b0.z,b0.w,b1.x,b1.y,b1.z,b1.w};
        __syncthreads();
        #pragma unroll
        for (int j = 0; j < 8; j++) { As[lk + j][lr] = av[j]; Bs[lk + j][lr] = bv[j]; }
        __syncthreads();
        #pragma unroll
        for (int k = 0; k < GK; k++) {
            float4 x0 = *(const float4*)&As[k][tm8];
            float4 x1 = *(const float4*)&As[k][tm8 + 4];
            float4 y0 = *(const float4*)&Bs[k][tn8];
            float4 y1 = *(const float4*)&Bs[k][tn8 + 4];
            float xa[8] = {x0.x,x0.y,x0.z,x0.w,x1.x,x1.y,x1.z,x1.w};
            float yb[8] = {y0.x,y0.y,y0.z,y0.w,y1.x,y1.y,y1.z,y1.w};
            #pragma unroll
            for (int i = 0; i < 8; i++)
                #pragma unroll
                for (int j = 0; j < 8; j++)
                    acc[i][j] += xa[i] * yb[j];
        }
    }

    #pragma unroll
    for (int i = 0; i < 8; i++) {
        int r = row0 + tm8 + i;
        if (r >= M) break;
        float* crow = C + (size_t)r * N;
        #pragma unroll
        for (int jj = 0; jj < 8; jj += 4) {
            int c = col0 + tn8 + jj;
            float4 v;
            v.x = acc[i][jj + 0] + bias[c + 0];
            v.y = acc[i][jj + 1] + bias[c + 1];
            v.z = acc[i][jj + 2] + bias[c + 2];
            v.w = acc[i][jj + 3] + bias[c + 3];
            if (res) {
                float4 rv = *(const float4*)(res + (size_t)r * N + c);
                v.x += rv.x; v.y += rv.y; v.z += rv.z; v.w += rv.w;
            }
            if (act == 1) {
                v.x = gelu_exact(v.x); v.y = gelu_exact(v.y);
                v.z = gelu_exact(v.z); v.w = gelu_exact(v.w);
            }
            *(float4*)(crow + c) = v;
        }
    }
}

// ---------------- flash attention (fp32) ----------------
// qkv: [B*LC][1536] = [q(512)|k(512)|v(512)], head h at col h*128 in each
#define AQ 64
#define AK 32
#define NKT 17   // ceil(513/32)
__global__ __launch_bounds__(256)
void attn(const float* __restrict__ qkv, float* __restrict__ outp)
{
    __shared__ float qT[128][AQ + 4];   // [d][r]
    __shared__ float kT[128][AK + 4];   // [d][j]
    __shared__ float vS[AK][128 + 4];   // [j][d]
    __shared__ float pT[AK][AQ + 4];    // [j][r]
    __shared__ float row_m[AQ], row_l[AQ], row_alpha[AQ];

    const int t = threadIdx.x;
    const int qt = blockIdx.x, h = blockIdx.y, b = blockIdx.z;
    const int q0 = qt * AQ;
    const float SCALE = 0.08838834764831845f; // 1/sqrt(128)

    // load Q tile (zero-pad OOB rows)
    #pragma unroll
    for (int i = 0; i < 8; i++) {
        int idx = t + i * 256;
        int r = idx >> 5;
        int d = (idx & 31) * 4;
        float4 v = make_float4(0.f, 0.f, 0.f, 0.f);
        int qr = q0 + r;
        if (qr < LC) v = *(const float4*)(qkv + ((size_t)(b * LC + qr)) * 1536 + h * DH + d);
        qT[d + 0][r] = v.x; qT[d + 1][r] = v.y; qT[d + 2][r] = v.z; qT[d + 3][r] = v.w;
    }
    if (t < AQ) { row_m[t] = -INFINITY; row_l[t] = 0.f; }

    const int sr4 = (t >> 4) * 4;   // S rows / O rows
    const int sc  = (t & 15);
    const int sc2 = sc * 2;         // S cols
    const int oc8 = sc * 8;         // O cols
    float o[4][8];
    #pragma unroll
    for (int i = 0; i < 4; i++)
        #pragma unroll
        for (int c = 0; c < 8; c++) o[i][c] = 0.f;

    for (int kt = 0; kt < NKT; kt++) {
        __syncthreads();  // protect kT/vS/pT from previous iteration's readers
        #pragma unroll
        for (int i = 0; i < 4; i++) {
            int idx = t + i * 256;
            int j = idx >> 5;
            int d = (idx & 31) * 4;
            int kr = kt * AK + j;
            float4 kv = make_float4(0.f, 0.f, 0.f, 0.f), vv = kv;
            if (kr < LC) {
                const float* base = qkv + ((size_t)(b * LC + kr)) * 1536 + h * DH + d;
                kv = *(const float4*)(base + 512);
                vv = *(const float4*)(base + 1024);
            }
            kT[d + 0][j] = kv.x; kT[d + 1][j] = kv.y; kT[d + 2][j] = kv.z; kT[d + 3][j] = kv.w;
            *(float4*)&vS[j][d] = vv;
        }
        __syncthreads();

        // S = Q K^T (4 rows x 2 cols per thread)
        float s[4][2];
        #pragma unroll
        for (int i = 0; i < 4; i++) { s[i][0] = 0.f; s[i][1] = 0.f; }
        #pragma unroll 4
        for (int d = 0; d < DH; d++) {
            float4 a = *(const float4*)&qT[d][sr4];
            float2 kk = *(const float2*)&kT[d][sc2];
            s[0][0] += a.x * kk.x; s[0][1] += a.x * kk.y;
            s[1][0] += a.y * kk.x; s[1][1] += a.y * kk.y;
            s[2][0] += a.z * kk.x; s[2][1] += a.z * kk.y;
            s[3][0] += a.w * kk.x; s[3][1] += a.w * kk.y;
        }
        int k0 = kt * AK;
        #pragma unroll
        for (int i = 0; i < 4; i++)
            #pragma unroll
            for (int j = 0; j < 2; j++) {
                float sv = s[i][j] * SCALE;
                if (k0 + sc2 + j >= LC) sv = -INFINITY;
                s[i][j] = sv;
            }

        // online softmax (reduce across the 16 threads sharing a row)
        float al[4], mnew[4], lnew[4];
        #pragma unroll
        for (int i = 0; i < 4; i++) {
            float rm = fmaxf(s[i][0], s[i][1]);
            #pragma unroll
            for (int off = 1; off < 16; off <<= 1) rm = fmaxf(rm, __shfl_xor(rm, off));
            float mo = row_m[sr4 + i];
            float mn = fmaxf(mo, rm);
            s[i][0] = expf(s[i][0] - mn);
            s[i][1] = expf(s[i][1] - mn);
            float ts = s[i][0] + s[i][1];
            #pragma unroll
            for (int off = 1; off < 16; off <<= 1) ts += __shfl_xor(ts, off);
            al[i] = expf(mo - mn);
            lnew[i] = al[i] * row_l[sr4 + i] + ts;
            mnew[i] = mn;
        }
        if (sc == 0) {
            #pragma unroll
            for (int i = 0; i < 4; i++) {
                row_m[sr4 + i] = mnew[i]; row_l[sr4 + i] = lnew[i]; row_alpha[sr4 + i] = al[i];
            }
        }
        #pragma unroll
        for (int i = 0; i < 4; i++) { pT[sc2 + 0][sr4 + i] = s[i][0]; pT[sc2 + 1][sr4 + i] = s[i][1]; }
        __syncthreads();

        // O accumulate: O = alpha*O + P V
        #pragma unroll
        for (int i = 0; i < 4; i++) {
            float a = row_alpha[sr4 + i];
            #pragma unroll
            for (int c = 0; c < 8; c++) o[i][c] *= a;
        }
        for (int j = 0; j < AK; j++) {
            float4 pa = *(const float4*)&pT[j][sr4];
            float4 v0 = *(const float4*)&vS[j][oc8];
            float4 v1 = *(const float4*)&vS[j][oc8 + 4];
            float pav[4] = {pa.x, pa.y, pa.z, pa.w};
            float vv[8] = {v0.x,v0.y,v0.z,v0.w,v1.x,v1.y,v1.z,v1.w};
            #pragma unroll
            for (int i = 0; i < 4; i++)
                #pragma unroll
                for (int c = 0; c < 8; c++)
                    o[i][c] += pav[i] * vv[c];
        }
    }

    // normalize + store
    #pragma unroll
    for (int i = 0; i < 4; i++) {
        int qr = q0 + sr4 + i;
        if (qr >= LC) continue;
        float inv = 1.0f / row_l[sr4 + i];
        float* dst = outp + ((size_t)(b * LC + qr)) * DD + h * DH + oc8;
        float4 r0, r1;
        r0.x = o[i][0] * inv; r0.y = o[i][1] * inv; r0.z = o[i][2] * inv; r0.w = o[i][3] * inv;
        r1.x = o[i][4] * inv; r1.y = o[i][5] * inv; r1.z = o[i][6] * inv; r1.w = o[i][7] * inv;
        *(float4*)dst = r0;
        *(float4*)(dst + 4) = r1;
    }
}

// ---------------- LayerNorm over 512 ----------------
__global__ __launch_bounds__(128)
void ln512(const float* __restrict__ X, const float* __restrict__ g,
           const float* __restrict__ bb, float* __restrict__ Y)
{
    __shared__ float red[2];
    int row = blockIdx.x, t = threadIdx.x;
    const float* x = X + (size_t)row * DD;
    float4 v = *(const float4*)(x + t * 4);
    float s = v.x + v.y + v.z + v.w;
    #pragma unroll
    for (int off = 1; off < 64; off <<= 1) s += __shfl_xor(s, off);
    if ((t & 63) == 0) red[t >> 6] = s;
    __syncthreads();
    float mean = (red[0] + red[1]) * (1.0f / 512.0f);
    __syncthreads();
    float d0 = v.x - mean, d1 = v.y - mean, d2 = v.z - mean, d3 = v.w - mean;
    float s2 = d0 * d0 + d1 * d1 + d2 * d2 + d3 * d3;
    #pragma unroll
    for (int off = 1; off < 64; off <<= 1) s2 += __shfl_xor(s2, off);
    if ((t & 63) == 0) red[t >> 6] = s2;
    __syncthreads();
    float var = (red[0] + red[1]) * (1.0f / 512.0f);
    float rstd = 1.0f / sqrtf(var + 1e-5f);
    float4 gv = *(const float4*)(g + t * 4);
    float4 bv = *(const float4*)(bb + t * 4);
    float4 ov;
    ov.x = d0 * rstd * gv.x + bv.x;
    ov.y = d1 * rstd * gv.y + bv.y;
    ov.z = d2 * rstd * gv.z + bv.z;
    ov.w = d3 * rstd * gv.w + bv.w;
    *(float4*)(Y + (size_t)row * DD + t * 4) = ov;
}

// ---------------- mean over L ----------------
__global__ __launch_bounds__(128)
void mean_l(const float* __restrict__ query, float* __restrict__ xm)
{
    int b = blockIdx.x, t = threadIdx.x;
    const float* base = query + (size_t)b * LQ * DD + t * 4;
    float ax = 0.f, ay = 0.f, az = 0.f, aw = 0.f;
    for (int l = 0; l < LQ; l++) {
        float4 v = *(const float4*)(base + (size_t)l * DD);
        ax += v.x; ay += v.y; az += v.z; aw += v.w;
    }
    float4 o = make_float4(ax * (1.f/512.f), ay * (1.f/512.f), az * (1.f/512.f), aw * (1.f/512.f));
    *(float4*)(xm + (size_t)b * DD + t * 4) = o;
}

static __device__ __forceinline__ float block128_sum(float x, float* red, int t) {
    #pragma unroll
    for (int off = 1; off < 64; off <<= 1) x += __shfl_xor(x, off);
    if ((t & 63) == 0) red[t >> 6] = x;
    __syncthreads();
    float r = red[0] + red[1];
    __syncthreads();
    return r;
}

// ---------------- proj + LN -> q_repr ----------------
__global__ __launch_bounds__(128)
void proj_ln(const float* __restrict__ h, const float* __restrict__ pW, const float* __restrict__ pb,
             const float* __restrict__ pg, const float* __restrict__ pbb, float* __restrict__ q_repr)
{
    __shared__ float xs[DD];
    __shared__ float red[2];
    int b = blockIdx.x, t = threadIdx.x;
    *(float4*)&xs[t * 4] = *(const float4*)(h + (size_t)(b * LC) * DD + t * 4);
    __syncthreads();
    const float* w = pW + (size_t)t * DD;
    float acc = pb[t];
    for (int k = 0; k < DD; k += 4) {
        float4 a = *(const float4*)&xs[k];
        float4 ww = *(const float4*)(w + k);
        acc += a.x * ww.x + a.y * ww.y + a.z * ww.z + a.w * ww.w;
    }
    float mean = block128_sum(acc, red, t) * (1.f / 128.f);
    float dx = acc - mean;
    float var = block128_sum(dx * dx, red, t) * (1.f / 128.f);
    float rstd = 1.0f / sqrtf(var + 1e-5f);
    q_repr[(size_t)b * DRr + t] = dx * rstd * pg[t] + pbb[t];
}

// ---------------- value encoder (fused) -> q_val ----------------
__global__ __launch_bounds__(128)
void venc(const float* __restrict__ xm, const float* __restrict__ vW1, const float* __restrict__ vb1,
          const float* __restrict__ vg, const float* __restrict__ vb,
          const float* __restrict__ vW2, const float* __restrict__ vb2,
          float* __restrict__ q_val)
{
    __shared__ float xs[DD];
    __shared__ float hg[DRr];
    __shared__ float red[2];
    int b = blockIdx.x, t = threadIdx.x;
    *(float4*)&xs[t * 4] = *(const float4*)(xm + (size_t)b * DD + t * 4);
    __syncthreads();
    const float* w = vW1 + (size_t)t * DD;
    float acc = vb1[t];
    for (int k = 0; k < DD; k += 4) {
        float4 a = *(const float4*)&xs[k];
        float4 ww = *(const float4*)(w + k);
        acc += a.x * ww.x + a.y * ww.y + a.z * ww.z + a.w * ww.w;
    }
    float mean = block128_sum(acc, red, t) * (1.f / 128.f);
    float dx = acc - mean;
    float var = block128_sum(dx * dx, red, t) * (1.f / 128.f);
    float rstd = 1.0f / sqrtf(var + 1e-5f);
    float hn = dx * rstd * vg[t] + vb[t];
    hg[t] = gelu_exact(hn);
    __syncthreads();
    const float* w2 = vW2 + (size_t)t * DRr;
    float acc2 = vb2[t];
    for (int k = 0; k < DRr; k += 4) {
        float4 a = *(const float4*)&hg[k];
        float4 ww = *(const float4*)(w2 + k);
        acc2 += a.x * ww.x + a.y * ww.y + a.z * ww.z + a.w * ww.w;
    }
    q_val[(size_t)b * DRr + t] = acc2;
}

// ---------------- combine ----------------
__global__ void combine_qk(const float* __restrict__ qr, const float* __restrict__ qv,
                           const float* __restrict__ swp, float* __restrict__ qk)
{
    int i = blockIdx.x * blockDim.x + threadIdx.x;
    if (i < B_ * DRr) {
        float sw = swp[0];
        qk[i] = sw * qr[i] + (1.f - sw) * qv[i];
    }
}

// ---------------- sim ----------------
__global__ __launch_bounds__(256)
void sim_kernel(const float* __restrict__ qk, const float* __restrict__ mkeys, float* __restrict__ sim)
{
    __shared__ float qs[DRr];
    int b = blockIdx.x, t = threadIdx.x;
    if (t < DRr) qs[t] = qk[(size_t)b * DRr + t];
    __syncthreads();
    float qn = 0.f;
    #pragma unroll 8
    for (int i = 0; i < DRr; i++) qn += qs[i] * qs[i];
    for (int n = t; n < NKEYS; n += 256) {
        const float* kr = mkeys + (size_t)n * DRr;
        float dot = 0.f, kn = 0.f;
        #pragma unroll 8
        for (int i = 0; i < DRr; i += 4) {
            float4 kv = *(const float4*)(kr + i);
            dot += qs[i] * kv.x + qs[i + 1] * kv.y + qs[i + 2] * kv.z + qs[i + 3] * kv.w;
            kn  += kv.x * kv.x + kv.y * kv.y + kv.z * kv.z + kv.w * kv.w;
        }
        float d = qn - 2.f * dot + kn;
        sim[(size_t)b * NKEYS + n] = -d / 0.1f;
    }
}

// ---------------- top-k (jax semantics: value desc, ties -> lower index) ----
static __device__ __forceinline__ void topk_insert(float* v, int* id, float x, int n) {
    bool better = (x > v[TOPK - 1]) || (x == v[TOPK - 1] && n < id[TOPK - 1]);
    if (better) {
        v[TOPK - 1] = x; id[TOPK - 1] = n;
        #pragma unroll
        for (int k = TOPK - 1; k > 0; k--) {
            bool sw = (v[k] > v[k - 1]) || (v[k] == v[k - 1] && id[k] < id[k - 1]);
            if (!sw) break;
            float tv = v[k]; v[k] = v[k - 1]; v[k - 1] = tv;
            int ti = id[k]; id[k] = id[k - 1]; id[k - 1] = ti;
        }
    }
}

__global__ __launch_bounds__(256)
void topk_kernel(const float* __restrict__ sim, int* __restrict__ topidx, float* __restrict__ wout)
{
    __shared__ float sv[256][TOPK];
    __shared__ int   si[256][TOPK];
    int b = blockIdx.x, t = threadIdx.x;
    float v[TOPK]; int id[TOPK];
    #pragma unroll
    for (int k = 0; k < TOPK; k++) { v[k] = -INFINITY; id[k] = 0x7fffffff; }
    for (int n = t; n < NKEYS; n += 256) {
        topk_insert(v, id, sim[(size_t)b * NKEYS + n], n);
    }
    #pragma unroll
    for (int k = 0; k < TOPK; k++) { sv[t][k] = v[k]; si[t][k] = id[k]; }
    for (int strd = 128; strd >= 1; strd >>= 1) {
        __syncthreads();
        if (t < strd) {
            #pragma unroll
            for (int k = 0; k < TOPK; k++) topk_insert(v, id, sv[t + strd][k], si[t + strd][k]);
            #pragma unroll
            for (int k = 0; k < TOPK; k++) { sv[t][k] = v[k]; si[t][k] = id[k]; }
        }
    }
    if (t == 0) {
        float m = v[0];
        float e[TOPK]; float sum = 0.f;
        #pragma unroll
        for (int k = 0; k < TOPK; k++) { e[k] = expf(v[k] - m); sum += e[k]; }
        #pragma unroll
        for (int k = 0; k < TOPK; k++) {
            wout[(size_t)b * TOPK + k] = e[k] / sum;
            topidx[b * TOPK + k] = id[k];
        }
    }
}

// ---------------- gather ----------------
__global__ __launch_bounds__(128)
void gather_kernel(const float* __restrict__ mv, const int* __restrict__ topidx, float* __restrict__ out)
{
    int blk = blockIdx.x;                 // b*480 + k*96 + p
    int b = blk / (TOPK * PP);
    int rem = blk - b * (TOPK * PP);
    int k = rem / PP;
    int p = rem - k * PP;
    int idx = topidx[b * TOPK + k];
    const float4* src = (const float4*)(mv + ((size_t)idx * PP + p) * DD);
    float4* dst = (float4*)(out + (size_t)blk * DD);
    dst[threadIdx.x] = src[threadIdx.x];
}

// ---------------- launch ----------------
extern "C" void kernel_launch(void* const* d_in, const int* in_sizes, int n_in,
                              void* d_out, int out_size, void* d_ws, size_t ws_size,
                              hipStream_t stream) {
    const float* query = (const float*)d_in[0];
    const float* mkeys = (const float*)d_in[1];
    const float* mvals = (const float*)d_in[2];
    const float* cls   = (const float*)d_in[3];
    const float* Wqkv  = (const float*)d_in[4];
    const float* bqkv  = (const float*)d_in[5];
    const float* Wo    = (const float*)d_in[6];
    const float* bo    = (const float*)d_in[7];
    const float* ln1g  = (const float*)d_in[8];
    const float* ln1b  = (const float*)d_in[9];
    const float* W1    = (const float*)d_in[10];
    const float* b1    = (const float*)d_in[11];
    const float* W2    = (const float*)d_in[12];
    const float* b2    = (const float*)d_in[13];
    const float* ln2g  = (const float*)d_in[14];
    const float* ln2b  = (const float*)d_in[15];
    const float* pW    = (const float*)d_in[16];
    const float* pb    = (const float*)d_in[17];
    const float* pg    = (const float*)d_in[18];
    const float* pbb   = (const float*)d_in[19];
    const float* vW1   = (const float*)d_in[20];
    const float* vb1   = (const float*)d_in[21];
    const float* vg    = (const float*)d_in[22];
    const float* vb    = (const float*)d_in[23];
    const float* vW2   = (const float*)d_in[24];
    const float* vb2   = (const float*)d_in[25];
    const float* swp   = (const float*)d_in[26];
    float* out = (float*)d_out;

    // workspace layout (floats). Total ~339 MB.
    float* ws   = (float*)d_ws;
    float* h    = ws;                        // 16,822,272
    float* big  = h    + (size_t)MROWS * DD; // 50,429,952 (qkv / ffn-mid)
    float* cbuf = big  + (size_t)MROWS * 1536; // 16,809,984
    float* xm   = cbuf + (size_t)MROWS * DD; // 32,768
    float* qval = xm   + (size_t)B_ * DD;    // 8,192
    float* qrep = qval + (size_t)B_ * DRr;   // 8,192
    float* qkv_ = qrep + (size_t)B_ * DRr;   // 8,192 (combined qk)
    float* simb = qkv_ + (size_t)B_ * DRr;   // 640,000
    int*   tidx = (int*)(simb + (size_t)B_ * NKEYS); // 320 ints
    (void)ws_size; (void)in_sizes; (void)n_in; (void)out_size;

    concat_cls<<<MROWS, 128, 0, stream>>>(query, cls, h);

    for (int l = 0; l < 2; l++) {
        const float* Wq  = Wqkv + (size_t)l * 1536 * DD;
        const float* bq  = bqkv + (size_t)l * 1536;
        const float* Wol = Wo   + (size_t)l * DD * DD;
        const float* bol = bo   + (size_t)l * DD;
        const float* g1  = ln1g + (size_t)l * DD;
        const float* be1 = ln1b + (size_t)l * DD;
        const float* W1l = W1   + (size_t)l * 1024 * DD;
        const float* b1l = b1   + (size_t)l * 1024;
        const float* W2l = W2   + (size_t)l * DD * 1024;
        const float* b2l = b2   + (size_t)l * DD;
        const float* g2  = ln2g + (size_t)l * DD;
        const float* be2 = ln2b + (size_t)l * DD;

        sgemm<<<dim3(257, 12), 256, 0, stream>>>(h, Wq, bq, nullptr, big, MROWS, 1536, 512, 0);
        attn<<<dim3(9, 4, 64), 256, 0, stream>>>(big, cbuf);
        sgemm<<<dim3(257, 4), 256, 0, stream>>>(cbuf, Wol, bol, h, big, MROWS, 512, 512, 0);
        ln512<<<MROWS, 128, 0, stream>>>(big, g1, be1, h);
        sgemm<<<dim3(257, 8), 256, 0, stream>>>(h, W1l, b1l, nullptr, big, MROWS, 1024, 512, 1);
        sgemm<<<dim3(257, 4), 256, 0, stream>>>(big, W2l, b2l, h, cbuf, MROWS, 512, 1024, 0);
        ln512<<<MROWS, 128, 0, stream>>>(cbuf, g2, be2, h);
    }

    proj_ln<<<B_, 128, 0, stream>>>(h, pW, pb, pg, pbb, qrep);
    mean_l<<<B_, 128, 0, stream>>>(query, xm);
    venc<<<B_, 128, 0, stream>>>(xm, vW1, vb1, vg, vb, vW2, vb2, qval);
    combine_qk<<<(B_ * DRr + 255) / 256, 256, 0, stream>>>(qrep, qval, swp, qkv_);
    sim_kernel<<<B_, 256, 0, stream>>>(qkv_, mkeys, simb);
    topk_kernel<<<B_, 256, 0, stream>>>(simb, tidx, out + (size_t)B_ * TOPK * PP * DD);
    gather_kernel<<<B_ * TOPK * PP, 128, 0, stream>>>(mvals, tidx, out);
}

// Round 2
// 3717.741 us; speedup vs baseline: 1.5581x; 1.5581x over previous
//
#include <hip/hip_runtime.h>
#include <math.h>

// Problem dims
#define B_    64
#define LQ    512
#define LC    513          // with CLS
#define DD    512
#define HH    4
#define DH    128
#define DRr   128
#define NKEYS 10000
#define PP    96
#define TOPK  5
#define MROWS (B_*LC)      // 32832

typedef __attribute__((ext_vector_type(8))) short short8v;
typedef __attribute__((ext_vector_type(4))) float f32x4;

static __device__ __forceinline__ float gelu_exact(float x) {
    return 0.5f * x * (1.0f + erff(x * 0.70710678118654752440f));
}

static __device__ __forceinline__ unsigned short f2bf(float x) {
    union { float f; unsigned u; } v; v.f = x;
    unsigned r = v.u + 0x7fff + ((v.u >> 16) & 1);
    return (unsigned short)(r >> 16);
}
static __device__ __forceinline__ float bf2f(unsigned short h) {
    union { float f; unsigned u; } v; v.u = ((unsigned)h) << 16;
    return v.f;
}
static __device__ __forceinline__ void split_bf(float x, unsigned short& hi, unsigned short& lo) {
    hi = f2bf(x);
    lo = f2bf(x - bf2f(hi));
}

// ---------------- generic fp32 -> (hi,lo) bf16 split ----------------
__global__ __launch_bounds__(256)
void split_kernel(const float* __restrict__ x, unsigned short* __restrict__ hi,
                  unsigned short* __restrict__ lo, int n4)
{
    int i = blockIdx.x * blockDim.x + threadIdx.x;
    if (i >= n4) return;
    float4 v = ((const float4*)x)[i];
    unsigned short h0,h1,h2,h3,l0,l1,l2,l3;
    split_bf(v.x,h0,l0); split_bf(v.y,h1,l1); split_bf(v.z,h2,l2); split_bf(v.w,h3,l3);
    unsigned hw0 = (unsigned)h0 | ((unsigned)h1 << 16);
    unsigned hw1 = (unsigned)h2 | ((unsigned)h3 << 16);
    unsigned lw0 = (unsigned)l0 | ((unsigned)l1 << 16);
    unsigned lw1 = (unsigned)l2 | ((unsigned)l3 << 16);
    ((uint2*)hi)[i] = make_uint2(hw0, hw1);
    ((uint2*)lo)[i] = make_uint2(lw0, lw1);
}

// ---------------- concat cls + query -> h (fp32 + splits) ----------------
__global__ __launch_bounds__(128)
void concat_cls(const float* __restrict__ query, const float* __restrict__ cls,
                float* __restrict__ h, unsigned short* __restrict__ h_hi,
                unsigned short* __restrict__ h_lo)
{
    int row = blockIdx.x;
    int t = threadIdx.x;
    int b = row / LC, r = row - b * LC;
    const float* src = (r == 0) ? cls : (query + ((size_t)b * LQ + (r - 1)) * DD);
    float4 v = *(const float4*)(src + t * 4);
    *(float4*)(h + (size_t)row * DD + t * 4) = v;
    unsigned short hs[4], ls[4];
    split_bf(v.x, hs[0], ls[0]); split_bf(v.y, hs[1], ls[1]);
    split_bf(v.z, hs[2], ls[2]); split_bf(v.w, hs[3], ls[3]);
    size_t o = (size_t)row * DD + t * 4;
    ((uint2*)(h_hi))[o >> 2] = make_uint2((unsigned)hs[0] | ((unsigned)hs[1]<<16),
                                          (unsigned)hs[2] | ((unsigned)hs[3]<<16));
    ((uint2*)(h_lo))[o >> 2] = make_uint2((unsigned)ls[0] | ((unsigned)ls[1]<<16),
                                          (unsigned)ls[2] | ((unsigned)ls[3]<<16));
}

// ---------------- split-bf16 MFMA GEMM: C = A @ W^T + bias (+res)(+gelu) ----
// A: [M][K] as hi/lo bf16, W: [N][K] as hi/lo bf16.
// MODE 0: C fp32 = acc + bias
// MODE 1: C fp32 = acc + bias + res
// MODE 2: (hi,lo) bf16 = gelu(acc + bias)
#define BM 128
#define BN 128
#define BK 32
#define LDST 40   // BK + 8 pad (keeps 16B alignment, breaks pow2 bank stride)

#define MFMA16(a, b, c) __builtin_amdgcn_mfma_f32_16x16x32_bf16(a, b, c, 0, 0, 0)

template<int MODE>
__global__ __launch_bounds__(256)
void gemm3(const unsigned short* __restrict__ Ahi, const unsigned short* __restrict__ Alo,
           const unsigned short* __restrict__ Whi, const unsigned short* __restrict__ Wlo,
           const float* __restrict__ bias, const float* __restrict__ res,
           float* __restrict__ Cf, unsigned short* __restrict__ Chi,
           unsigned short* __restrict__ Clo, int M, int N, int K)
{
    __shared__ __align__(16) unsigned short Ah[BM][LDST];
    __shared__ __align__(16) unsigned short Al[BM][LDST];
    __shared__ __align__(16) unsigned short Bh[BN][LDST];
    __shared__ __align__(16) unsigned short Bl[BN][LDST];

    const int t = threadIdx.x;
    const int lane = t & 63, w = t >> 6;
    const int wr = w >> 1, wc = w & 1;
    const int row0 = blockIdx.x * BM, col0 = blockIdx.y * BN;

    // staging: thread covers (row sr, 16 cols at sc)
    const int sr = t >> 1;
    const int sc = (t & 1) * 16;
    int agr = row0 + sr; if (agr >= M) agr = M - 1;
    const size_t aoff = (size_t)agr * K + sc;
    const size_t boff = (size_t)(col0 + sr) * K + sc;

    f32x4 acc[4][4];
    #pragma unroll
    for (int m = 0; m < 4; m++)
        #pragma unroll
        for (int n = 0; n < 4; n++) { acc[m][n][0]=0.f; acc[m][n][1]=0.f; acc[m][n][2]=0.f; acc[m][n][3]=0.f; }

    const int fr = lane & 15;
    const int fk = (lane >> 4) * 8;

    short8v sa_h[2], sa_l[2], sb_h[2], sb_l[2];
    {
        const short8v* p;
        p = (const short8v*)(Ahi + aoff); sa_h[0] = p[0]; sa_h[1] = p[1];
        p = (const short8v*)(Alo + aoff); sa_l[0] = p[0]; sa_l[1] = p[1];
        p = (const short8v*)(Whi + boff); sb_h[0] = p[0]; sb_h[1] = p[1];
        p = (const short8v*)(Wlo + boff); sb_l[0] = p[0]; sb_l[1] = p[1];
    }

    const int KT = K / BK;
    for (int kt = 0; kt < KT; kt++) {
        __syncthreads();
        *(short8v*)&Ah[sr][sc] = sa_h[0]; *(short8v*)&Ah[sr][sc + 8] = sa_h[1];
        *(short8v*)&Al[sr][sc] = sa_l[0]; *(short8v*)&Al[sr][sc + 8] = sa_l[1];
        *(short8v*)&Bh[sr][sc] = sb_h[0]; *(short8v*)&Bh[sr][sc + 8] = sb_h[1];
        *(short8v*)&Bl[sr][sc] = sb_l[0]; *(short8v*)&Bl[sr][sc + 8] = sb_l[1];
        __syncthreads();

        short8v ah[4], al[4], bh[4], bl[4];
        #pragma unroll
        for (int m = 0; m < 4; m++) {
            int r = wr * 64 + m * 16 + fr;
            ah[m] = *(const short8v*)&Ah[r][fk];
            al[m] = *(const short8v*)&Al[r][fk];
        }
        #pragma unroll
        for (int n = 0; n < 4; n++) {
            int c = wc * 64 + n * 16 + fr;
            bh[n] = *(const short8v*)&Bh[c][fk];
            bl[n] = *(const short8v*)&Bl[c][fk];
        }

        if (kt + 1 < KT) {
            int k0n = (kt + 1) * BK;
            const short8v* p;
            p = (const short8v*)(Ahi + aoff + k0n); sa_h[0] = p[0]; sa_h[1] = p[1];
            p = (const short8v*)(Alo + aoff + k0n); sa_l[0] = p[0]; sa_l[1] = p[1];
            p = (const short8v*)(Whi + boff + k0n); sb_h[0] = p[0]; sb_h[1] = p[1];
            p = (const short8v*)(Wlo + boff + k0n); sb_l[0] = p[0]; sb_l[1] = p[1];
        }

        #pragma unroll
        for (int m = 0; m < 4; m++)
            #pragma unroll
            for (int n = 0; n < 4; n++) {
                acc[m][n] = MFMA16(ah[m], bh[n], acc[m][n]);
                acc[m][n] = MFMA16(al[m], bh[n], acc[m][n]);
                acc[m][n] = MFMA16(ah[m], bl[n], acc[m][n]);
            }
    }

    // epilogue: C/D layout col=lane&15, row=(lane>>4)*4+reg
    #pragma unroll
    for (int m = 0; m < 4; m++) {
        int rb = row0 + wr * 64 + m * 16 + (lane >> 4) * 4;
        #pragma unroll
        for (int n = 0; n < 4; n++) {
            int c = col0 + wc * 64 + n * 16 + fr;
            float bcol = bias[c];
            #pragma unroll
            for (int r = 0; r < 4; r++) {
                int row = rb + r;
                if (row < M) {
                    float v = acc[m][n][r] + bcol;
                    if (MODE == 1) v += res[(size_t)row * N + c];
                    if (MODE == 2) {
                        v = gelu_exact(v);
                        unsigned short hv, lv;
                        split_bf(v, hv, lv);
                        Chi[(size_t)row * N + c] = hv;
                        Clo[(size_t)row * N + c] = lv;
                    } else {
                        Cf[(size_t)row * N + c] = v;
                    }
                }
            }
        }
    }
}

// ---------------- flash attention (fp32 in, split-bf16 out) ----------------
// qkv: [B*LC][1536] = [q(512)|k(512)|v(512)], head h at col h*128 in each
#define AQ 64
#define AK 32
#define NKT 17   // ceil(513/32)
__global__ __launch_bounds__(256)
void attn(const float* __restrict__ qkv, unsigned short* __restrict__ chi,
          unsigned short* __restrict__ clo)
{
    __shared__ float qT[128][AQ + 4];   // [d][r]
    __shared__ float kT[128][AK + 4];   // [d][j]
    __shared__ float vS[AK][128 + 4];   // [j][d]
    __shared__ float pT[AK][AQ + 4];    // [j][r]
    __shared__ float row_m[AQ], row_l[AQ], row_alpha[AQ];

    const int t = threadIdx.x;
    const int qt = blockIdx.x, h = blockIdx.y, b = blockIdx.z;
    const int q0 = qt * AQ;
    const float SCALE = 0.08838834764831845f; // 1/sqrt(128)

    #pragma unroll
    for (int i = 0; i < 8; i++) {
        int idx = t + i * 256;
        int r = idx >> 5;
        int d = (idx & 31) * 4;
        float4 v = make_float4(0.f, 0.f, 0.f, 0.f);
        int qr = q0 + r;
        if (qr < LC) v = *(const float4*)(qkv + ((size_t)(b * LC + qr)) * 1536 + h * DH + d);
        qT[d + 0][r] = v.x; qT[d + 1][r] = v.y; qT[d + 2][r] = v.z; qT[d + 3][r] = v.w;
    }
    if (t < AQ) { row_m[t] = -INFINITY; row_l[t] = 0.f; }

    const int sr4 = (t >> 4) * 4;
    const int sc  = (t & 15);
    const int sc2 = sc * 2;
    const int oc8 = sc * 8;
    float o[4][8];
    #pragma unroll
    for (int i = 0; i < 4; i++)
        #pragma unroll
        for (int c = 0; c < 8; c++) o[i][c] = 0.f;

    for (int kt = 0; kt < NKT; kt++) {
        __syncthreads();
        #pragma unroll
        for (int i = 0; i < 4; i++) {
            int idx = t + i * 256;
            int j = idx >> 5;
            int d = (idx & 31) * 4;
            int kr = kt * AK + j;
            float4 kv = make_float4(0.f, 0.f, 0.f, 0.f), vv = kv;
            if (kr < LC) {
                const float* base = qkv + ((size_t)(b * LC + kr)) * 1536 + h * DH + d;
                kv = *(const float4*)(base + 512);
                vv = *(const float4*)(base + 1024);
            }
            kT[d + 0][j] = kv.x; kT[d + 1][j] = kv.y; kT[d + 2][j] = kv.z; kT[d + 3][j] = kv.w;
            *(float4*)&vS[j][d] = vv;
        }
        __syncthreads();

        float s[4][2];
        #pragma unroll
        for (int i = 0; i < 4; i++) { s[i][0] = 0.f; s[i][1] = 0.f; }
        #pragma unroll 4
        for (int d = 0; d < DH; d++) {
            float4 a = *(const float4*)&qT[d][sr4];
            float2 kk = *(const float2*)&kT[d][sc2];
            s[0][0] += a.x * kk.x; s[0][1] += a.x * kk.y;
            s[1][0] += a.y * kk.x; s[1][1] += a.y * kk.y;
            s[2][0] += a.z * kk.x; s[2][1] += a.z * kk.y;
            s[3][0] += a.w * kk.x; s[3][1] += a.w * kk.y;
        }
        int k0 = kt * AK;
        #pragma unroll
        for (int i = 0; i < 4; i++)
            #pragma unroll
            for (int j = 0; j < 2; j++) {
                float sv = s[i][j] * SCALE;
                if (k0 + sc2 + j >= LC) sv = -INFINITY;
                s[i][j] = sv;
            }

        float al[4], mnew[4], lnew[4];
        #pragma unroll
        for (int i = 0; i < 4; i++) {
            float rm = fmaxf(s[i][0], s[i][1]);
            #pragma unroll
            for (int off = 1; off < 16; off <<= 1) rm = fmaxf(rm, __shfl_xor(rm, off));
            float mo = row_m[sr4 + i];
            float mn = fmaxf(mo, rm);
            s[i][0] = expf(s[i][0] - mn);
            s[i][1] = expf(s[i][1] - mn);
            float ts = s[i][0] + s[i][1];
            #pragma unroll
            for (int off = 1; off < 16; off <<= 1) ts += __shfl_xor(ts, off);
            al[i] = expf(mo - mn);
            lnew[i] = al[i] * row_l[sr4 + i] + ts;
            mnew[i] = mn;
        }
        if (sc == 0) {
            #pragma unroll
            for (int i = 0; i < 4; i++) {
                row_m[sr4 + i] = mnew[i]; row_l[sr4 + i] = lnew[i]; row_alpha[sr4 + i] = al[i];
            }
        }
        #pragma unroll
        for (int i = 0; i < 4; i++) { pT[sc2 + 0][sr4 + i] = s[i][0]; pT[sc2 + 1][sr4 + i] = s[i][1]; }
        __syncthreads();

        #pragma unroll
        for (int i = 0; i < 4; i++) {
            float a = row_alpha[sr4 + i];
            #pragma unroll
            for (int c = 0; c < 8; c++) o[i][c] *= a;
        }
        for (int j = 0; j < AK; j++) {
            float4 pa = *(const float4*)&pT[j][sr4];
            float4 v0 = *(const float4*)&vS[j][oc8];
            float4 v1 = *(const float4*)&vS[j][oc8 + 4];
            float pav[4] = {pa.x, pa.y, pa.z, pa.w};
            float vv[8] = {v0.x,v0.y,v0.z,v0.w,v1.x,v1.y,v1.z,v1.w};
            #pragma unroll
            for (int i = 0; i < 4; i++)
                #pragma unroll
                for (int c = 0; c < 8; c++)
                    o[i][c] += pav[i] * vv[c];
        }
    }

    // normalize + split-store
    #pragma unroll
    for (int i = 0; i < 4; i++) {
        int qr = q0 + sr4 + i;
        if (qr >= LC) continue;
        float inv = 1.0f / row_l[sr4 + i];
        size_t base = ((size_t)(b * LC + qr)) * DD + h * DH + oc8;
        unsigned short hs[8], ls[8];
        #pragma unroll
        for (int c = 0; c < 8; c++) {
            float v = o[i][c] * inv;
            split_bf(v, hs[c], ls[c]);
        }
        ((uint2*)chi)[base >> 2] = make_uint2((unsigned)hs[0] | ((unsigned)hs[1]<<16),
                                              (unsigned)hs[2] | ((unsigned)hs[3]<<16));
        ((uint2*)(chi))[(base >> 2) + 1] = make_uint2((unsigned)hs[4] | ((unsigned)hs[5]<<16),
                                                      (unsigned)hs[6] | ((unsigned)hs[7]<<16));
        ((uint2*)clo)[base >> 2] = make_uint2((unsigned)ls[0] | ((unsigned)ls[1]<<16),
                                              (unsigned)ls[2] | ((unsigned)ls[3]<<16));
        ((uint2*)(clo))[(base >> 2) + 1] = make_uint2((unsigned)ls[4] | ((unsigned)ls[5]<<16),
                                                      (unsigned)ls[6] | ((unsigned)ls[7]<<16));
    }
}

// ---------------- LayerNorm over 512, writes fp32 + splits ----------------
__global__ __launch_bounds__(128)
void ln512(const float* __restrict__ X, const float* __restrict__ g,
           const float* __restrict__ bb, float* __restrict__ Y,
           unsigned short* __restrict__ Yhi, unsigned short* __restrict__ Ylo)
{
    __shared__ float red[2];
    int row = blockIdx.x, t = threadIdx.x;
    const float* x = X + (size_t)row * DD;
    float4 v = *(const float4*)(x + t * 4);
    float s = v.x + v.y + v.z + v.w;
    #pragma unroll
    for (int off = 1; off < 64; off <<= 1) s += __shfl_xor(s, off);
    if ((t & 63) == 0) red[t >> 6] = s;
    __syncthreads();
    float mean = (red[0] + red[1]) * (1.0f / 512.0f);
    __syncthreads();
    float d0 = v.x - mean, d1 = v.y - mean, d2 = v.z - mean, d3 = v.w - mean;
    float s2 = d0 * d0 + d1 * d1 + d2 * d2 + d3 * d3;
    #pragma unroll
    for (int off = 1; off < 64; off <<= 1) s2 += __shfl_xor(s2, off);
    if ((t & 63) == 0) red[t >> 6] = s2;
    __syncthreads();
    float var = (red[0] + red[1]) * (1.0f / 512.0f);
    float rstd = 1.0f / sqrtf(var + 1e-5f);
    float4 gv = *(const float4*)(g + t * 4);
    float4 bv = *(const float4*)(bb + t * 4);
    float4 ov;
    ov.x = d0 * rstd * gv.x + bv.x;
    ov.y = d1 * rstd * gv.y + bv.y;
    ov.z = d2 * rstd * gv.z + bv.z;
    ov.w = d3 * rstd * gv.w + bv.w;
    size_t o = (size_t)row * DD + t * 4;
    *(float4*)(Y + o) = ov;
    unsigned short hs[4], ls[4];
    split_bf(ov.x, hs[0], ls[0]); split_bf(ov.y, hs[1], ls[1]);
    split_bf(ov.z, hs[2], ls[2]); split_bf(ov.w, hs[3], ls[3]);
    ((uint2*)Yhi)[o >> 2] = make_uint2((unsigned)hs[0] | ((unsigned)hs[1]<<16),
                                       (unsigned)hs[2] | ((unsigned)hs[3]<<16));
    ((uint2*)Ylo)[o >> 2] = make_uint2((unsigned)ls[0] | ((unsigned)ls[1]<<16),
                                       (unsigned)ls[2] | ((unsigned)ls[3]<<16));
}

// ---------------- mean over L ----------------
__global__ __launch_bounds__(128)
void mean_l(const float* __restrict__ query, float* __restrict__ xm)
{
    int b = blockIdx.x, t = threadIdx.x;
    const float* base = query + (size_t)b * LQ * DD + t * 4;
    float ax = 0.f, ay = 0.f, az = 0.f, aw = 0.f;
    for (int l = 0; l < LQ; l++) {
        float4 v = *(const float4*)(base + (size_t)l * DD);
        ax += v.x; ay += v.y; az += v.z; aw += v.w;
    }
    float4 o = make_float4(ax * (1.f/512.f), ay * (1.f/512.f), az * (1.f/512.f), aw * (1.f/512.f));
    *(float4*)(xm + (size_t)b * DD + t * 4) = o;
}

static __device__ __forceinline__ float block128_sum(float x, float* red, int t) {
    #pragma unroll
    for (int off = 1; off < 64; off <<= 1) x += __shfl_xor(x, off);
    if ((t & 63) == 0) red[t >> 6] = x;
    __syncthreads();
    float r = red[0] + red[1];
    __syncthreads();
    return r;
}

// ---------------- proj + LN -> q_repr ----------------
__global__ __launch_bounds__(128)
void proj_ln(const float* __restrict__ h, const float* __restrict__ pW, const float* __restrict__ pb,
             const float* __restrict__ pg, const float* __restrict__ pbb, float* __restrict__ q_repr)
{
    __shared__ float xs[DD];
    __shared__ float red[2];
    int b = blockIdx.x, t = threadIdx.x;
    *(float4*)&xs[t * 4] = *(const float4*)(h + (size_t)(b * LC) * DD + t * 4);
    __syncthreads();
    const float* w = pW + (size_t)t * DD;
    float acc = pb[t];
    for (int k = 0; k < DD; k += 4) {
        float4 a = *(const float4*)&xs[k];
        float4 ww = *(const float4*)(w + k);
        acc += a.x * ww.x + a.y * ww.y + a.z * ww.z + a.w * ww.w;
    }
    float mean = block128_sum(acc, red, t) * (1.f / 128.f);
    float dx = acc - mean;
    float var = block128_sum(dx * dx, red, t) * (1.f / 128.f);
    float rstd = 1.0f / sqrtf(var + 1e-5f);
    q_repr[(size_t)b * DRr + t] = dx * rstd * pg[t] + pbb[t];
}

// ---------------- value encoder (fused) -> q_val ----------------
__global__ __launch_bounds__(128)
void venc(const float* __restrict__ xm, const float* __restrict__ vW1, const float* __restrict__ vb1,
          const float* __restrict__ vg, const float* __restrict__ vb,
          const float* __restrict__ vW2, const float* __restrict__ vb2,
          float* __restrict__ q_val)
{
    __shared__ float xs[DD];
    __shared__ float hg[DRr];
    __shared__ float red[2];
    int b = blockIdx.x, t = threadIdx.x;
    *(float4*)&xs[t * 4] = *(const float4*)(xm + (size_t)b * DD + t * 4);
    __syncthreads();
    const float* w = vW1 + (size_t)t * DD;
    float acc = vb1[t];
    for (int k = 0; k < DD; k += 4) {
        float4 a = *(const float4*)&xs[k];
        float4 ww = *(const float4*)(w + k);
        acc += a.x * ww.x + a.y * ww.y + a.z * ww.z + a.w * ww.w;
    }
    float mean = block128_sum(acc, red, t) * (1.f / 128.f);
    float dx = acc - mean;
    float var = block128_sum(dx * dx, red, t) * (1.f / 128.f);
    float rstd = 1.0f / sqrtf(var + 1e-5f);
    float hn = dx * rstd * vg[t] + vb[t];
    hg[t] = gelu_exact(hn);
    __syncthreads();
    const float* w2 = vW2 + (size_t)t * DRr;
    float acc2 = vb2[t];
    for (int k = 0; k < DRr; k += 4) {
        float4 a = *(const float4*)&hg[k];
        float4 ww = *(const float4*)(w2 + k);
        acc2 += a.x * ww.x + a.y * ww.y + a.z * ww.z + a.w * ww.w;
    }
    q_val[(size_t)b * DRr + t] = acc2;
}

// ---------------- combine ----------------
__global__ void combine_qk(const float* __restrict__ qr, const float* __restrict__ qv,
                           const float* __restrict__ swp, float* __restrict__ qk)
{
    int i = blockIdx.x * blockDim.x + threadIdx.x;
    if (i < B_ * DRr) {
        float sw = swp[0];
        qk[i] = sw * qr[i] + (1.f - sw) * qv[i];
    }
}

// ---------------- sim ----------------
__global__ __launch_bounds__(256)
void sim_kernel(const float* __restrict__ qk, const float* __restrict__ mkeys, float* __restrict__ sim)
{
    __shared__ float qs[DRr];
    int b = blockIdx.x, t = threadIdx.x;
    if (t < DRr) qs[t] = qk[(size_t)b * DRr + t];
    __syncthreads();
    float qn = 0.f;
    #pragma unroll 8
    for (int i = 0; i < DRr; i++) qn += qs[i] * qs[i];
    for (int n = t; n < NKEYS; n += 256) {
        const float* kr = mkeys + (size_t)n * DRr;
        float dot = 0.f, kn = 0.f;
        #pragma unroll 8
        for (int i = 0; i < DRr; i += 4) {
            float4 kv = *(const float4*)(kr + i);
            dot += qs[i] * kv.x + qs[i + 1] * kv.y + qs[i + 2] * kv.z + qs[i + 3] * kv.w;
            kn  += kv.x * kv.x + kv.y * kv.y + kv.z * kv.z + kv.w * kv.w;
        }
        float d = qn - 2.f * dot + kn;
        sim[(size_t)b * NKEYS + n] = -d / 0.1f;
    }
}

// ---------------- top-k (jax semantics: value desc, ties -> lower index) ----
static __device__ __forceinline__ void topk_insert(float* v, int* id, float x, int n) {
    bool better = (x > v[TOPK - 1]) || (x == v[TOPK - 1] && n < id[TOPK - 1]);
    if (better) {
        v[TOPK - 1] = x; id[TOPK - 1] = n;
        #pragma unroll
        for (int k = TOPK - 1; k > 0; k--) {
            bool sw = (v[k] > v[k - 1]) || (v[k] == v[k - 1] && id[k] < id[k - 1]);
            if (!sw) break;
            float tv = v[k]; v[k] = v[k - 1]; v[k - 1] = tv;
            int ti = id[k]; id[k] = id[k - 1]; id[k - 1] = ti;
        }
    }
}

__global__ __launch_bounds__(256)
void topk_kernel(const float* __restrict__ sim, int* __restrict__ topidx, float* __restrict__ wout)
{
    __shared__ float sv[256][TOPK];
    __shared__ int   si[256][TOPK];
    int b = blockIdx.x, t = threadIdx.x;
    float v[TOPK]; int id[TOPK];
    #pragma unroll
    for (int k = 0; k < TOPK; k++) { v[k] = -INFINITY; id[k] = 0x7fffffff; }
    for (int n = t; n < NKEYS; n += 256) {
        topk_insert(v, id, sim[(size_t)b * NKEYS + n], n);
    }
    #pragma unroll
    for (int k = 0; k < TOPK; k++) { sv[t][k] = v[k]; si[t][k] = id[k]; }
    for (int strd = 128; strd >= 1; strd >>= 1) {
        __syncthreads();
        if (t < strd) {
            #pragma unroll
            for (int k = 0; k < TOPK; k++) topk_insert(v, id, sv[t + strd][k], si[t + strd][k]);
            #pragma unroll
            for (int k = 0; k < TOPK; k++) { sv[t][k] = v[k]; si[t][k] = id[k]; }
        }
    }
    if (t == 0) {
        float m = v[0];
        float e[TOPK]; float sum = 0.f;
        #pragma unroll
        for (int k = 0; k < TOPK; k++) { e[k] = expf(v[k] - m); sum += e[k]; }
        #pragma unroll
        for (int k = 0; k < TOPK; k++) {
            wout[(size_t)b * TOPK + k] = e[k] / sum;
            topidx[b * TOPK + k] = id[k];
        }
    }
}

// ---------------- gather ----------------
__global__ __launch_bounds__(128)
void gather_kernel(const float* __restrict__ mv, const int* __restrict__ topidx, float* __restrict__ out)
{
    int blk = blockIdx.x;                 // b*480 + k*96 + p
    int b = blk / (TOPK * PP);
    int rem = blk - b * (TOPK * PP);
    int k = rem / PP;
    int p = rem - k * PP;
    int idx = topidx[b * TOPK + k];
    const float4* src = (const float4*)(mv + ((size_t)idx * PP + p) * DD);
    float4* dst = (float4*)(out + (size_t)blk * DD);
    dst[threadIdx.x] = src[threadIdx.x];
}

// ---------------- launch ----------------
extern "C" void kernel_launch(void* const* d_in, const int* in_sizes, int n_in,
                              void* d_out, int out_size, void* d_ws, size_t ws_size,
                              hipStream_t stream) {
    const float* query = (const float*)d_in[0];
    const float* mkeys = (const float*)d_in[1];
    const float* mvals = (const float*)d_in[2];
    const float* cls   = (const float*)d_in[3];
    const float* Wqkv  = (const float*)d_in[4];
    const float* bqkv  = (const float*)d_in[5];
    const float* Wo    = (const float*)d_in[6];
    const float* bo    = (const float*)d_in[7];
    const float* ln1g  = (const float*)d_in[8];
    const float* ln1b  = (const float*)d_in[9];
    const float* W1    = (const float*)d_in[10];
    const float* b1    = (const float*)d_in[11];
    const float* W2    = (const float*)d_in[12];
    const float* b2    = (const float*)d_in[13];
    const float* ln2g  = (const float*)d_in[14];
    const float* ln2b  = (const float*)d_in[15];
    const float* pW    = (const float*)d_in[16];
    const float* pb    = (const float*)d_in[17];
    const float* pg    = (const float*)d_in[18];
    const float* pbb   = (const float*)d_in[19];
    const float* vW1   = (const float*)d_in[20];
    const float* vb1   = (const float*)d_in[21];
    const float* vg    = (const float*)d_in[22];
    const float* vb    = (const float*)d_in[23];
    const float* vW2   = (const float*)d_in[24];
    const float* vb2   = (const float*)d_in[25];
    const float* swp   = (const float*)d_in[26];
    float* out = (float*)d_out;

    // ---- workspace layout ----
    float* ws   = (float*)d_ws;
    float* h    = ws;                                  // MROWS*512 fp32 (residual stream)
    float* big  = h + (size_t)MROWS * DD;              // MROWS*1536 fp32 arena
    // arena zones: zoneA = big[0 : MROWS*512] fp32 (pre-LN outputs)
    //              zoneB = big[MROWS*512 : ] hosts mid_hi/mid_lo (bf16) during FFN
    unsigned short* mid_hi = (unsigned short*)(big + (size_t)MROWS * DD);
    unsigned short* mid_lo = mid_hi + (size_t)MROWS * 1024;
    unsigned short* h_hi = (unsigned short*)(big + (size_t)MROWS * 1536);
    unsigned short* h_lo = h_hi + (size_t)MROWS * DD;  // attn-out splits alias h_hi/h_lo
    unsigned short* wq_hi = h_lo + (size_t)MROWS * DD;
    unsigned short* wq_lo = wq_hi + (size_t)2 * 1536 * DD;
    unsigned short* wo_hi = wq_lo + (size_t)2 * 1536 * DD;
    unsigned short* wo_lo = wo_hi + (size_t)2 * DD * DD;
    unsigned short* w1_hi = wo_lo + (size_t)2 * DD * DD;
    unsigned short* w1_lo = w1_hi + (size_t)2 * 1024 * DD;
    unsigned short* w2_hi = w1_lo + (size_t)2 * 1024 * DD;
    unsigned short* w2_lo = w2_hi + (size_t)2 * DD * 1024;
    float* xm   = (float*)(w2_lo + (size_t)2 * DD * 1024);
    float* qval = xm   + (size_t)B_ * DD;
    float* qrep = qval + (size_t)B_ * DRr;
    float* qkc  = qrep + (size_t)B_ * DRr;
    float* simb = qkc  + (size_t)B_ * DRr;
    int*   tidx = (int*)(simb + (size_t)B_ * NKEYS);
    (void)ws_size; (void)in_sizes; (void)n_in; (void)out_size;

    // ---- weight splits (once per call) ----
    {
        int n4;
        n4 = 2 * 1536 * DD / 4;
        split_kernel<<<(n4 + 255) / 256, 256, 0, stream>>>(Wqkv, wq_hi, wq_lo, n4);
        n4 = 2 * DD * DD / 4;
        split_kernel<<<(n4 + 255) / 256, 256, 0, stream>>>(Wo, wo_hi, wo_lo, n4);
        n4 = 2 * 1024 * DD / 4;
        split_kernel<<<(n4 + 255) / 256, 256, 0, stream>>>(W1, w1_hi, w1_lo, n4);
        n4 = 2 * DD * 1024 / 4;
        split_kernel<<<(n4 + 255) / 256, 256, 0, stream>>>(W2, w2_hi, w2_lo, n4);
    }

    concat_cls<<<MROWS, 128, 0, stream>>>(query, cls, h, h_hi, h_lo);

    for (int l = 0; l < 2; l++) {
        const unsigned short* wqh = wq_hi + (size_t)l * 1536 * DD;
        const unsigned short* wql = wq_lo + (size_t)l * 1536 * DD;
        const unsigned short* woh = wo_hi + (size_t)l * DD * DD;
        const unsigned short* wol = wo_lo + (size_t)l * DD * DD;
        const unsigned short* w1h = w1_hi + (size_t)l * 1024 * DD;
        const unsigned short* w1l = w1_lo + (size_t)l * 1024 * DD;
        const unsigned short* w2h = w2_hi + (size_t)l * DD * 1024;
        const unsigned short* w2l = w2_lo + (size_t)l * DD * 1024;
        const float* bq  = bqkv + (size_t)l * 1536;
        const float* bol = bo   + (size_t)l * DD;
        const float* g1  = ln1g + (size_t)l * DD;
        const float* be1 = ln1b + (size_t)l * DD;
        const float* b1l = b1   + (size_t)l * 1024;
        const float* b2l = b2   + (size_t)l * DD;
        const float* g2  = ln2g + (size_t)l * DD;
        const float* be2 = ln2b + (size_t)l * DD;

        // QKV: h_split @ Wqkv^T -> big (fp32, MROWS x 1536)
        gemm3<0><<<dim3(257, 12), 256, 0, stream>>>(h_hi, h_lo, wqh, wql, bq, nullptr,
                                                    big, nullptr, nullptr, MROWS, 1536, DD);
        // attention -> split bf16 into h_hi/h_lo (c splits)
        attn<<<dim3(9, 4, 64), 256, 0, stream>>>(big, h_hi, h_lo);
        // Wo: c_split @ Wo^T + bo + h -> zoneA fp32
        gemm3<1><<<dim3(257, 4), 256, 0, stream>>>(h_hi, h_lo, woh, wol, bol, h,
                                                   big, nullptr, nullptr, MROWS, DD, DD);
        // ln1: zoneA -> h fp32 + h splits
        ln512<<<MROWS, 128, 0, stream>>>(big, g1, be1, h, h_hi, h_lo);
        // FFN1: h_split @ W1^T + b1, gelu, split-out -> mid splits (zoneB)
        gemm3<2><<<dim3(257, 8), 256, 0, stream>>>(h_hi, h_lo, w1h, w1l, b1l, nullptr,
                                                   nullptr, mid_hi, mid_lo, MROWS, 1024, DD);
        // FFN2: mid_split @ W2^T + b2 + h -> zoneA fp32
        gemm3<1><<<dim3(257, 4), 256, 0, stream>>>(mid_hi, mid_lo, w2h, w2l, b2l, h,
                                                   big, nullptr, nullptr, MROWS, DD, 1024);
        // ln2: zoneA -> h fp32 + h splits
        ln512<<<MROWS, 128, 0, stream>>>(big, g2, be2, h, h_hi, h_lo);
    }

    proj_ln<<<B_, 128, 0, stream>>>(h, pW, pb, pg, pbb, qrep);
    mean_l<<<B_, 128, 0, stream>>>(query, xm);
    venc<<<B_, 128, 0, stream>>>(xm, vW1, vb1, vg, vb, vW2, vb2, qval);
    combine_qk<<<(B_ * DRr + 255) / 256, 256, 0, stream>>>(qrep, qval, swp, qkc);
    sim_kernel<<<B_, 256, 0, stream>>>(qkc, mkeys, simb);
    topk_kernel<<<B_, 256, 0, stream>>>(simb, tidx, out + (size_t)B_ * TOPK * PP * DD);
    gather_kernel<<<B_ * TOPK * PP, 128, 0, stream>>>(mvals, tidx, out);
}

// Round 3
// 2832.962 us; speedup vs baseline: 2.0447x; 1.3123x over previous
//
#include <hip/hip_runtime.h>
#include <math.h>

// Problem dims
#define B_    64
#define LQ    512
#define LC    513          // with CLS
#define DD    512
#define HH    4
#define DH    128
#define DRr   128
#define NKEYS 10000
#define PP    96
#define TOPK  5
#define MROWS (B_*LC)      // 32832
#define VTSTRIDE 544       // padded LC for transposed V (multiple of 16)

typedef __attribute__((ext_vector_type(8))) short short8v;
typedef __attribute__((ext_vector_type(4))) float f32x4;

static __device__ __forceinline__ float gelu_exact(float x) {
    return 0.5f * x * (1.0f + erff(x * 0.70710678118654752440f));
}

static __device__ __forceinline__ unsigned short f2bf(float x) {
    union { float f; unsigned u; } v; v.f = x;
    unsigned r = v.u + 0x7fff + ((v.u >> 16) & 1);
    return (unsigned short)(r >> 16);
}
static __device__ __forceinline__ float bf2f(unsigned short h) {
    union { float f; unsigned u; } v; v.u = ((unsigned)h) << 16;
    return v.f;
}
static __device__ __forceinline__ void split_bf(float x, unsigned short& hi, unsigned short& lo) {
    hi = f2bf(x);
    lo = f2bf(x - bf2f(hi));
}

// ---------------- generic fp32 -> (hi,lo) bf16 split ----------------
__global__ __launch_bounds__(256)
void split_kernel(const float* __restrict__ x, unsigned short* __restrict__ hi,
                  unsigned short* __restrict__ lo, int n4)
{
    int i = blockIdx.x * blockDim.x + threadIdx.x;
    if (i >= n4) return;
    float4 v = ((const float4*)x)[i];
    unsigned short h0,h1,h2,h3,l0,l1,l2,l3;
    split_bf(v.x,h0,l0); split_bf(v.y,h1,l1); split_bf(v.z,h2,l2); split_bf(v.w,h3,l3);
    ((uint2*)hi)[i] = make_uint2((unsigned)h0 | ((unsigned)h1 << 16), (unsigned)h2 | ((unsigned)h3 << 16));
    ((uint2*)lo)[i] = make_uint2((unsigned)l0 | ((unsigned)l1 << 16), (unsigned)l2 | ((unsigned)l3 << 16));
}

// ---------------- concat cls + query -> h (fp32 + splits) ----------------
__global__ __launch_bounds__(128)
void concat_cls(const float* __restrict__ query, const float* __restrict__ cls,
                float* __restrict__ h, unsigned short* __restrict__ h_hi,
                unsigned short* __restrict__ h_lo)
{
    int row = blockIdx.x;
    int t = threadIdx.x;
    int b = row / LC, r = row - b * LC;
    const float* src = (r == 0) ? cls : (query + ((size_t)b * LQ + (r - 1)) * DD);
    float4 v = *(const float4*)(src + t * 4);
    *(float4*)(h + (size_t)row * DD + t * 4) = v;
    unsigned short hs[4], ls[4];
    split_bf(v.x, hs[0], ls[0]); split_bf(v.y, hs[1], ls[1]);
    split_bf(v.z, hs[2], ls[2]); split_bf(v.w, hs[3], ls[3]);
    size_t o = (size_t)row * DD + t * 4;
    ((uint2*)(h_hi))[o >> 2] = make_uint2((unsigned)hs[0] | ((unsigned)hs[1]<<16),
                                          (unsigned)hs[2] | ((unsigned)hs[3]<<16));
    ((uint2*)(h_lo))[o >> 2] = make_uint2((unsigned)ls[0] | ((unsigned)ls[1]<<16),
                                          (unsigned)ls[2] | ((unsigned)ls[3]<<16));
}

// ---------------- split-bf16 MFMA GEMM: C = A @ W^T + bias (+res)(+gelu) ----
// MODE 0: C fp32 = acc + bias
// MODE 1: C fp32 = acc + bias + res
// MODE 2: (hi,lo) bf16 = gelu(acc + bias)
// MODE 3: QKV epilogue: c<1024 -> qk hi/lo [row][1024]; c>=1024 -> transposed V
#define BM 128
#define BN 128
#define BK 32
#define LDST 40

#define MFMA16(a, b, c) __builtin_amdgcn_mfma_f32_16x16x32_bf16(a, b, c, 0, 0, 0)

template<int MODE>
__global__ __launch_bounds__(256)
void gemm3(const unsigned short* __restrict__ Ahi, const unsigned short* __restrict__ Alo,
           const unsigned short* __restrict__ Whi, const unsigned short* __restrict__ Wlo,
           const float* __restrict__ bias, const float* __restrict__ res,
           float* __restrict__ Cf, unsigned short* __restrict__ Chi,
           unsigned short* __restrict__ Clo, unsigned short* __restrict__ Vhi,
           unsigned short* __restrict__ Vlo, int M, int N, int K)
{
    __shared__ __align__(16) unsigned short Ah[BM][LDST];
    __shared__ __align__(16) unsigned short Al[BM][LDST];
    __shared__ __align__(16) unsigned short Bh[BN][LDST];
    __shared__ __align__(16) unsigned short Bl[BN][LDST];

    const int t = threadIdx.x;
    const int lane = t & 63, w = t >> 6;
    const int wr = w >> 1, wc = w & 1;
    const int row0 = blockIdx.x * BM, col0 = blockIdx.y * BN;

    const int sr = t >> 1;
    const int sc = (t & 1) * 16;
    int agr = row0 + sr; if (agr >= M) agr = M - 1;
    const size_t aoff = (size_t)agr * K + sc;
    const size_t boff = (size_t)(col0 + sr) * K + sc;

    f32x4 acc[4][4];
    #pragma unroll
    for (int m = 0; m < 4; m++)
        #pragma unroll
        for (int n = 0; n < 4; n++) { acc[m][n][0]=0.f; acc[m][n][1]=0.f; acc[m][n][2]=0.f; acc[m][n][3]=0.f; }

    const int fr = lane & 15;
    const int fk = (lane >> 4) * 8;

    short8v sa_h[2], sa_l[2], sb_h[2], sb_l[2];
    {
        const short8v* p;
        p = (const short8v*)(Ahi + aoff); sa_h[0] = p[0]; sa_h[1] = p[1];
        p = (const short8v*)(Alo + aoff); sa_l[0] = p[0]; sa_l[1] = p[1];
        p = (const short8v*)(Whi + boff); sb_h[0] = p[0]; sb_h[1] = p[1];
        p = (const short8v*)(Wlo + boff); sb_l[0] = p[0]; sb_l[1] = p[1];
    }

    const int KT = K / BK;
    for (int kt = 0; kt < KT; kt++) {
        __syncthreads();
        *(short8v*)&Ah[sr][sc] = sa_h[0]; *(short8v*)&Ah[sr][sc + 8] = sa_h[1];
        *(short8v*)&Al[sr][sc] = sa_l[0]; *(short8v*)&Al[sr][sc + 8] = sa_l[1];
        *(short8v*)&Bh[sr][sc] = sb_h[0]; *(short8v*)&Bh[sr][sc + 8] = sb_h[1];
        *(short8v*)&Bl[sr][sc] = sb_l[0]; *(short8v*)&Bl[sr][sc + 8] = sb_l[1];
        __syncthreads();

        short8v ah[4], al[4], bh[4], bl[4];
        #pragma unroll
        for (int m = 0; m < 4; m++) {
            int r = wr * 64 + m * 16 + fr;
            ah[m] = *(const short8v*)&Ah[r][fk];
            al[m] = *(const short8v*)&Al[r][fk];
        }
        #pragma unroll
        for (int n = 0; n < 4; n++) {
            int c = wc * 64 + n * 16 + fr;
            bh[n] = *(const short8v*)&Bh[c][fk];
            bl[n] = *(const short8v*)&Bl[c][fk];
        }

        if (kt + 1 < KT) {
            int k0n = (kt + 1) * BK;
            const short8v* p;
            p = (const short8v*)(Ahi + aoff + k0n); sa_h[0] = p[0]; sa_h[1] = p[1];
            p = (const short8v*)(Alo + aoff + k0n); sa_l[0] = p[0]; sa_l[1] = p[1];
            p = (const short8v*)(Whi + boff + k0n); sb_h[0] = p[0]; sb_h[1] = p[1];
            p = (const short8v*)(Wlo + boff + k0n); sb_l[0] = p[0]; sb_l[1] = p[1];
        }

        #pragma unroll
        for (int m = 0; m < 4; m++)
            #pragma unroll
            for (int n = 0; n < 4; n++) {
                acc[m][n] = MFMA16(ah[m], bh[n], acc[m][n]);
                acc[m][n] = MFMA16(al[m], bh[n], acc[m][n]);
                acc[m][n] = MFMA16(ah[m], bl[n], acc[m][n]);
            }
    }

    // epilogue: C/D layout col=lane&15, row=(lane>>4)*4+reg
    #pragma unroll
    for (int m = 0; m < 4; m++) {
        int rb = row0 + wr * 64 + m * 16 + (lane >> 4) * 4;
        #pragma unroll
        for (int n = 0; n < 4; n++) {
            int c = col0 + wc * 64 + n * 16 + fr;
            float bcol = bias[c];
            #pragma unroll
            for (int r = 0; r < 4; r++) {
                int row = rb + r;
                if (row < M) {
                    float v = acc[m][n][r] + bcol;
                    if (MODE == 1) v += res[(size_t)row * N + c];
                    if (MODE == 2) {
                        v = gelu_exact(v);
                        unsigned short hv, lv;
                        split_bf(v, hv, lv);
                        Chi[(size_t)row * N + c] = hv;
                        Clo[(size_t)row * N + c] = lv;
                    } else if (MODE == 3) {
                        unsigned short hv, lv;
                        split_bf(v, hv, lv);
                        if (c < 1024) {
                            Chi[(size_t)row * 1024 + c] = hv;
                            Clo[(size_t)row * 1024 + c] = lv;
                        } else {
                            int da = c - 1024, hh = da >> 7, dd = da & 127;
                            int bb = row / LC, ll = row - bb * LC;
                            size_t vi = ((size_t)((bb * HH + hh) * DH + dd)) * VTSTRIDE + ll;
                            Vhi[vi] = hv; Vlo[vi] = lv;
                        }
                    } else {
                        Cf[(size_t)row * N + c] = v;
                    }
                }
            }
        }
    }
}

// ---------------- MFMA flash attention, split-bf16 ----------------
// qk:  [MROWS][1024] hi/lo (q cols 0..511, k cols 512..1023; head h at h*128)
// vt:  [(b*4+h)*128 + d][VTSTRIDE] hi/lo  (transposed V)
// out: [MROWS][512] hi/lo splits
#define AQT 64
#define AKT 32
#define NKT2 17
// LDS layout (shorts):
//  KH [32][136] @0      KL @4352
//  VH [128][40] @8704   VL @13824
//  PH [64][40]  @18944  PL @21504          total 24064 shorts = 48128 B
//  OS [64][136] @0 (reuses K region after main loop)
__global__ __launch_bounds__(256)
void attn_mfma(const unsigned short* __restrict__ qkhi, const unsigned short* __restrict__ qklo,
               const unsigned short* __restrict__ vthi, const unsigned short* __restrict__ vtlo,
               unsigned short* __restrict__ ohi, unsigned short* __restrict__ olo)
{
    __shared__ __align__(16) unsigned short SM[24064];
    #define KH(r,d) SM[(r)*136 + (d)]
    #define KL(r,d) SM[4352 + (r)*136 + (d)]
    #define VH(d,k) SM[8704 + (d)*40 + (k)]
    #define VL(d,k) SM[13824 + (d)*40 + (k)]
    #define PH(r,k) SM[18944 + (r)*40 + (k)]
    #define PL(r,k) SM[21504 + (r)*40 + (k)]
    #define OS(r,d) SM[(r)*136 + (d)]

    const int t = threadIdx.x;
    const int lane = t & 63, w = t >> 6;
    const int qt = blockIdx.x, h = blockIdx.y, b = blockIdx.z;
    const int q0 = qt * AQT;
    const int c = lane & 15, g = lane >> 4;
    const float SCALE = 0.08838834764831845f; // 1/sqrt(128)

    // Q A-fragments in registers: rows w*16 + c, d = ks*32 + g*8 + j
    short8v qh[4], ql[4];
    {
        int qrow = b * LC + q0 + w * 16 + c;
        if (qrow > MROWS - 1) qrow = MROWS - 1;
        const unsigned short* bh_ = qkhi + (size_t)qrow * 1024 + h * DH;
        const unsigned short* bl_ = qklo + (size_t)qrow * 1024 + h * DH;
        #pragma unroll
        for (int ks = 0; ks < 4; ks++) {
            qh[ks] = *(const short8v*)(bh_ + ks * 32 + g * 8);
            ql[ks] = *(const short8v*)(bl_ + ks * 32 + g * 8);
        }
    }

    float m_r[4], l_r[4];
    #pragma unroll
    for (int r = 0; r < 4; r++) { m_r[r] = -INFINITY; l_r[r] = 0.f; }
    f32x4 acc_o[8];
    #pragma unroll
    for (int n = 0; n < 8; n++) { acc_o[n][0]=0.f; acc_o[n][1]=0.f; acc_o[n][2]=0.f; acc_o[n][3]=0.f; }

    // staging indices
    const int skr = t >> 3, skd = (t & 7) * 16;      // K: 32 rows x 128 d
    const int svd = t >> 1, svk = (t & 1) * 16;      // V: 128 d x 32 kv

    for (int kt = 0; kt < NKT2; kt++) {
        __syncthreads();
        {
            int krow = b * LC + kt * AKT + skr;
            if (krow > MROWS - 1) krow = MROWS - 1;
            const unsigned short* kb  = qkhi + (size_t)krow * 1024 + 512 + h * DH + skd;
            const unsigned short* kbl = qklo + (size_t)krow * 1024 + 512 + h * DH + skd;
            *(short8v*)&KH(skr, skd)     = *(const short8v*)kb;
            *(short8v*)&KH(skr, skd + 8) = *(const short8v*)(kb + 8);
            *(short8v*)&KL(skr, skd)     = *(const short8v*)kbl;
            *(short8v*)&KL(skr, skd + 8) = *(const short8v*)(kbl + 8);
            const unsigned short* vb  = vthi + ((size_t)((b * HH + h) * DH + svd)) * VTSTRIDE + kt * AKT + svk;
            const unsigned short* vbl = vtlo + ((size_t)((b * HH + h) * DH + svd)) * VTSTRIDE + kt * AKT + svk;
            *(short8v*)&VH(svd, svk)     = *(const short8v*)vb;
            *(short8v*)&VH(svd, svk + 8) = *(const short8v*)(vb + 8);
            *(short8v*)&VL(svd, svk)     = *(const short8v*)vbl;
            *(short8v*)&VL(svd, svk + 8) = *(const short8v*)(vbl + 8);
        }
        __syncthreads();

        // S = Q K^T : this wave's rows w*16.., cols kt*32 + n*16 + c
        f32x4 s[2];
        s[0][0]=s[0][1]=s[0][2]=s[0][3]=0.f;
        s[1][0]=s[1][1]=s[1][2]=s[1][3]=0.f;
        #pragma unroll
        for (int n = 0; n < 2; n++) {
            #pragma unroll
            for (int ks = 0; ks < 4; ks++) {
                short8v kh = *(const short8v*)&KH(n * 16 + c, ks * 32 + g * 8);
                short8v kl = *(const short8v*)&KL(n * 16 + c, ks * 32 + g * 8);
                s[n] = MFMA16(qh[ks], kh, s[n]);
                s[n] = MFMA16(ql[ks], kh, s[n]);
                s[n] = MFMA16(qh[ks], kl, s[n]);
            }
        }

        // scale + mask (cols >= LC)
        #pragma unroll
        for (int n = 0; n < 2; n++) {
            bool oob = (kt * 32 + n * 16 + c) >= LC;
            #pragma unroll
            for (int r = 0; r < 4; r++) {
                float sv = s[n][r] * SCALE;
                s[n][r] = oob ? -INFINITY : sv;
            }
        }

        // online softmax; rows = q0 + w*16 + g*4 + r, replicated across 16-lane group
        float alpha[4], p0v[4], p1v[4];
        #pragma unroll
        for (int r = 0; r < 4; r++) {
            float rm = fmaxf(s[0][r], s[1][r]);
            #pragma unroll
            for (int off = 1; off < 16; off <<= 1) rm = fmaxf(rm, __shfl_xor(rm, off));
            float mn = fmaxf(m_r[r], rm);
            float p0 = expf(s[0][r] - mn);
            float p1 = expf(s[1][r] - mn);
            float ts = p0 + p1;
            #pragma unroll
            for (int off = 1; off < 16; off <<= 1) ts += __shfl_xor(ts, off);
            float al = expf(m_r[r] - mn);
            m_r[r] = mn;
            l_r[r] = al * l_r[r] + ts;
            alpha[r] = al;
            p0v[r] = p0; p1v[r] = p1;
        }

        // rescale O
        #pragma unroll
        for (int n = 0; n < 8; n++)
            #pragma unroll
            for (int r = 0; r < 4; r++) acc_o[n][r] *= alpha[r];

        // P splits -> LDS (wave-private rows)
        #pragma unroll
        for (int r = 0; r < 4; r++) {
            unsigned short ph, pl;
            split_bf(p0v[r], ph, pl);
            PH(w * 16 + g * 4 + r, c) = ph;
            PL(w * 16 + g * 4 + r, c) = pl;
            split_bf(p1v[r], ph, pl);
            PH(w * 16 + g * 4 + r, 16 + c) = ph;
            PL(w * 16 + g * 4 + r, 16 + c) = pl;
        }
        __syncthreads();

        // PV: O[16q][128d] += P[16q][32kv] * V[32kv][128d]
        short8v pah = *(const short8v*)&PH(w * 16 + c, g * 8);
        short8v pal = *(const short8v*)&PL(w * 16 + c, g * 8);
        #pragma unroll
        for (int n = 0; n < 8; n++) {
            short8v vh = *(const short8v*)&VH(n * 16 + c, g * 8);
            short8v vl = *(const short8v*)&VL(n * 16 + c, g * 8);
            acc_o[n] = MFMA16(pah, vh, acc_o[n]);
            acc_o[n] = MFMA16(pal, vh, acc_o[n]);
            acc_o[n] = MFMA16(pah, vl, acc_o[n]);
        }
    }

    float inv[4];
    #pragma unroll
    for (int r = 0; r < 4; r++) inv[r] = 1.0f / l_r[r];

    // two-pass O store via LDS (coalesced)
    const int orow = t >> 2, oc0 = (t & 3) * 32;
    #pragma unroll
    for (int pass = 0; pass < 2; pass++) {
        __syncthreads();
        #pragma unroll
        for (int n = 0; n < 8; n++)
            #pragma unroll
            for (int r = 0; r < 4; r++) {
                float v = acc_o[n][r] * inv[r];
                unsigned short hv, lv;
                split_bf(v, hv, lv);
                OS(w * 16 + g * 4 + r, n * 16 + c) = pass ? lv : hv;
            }
        __syncthreads();
        int grow = q0 + orow;
        if (grow < LC) {
            unsigned short* dst = (pass ? olo : ohi) + ((size_t)(b * LC + grow)) * DD + h * DH + oc0;
            #pragma unroll
            for (int u = 0; u < 4; u++)
                *(short8v*)(dst + u * 8) = *(const short8v*)&OS(orow, oc0 + u * 8);
        }
    }
    #undef KH
    #undef KL
    #undef VH
    #undef VL
    #undef PH
    #undef PL
    #undef OS
}

// ---------------- LayerNorm over 512, writes fp32 + splits ----------------
__global__ __launch_bounds__(128)
void ln512(const float* __restrict__ X, const float* __restrict__ g,
           const float* __restrict__ bb, float* __restrict__ Y,
           unsigned short* __restrict__ Yhi, unsigned short* __restrict__ Ylo)
{
    __shared__ float red[2];
    int row = blockIdx.x, t = threadIdx.x;
    const float* x = X + (size_t)row * DD;
    float4 v = *(const float4*)(x + t * 4);
    float s = v.x + v.y + v.z + v.w;
    #pragma unroll
    for (int off = 1; off < 64; off <<= 1) s += __shfl_xor(s, off);
    if ((t & 63) == 0) red[t >> 6] = s;
    __syncthreads();
    float mean = (red[0] + red[1]) * (1.0f / 512.0f);
    __syncthreads();
    float d0 = v.x - mean, d1 = v.y - mean, d2 = v.z - mean, d3 = v.w - mean;
    float s2 = d0 * d0 + d1 * d1 + d2 * d2 + d3 * d3;
    #pragma unroll
    for (int off = 1; off < 64; off <<= 1) s2 += __shfl_xor(s2, off);
    if ((t & 63) == 0) red[t >> 6] = s2;
    __syncthreads();
    float var = (red[0] + red[1]) * (1.0f / 512.0f);
    float rstd = 1.0f / sqrtf(var + 1e-5f);
    float4 gv = *(const float4*)(g + t * 4);
    float4 bv = *(const float4*)(bb + t * 4);
    float4 ov;
    ov.x = d0 * rstd * gv.x + bv.x;
    ov.y = d1 * rstd * gv.y + bv.y;
    ov.z = d2 * rstd * gv.z + bv.z;
    ov.w = d3 * rstd * gv.w + bv.w;
    size_t o = (size_t)row * DD + t * 4;
    *(float4*)(Y + o) = ov;
    unsigned short hs[4], ls[4];
    split_bf(ov.x, hs[0], ls[0]); split_bf(ov.y, hs[1], ls[1]);
    split_bf(ov.z, hs[2], ls[2]); split_bf(ov.w, hs[3], ls[3]);
    ((uint2*)Yhi)[o >> 2] = make_uint2((unsigned)hs[0] | ((unsigned)hs[1]<<16),
                                       (unsigned)hs[2] | ((unsigned)hs[3]<<16));
    ((uint2*)Ylo)[o >> 2] = make_uint2((unsigned)ls[0] | ((unsigned)ls[1]<<16),
                                       (unsigned)ls[2] | ((unsigned)ls[3]<<16));
}

// ---------------- mean over L ----------------
__global__ __launch_bounds__(128)
void mean_l(const float* __restrict__ query, float* __restrict__ xm)
{
    int b = blockIdx.x, t = threadIdx.x;
    const float* base = query + (size_t)b * LQ * DD + t * 4;
    float ax = 0.f, ay = 0.f, az = 0.f, aw = 0.f;
    for (int l = 0; l < LQ; l++) {
        float4 v = *(const float4*)(base + (size_t)l * DD);
        ax += v.x; ay += v.y; az += v.z; aw += v.w;
    }
    float4 o = make_float4(ax * (1.f/512.f), ay * (1.f/512.f), az * (1.f/512.f), aw * (1.f/512.f));
    *(float4*)(xm + (size_t)b * DD + t * 4) = o;
}

static __device__ __forceinline__ float block128_sum(float x, float* red, int t) {
    #pragma unroll
    for (int off = 1; off < 64; off <<= 1) x += __shfl_xor(x, off);
    if ((t & 63) == 0) red[t >> 6] = x;
    __syncthreads();
    float r = red[0] + red[1];
    __syncthreads();
    return r;
}

// ---------------- proj + LN -> q_repr ----------------
__global__ __launch_bounds__(128)
void proj_ln(const float* __restrict__ h, const float* __restrict__ pW, const float* __restrict__ pb,
             const float* __restrict__ pg, const float* __restrict__ pbb, float* __restrict__ q_repr)
{
    __shared__ float xs[DD];
    __shared__ float red[2];
    int b = blockIdx.x, t = threadIdx.x;
    *(float4*)&xs[t * 4] = *(const float4*)(h + (size_t)(b * LC) * DD + t * 4);
    __syncthreads();
    const float* w = pW + (size_t)t * DD;
    float acc = pb[t];
    for (int k = 0; k < DD; k += 4) {
        float4 a = *(const float4*)&xs[k];
        float4 ww = *(const float4*)(w + k);
        acc += a.x * ww.x + a.y * ww.y + a.z * ww.z + a.w * ww.w;
    }
    float mean = block128_sum(acc, red, t) * (1.f / 128.f);
    float dx = acc - mean;
    float var = block128_sum(dx * dx, red, t) * (1.f / 128.f);
    float rstd = 1.0f / sqrtf(var + 1e-5f);
    q_repr[(size_t)b * DRr + t] = dx * rstd * pg[t] + pbb[t];
}

// ---------------- value encoder (fused) -> q_val ----------------
__global__ __launch_bounds__(128)
void venc(const float* __restrict__ xm, const float* __restrict__ vW1, const float* __restrict__ vb1,
          const float* __restrict__ vg, const float* __restrict__ vb,
          const float* __restrict__ vW2, const float* __restrict__ vb2,
          float* __restrict__ q_val)
{
    __shared__ float xs[DD];
    __shared__ float hg[DRr];
    __shared__ float red[2];
    int b = blockIdx.x, t = threadIdx.x;
    *(float4*)&xs[t * 4] = *(const float4*)(xm + (size_t)b * DD + t * 4);
    __syncthreads();
    const float* w = vW1 + (size_t)t * DD;
    float acc = vb1[t];
    for (int k = 0; k < DD; k += 4) {
        float4 a = *(const float4*)&xs[k];
        float4 ww = *(const float4*)(w + k);
        acc += a.x * ww.x + a.y * ww.y + a.z * ww.z + a.w * ww.w;
    }
    float mean = block128_sum(acc, red, t) * (1.f / 128.f);
    float dx = acc - mean;
    float var = block128_sum(dx * dx, red, t) * (1.f / 128.f);
    float rstd = 1.0f / sqrtf(var + 1e-5f);
    float hn = dx * rstd * vg[t] + vb[t];
    hg[t] = gelu_exact(hn);
    __syncthreads();
    const float* w2 = vW2 + (size_t)t * DRr;
    float acc2 = vb2[t];
    for (int k = 0; k < DRr; k += 4) {
        float4 a = *(const float4*)&hg[k];
        float4 ww = *(const float4*)(w2 + k);
        acc2 += a.x * ww.x + a.y * ww.y + a.z * ww.z + a.w * ww.w;
    }
    q_val[(size_t)b * DRr + t] = acc2;
}

// ---------------- combine ----------------
__global__ void combine_qk(const float* __restrict__ qr, const float* __restrict__ qv,
                           const float* __restrict__ swp, float* __restrict__ qk)
{
    int i = blockIdx.x * blockDim.x + threadIdx.x;
    if (i < B_ * DRr) {
        float sw = swp[0];
        qk[i] = sw * qr[i] + (1.f - sw) * qv[i];
    }
}

// ---------------- sim ----------------
__global__ __launch_bounds__(256)
void sim_kernel(const float* __restrict__ qk, const float* __restrict__ mkeys, float* __restrict__ sim)
{
    __shared__ float qs[DRr];
    int b = blockIdx.x, t = threadIdx.x;
    if (t < DRr) qs[t] = qk[(size_t)b * DRr + t];
    __syncthreads();
    float qn = 0.f;
    #pragma unroll 8
    for (int i = 0; i < DRr; i++) qn += qs[i] * qs[i];
    for (int n = t; n < NKEYS; n += 256) {
        const float* kr = mkeys + (size_t)n * DRr;
        float dot = 0.f, kn = 0.f;
        #pragma unroll 8
        for (int i = 0; i < DRr; i += 4) {
            float4 kv = *(const float4*)(kr + i);
            dot += qs[i] * kv.x + qs[i + 1] * kv.y + qs[i + 2] * kv.z + qs[i + 3] * kv.w;
            kn  += kv.x * kv.x + kv.y * kv.y + kv.z * kv.z + kv.w * kv.w;
        }
        float d = qn - 2.f * dot + kn;
        sim[(size_t)b * NKEYS + n] = -d / 0.1f;
    }
}

// ---------------- top-k (jax semantics: value desc, ties -> lower index) ----
static __device__ __forceinline__ void topk_insert(float* v, int* id, float x, int n) {
    bool better = (x > v[TOPK - 1]) || (x == v[TOPK - 1] && n < id[TOPK - 1]);
    if (better) {
        v[TOPK - 1] = x; id[TOPK - 1] = n;
        #pragma unroll
        for (int k = TOPK - 1; k > 0; k--) {
            bool sw = (v[k] > v[k - 1]) || (v[k] == v[k - 1] && id[k] < id[k - 1]);
            if (!sw) break;
            float tv = v[k]; v[k] = v[k - 1]; v[k - 1] = tv;
            int ti = id[k]; id[k] = id[k - 1]; id[k - 1] = ti;
        }
    }
}

__global__ __launch_bounds__(256)
void topk_kernel(const float* __restrict__ sim, int* __restrict__ topidx, float* __restrict__ wout)
{
    __shared__ float sv[256][TOPK];
    __shared__ int   si[256][TOPK];
    int b = blockIdx.x, t = threadIdx.x;
    float v[TOPK]; int id[TOPK];
    #pragma unroll
    for (int k = 0; k < TOPK; k++) { v[k] = -INFINITY; id[k] = 0x7fffffff; }
    for (int n = t; n < NKEYS; n += 256) {
        topk_insert(v, id, sim[(size_t)b * NKEYS + n], n);
    }
    #pragma unroll
    for (int k = 0; k < TOPK; k++) { sv[t][k] = v[k]; si[t][k] = id[k]; }
    for (int strd = 128; strd >= 1; strd >>= 1) {
        __syncthreads();
        if (t < strd) {
            #pragma unroll
            for (int k = 0; k < TOPK; k++) topk_insert(v, id, sv[t + strd][k], si[t + strd][k]);
            #pragma unroll
            for (int k = 0; k < TOPK; k++) { sv[t][k] = v[k]; si[t][k] = id[k]; }
        }
    }
    if (t == 0) {
        float m = v[0];
        float e[TOPK]; float sum = 0.f;
        #pragma unroll
        for (int k = 0; k < TOPK; k++) { e[k] = expf(v[k] - m); sum += e[k]; }
        #pragma unroll
        for (int k = 0; k < TOPK; k++) {
            wout[(size_t)b * TOPK + k] = e[k] / sum;
            topidx[b * TOPK + k] = id[k];
        }
    }
}

// ---------------- gather ----------------
__global__ __launch_bounds__(128)
void gather_kernel(const float* __restrict__ mv, const int* __restrict__ topidx, float* __restrict__ out)
{
    int blk = blockIdx.x;
    int b = blk / (TOPK * PP);
    int rem = blk - b * (TOPK * PP);
    int k = rem / PP;
    int p = rem - k * PP;
    int idx = topidx[b * TOPK + k];
    const float4* src = (const float4*)(mv + ((size_t)idx * PP + p) * DD);
    float4* dst = (float4*)(out + (size_t)blk * DD);
    dst[threadIdx.x] = src[threadIdx.x];
}

// ---------------- launch ----------------
extern "C" void kernel_launch(void* const* d_in, const int* in_sizes, int n_in,
                              void* d_out, int out_size, void* d_ws, size_t ws_size,
                              hipStream_t stream) {
    const float* query = (const float*)d_in[0];
    const float* mkeys = (const float*)d_in[1];
    const float* mvals = (const float*)d_in[2];
    const float* cls   = (const float*)d_in[3];
    const float* Wqkv  = (const float*)d_in[4];
    const float* bqkv  = (const float*)d_in[5];
    const float* Wo    = (const float*)d_in[6];
    const float* bo    = (const float*)d_in[7];
    const float* ln1g  = (const float*)d_in[8];
    const float* ln1b  = (const float*)d_in[9];
    const float* W1    = (const float*)d_in[10];
    const float* b1    = (const float*)d_in[11];
    const float* W2    = (const float*)d_in[12];
    const float* b2    = (const float*)d_in[13];
    const float* ln2g  = (const float*)d_in[14];
    const float* ln2b  = (const float*)d_in[15];
    const float* pW    = (const float*)d_in[16];
    const float* pb    = (const float*)d_in[17];
    const float* pg    = (const float*)d_in[18];
    const float* pbb   = (const float*)d_in[19];
    const float* vW1   = (const float*)d_in[20];
    const float* vb1   = (const float*)d_in[21];
    const float* vg    = (const float*)d_in[22];
    const float* vb    = (const float*)d_in[23];
    const float* vW2   = (const float*)d_in[24];
    const float* vb2   = (const float*)d_in[25];
    const float* swp   = (const float*)d_in[26];
    float* out = (float*)d_out;

    // ---- workspace layout ----
    float* ws    = (float*)d_ws;
    float* h     = ws;                                   // MROWS*512 fp32 residual
    float* preln = h + (size_t)MROWS * DD;               // MROWS*512 fp32
    unsigned short* h_hi  = (unsigned short*)(preln + (size_t)MROWS * DD);
    unsigned short* h_lo  = h_hi  + (size_t)MROWS * DD;
    unsigned short* mid_hi = h_lo + (size_t)MROWS * DD;  // MROWS*1024
    unsigned short* mid_lo = mid_hi + (size_t)MROWS * 1024;
    unsigned short* qkhi  = mid_lo + (size_t)MROWS * 1024;
    unsigned short* qklo  = qkhi  + (size_t)MROWS * 1024;
    unsigned short* vthi  = qklo  + (size_t)MROWS * 1024;   // 32768*VTSTRIDE
    unsigned short* vtlo  = vthi  + (size_t)32768 * VTSTRIDE;
    unsigned short* wq_hi = vtlo  + (size_t)32768 * VTSTRIDE;
    unsigned short* wq_lo = wq_hi + (size_t)2 * 1536 * DD;
    unsigned short* wo_hi = wq_lo + (size_t)2 * 1536 * DD;
    unsigned short* wo_lo = wo_hi + (size_t)2 * DD * DD;
    unsigned short* w1_hi = wo_lo + (size_t)2 * DD * DD;
    unsigned short* w1_lo = w1_hi + (size_t)2 * 1024 * DD;
    unsigned short* w2_hi = w1_lo + (size_t)2 * 1024 * DD;
    unsigned short* w2_lo = w2_hi + (size_t)2 * DD * 1024;
    float* xm   = (float*)(w2_lo + (size_t)2 * DD * 1024);
    float* qval = xm   + (size_t)B_ * DD;
    float* qrep = qval + (size_t)B_ * DRr;
    float* qkc  = qrep + (size_t)B_ * DRr;
    float* simb = qkc  + (size_t)B_ * DRr;
    int*   tidx = (int*)(simb + (size_t)B_ * NKEYS);
    (void)ws_size; (void)in_sizes; (void)n_in; (void)out_size;

    // ---- weight splits ----
    {
        int n4;
        n4 = 2 * 1536 * DD / 4;
        split_kernel<<<(n4 + 255) / 256, 256, 0, stream>>>(Wqkv, wq_hi, wq_lo, n4);
        n4 = 2 * DD * DD / 4;
        split_kernel<<<(n4 + 255) / 256, 256, 0, stream>>>(Wo, wo_hi, wo_lo, n4);
        n4 = 2 * 1024 * DD / 4;
        split_kernel<<<(n4 + 255) / 256, 256, 0, stream>>>(W1, w1_hi, w1_lo, n4);
        n4 = 2 * DD * 1024 / 4;
        split_kernel<<<(n4 + 255) / 256, 256, 0, stream>>>(W2, w2_hi, w2_lo, n4);
    }

    concat_cls<<<MROWS, 128, 0, stream>>>(query, cls, h, h_hi, h_lo);

    for (int l = 0; l < 2; l++) {
        const unsigned short* wqh = wq_hi + (size_t)l * 1536 * DD;
        const unsigned short* wql = wq_lo + (size_t)l * 1536 * DD;
        const unsigned short* woh = wo_hi + (size_t)l * DD * DD;
        const unsigned short* wol = wo_lo + (size_t)l * DD * DD;
        const unsigned short* w1h = w1_hi + (size_t)l * 1024 * DD;
        const unsigned short* w1l = w1_lo + (size_t)l * 1024 * DD;
        const unsigned short* w2h = w2_hi + (size_t)l * DD * 1024;
        const unsigned short* w2l = w2_lo + (size_t)l * DD * 1024;
        const float* bq  = bqkv + (size_t)l * 1536;
        const float* bol = bo   + (size_t)l * DD;
        const float* g1  = ln1g + (size_t)l * DD;
        const float* be1 = ln1b + (size_t)l * DD;
        const float* b1l = b1   + (size_t)l * 1024;
        const float* b2l = b2   + (size_t)l * DD;
        const float* g2  = ln2g + (size_t)l * DD;
        const float* be2 = ln2b + (size_t)l * DD;

        // QKV -> qk splits + transposed V splits
        gemm3<3><<<dim3(257, 12), 256, 0, stream>>>(h_hi, h_lo, wqh, wql, bq, nullptr,
                                                    nullptr, qkhi, qklo, vthi, vtlo,
                                                    MROWS, 1536, DD);
        // MFMA attention -> h_hi/h_lo (attn-out splits)
        attn_mfma<<<dim3(9, HH, B_), 256, 0, stream>>>(qkhi, qklo, vthi, vtlo, h_hi, h_lo);
        // Wo + residual -> preln fp32
        gemm3<1><<<dim3(257, 4), 256, 0, stream>>>(h_hi, h_lo, woh, wol, bol, h,
                                                   preln, nullptr, nullptr, nullptr, nullptr,
                                                   MROWS, DD, DD);
        ln512<<<MROWS, 128, 0, stream>>>(preln, g1, be1, h, h_hi, h_lo);
        // FFN1 + gelu -> mid splits
        gemm3<2><<<dim3(257, 8), 256, 0, stream>>>(h_hi, h_lo, w1h, w1l, b1l, nullptr,
                                                   nullptr, mid_hi, mid_lo, nullptr, nullptr,
                                                   MROWS, 1024, DD);
        // FFN2 + residual -> preln fp32
        gemm3<1><<<dim3(257, 4), 256, 0, stream>>>(mid_hi, mid_lo, w2h, w2l, b2l, h,
                                                   preln, nullptr, nullptr, nullptr, nullptr,
                                                   MROWS, DD, 1024);
        ln512<<<MROWS, 128, 0, stream>>>(preln, g2, be2, h, h_hi, h_lo);
    }

    proj_ln<<<B_, 128, 0, stream>>>(h, pW, pb, pg, pbb, qrep);
    mean_l<<<B_, 128, 0, stream>>>(query, xm);
    venc<<<B_, 128, 0, stream>>>(xm, vW1, vb1, vg, vb, vW2, vb2, qval);
    combine_qk<<<(B_ * DRr + 255) / 256, 256, 0, stream>>>(qrep, qval, swp, qkc);
    sim_kernel<<<B_, 256, 0, stream>>>(qkc, mkeys, simb);
    topk_kernel<<<B_, 256, 0, stream>>>(simb, tidx, out + (size_t)B_ * TOPK * PP * DD);
    gather_kernel<<<B_ * TOPK * PP, 128, 0, stream>>>(mvals, tidx, out);
}

// Round 4
// 2498.970 us; speedup vs baseline: 2.3179x; 1.1337x over previous
//
#include <hip/hip_runtime.h>
#include <math.h>

// Problem dims
#define B_    64
#define LQ    512
#define LC    513          // with CLS
#define DD    512
#define HH    4
#define DH    128
#define DRr   128
#define NKEYS 10000
#define PP    96
#define TOPK  5
#define MROWS (B_*LC)      // 32832
#define VTSTRIDE 544       // padded LC for transposed V (multiple of 16)

typedef __attribute__((ext_vector_type(8))) short short8v;
typedef __attribute__((ext_vector_type(4))) float f32x4;

static __device__ __forceinline__ float gelu_exact(float x) {
    return 0.5f * x * (1.0f + erff(x * 0.70710678118654752440f));
}

static __device__ __forceinline__ unsigned short f2bf(float x) {
    union { float f; unsigned u; } v; v.f = x;
    unsigned r = v.u + 0x7fff + ((v.u >> 16) & 1);
    return (unsigned short)(r >> 16);
}
static __device__ __forceinline__ float bf2f(unsigned short h) {
    union { float f; unsigned u; } v; v.u = ((unsigned)h) << 16;
    return v.f;
}
static __device__ __forceinline__ void split_bf(float x, unsigned short& hi, unsigned short& lo) {
    hi = f2bf(x);
    lo = f2bf(x - bf2f(hi));
}

// async global->LDS, 16B per lane. LDS dest must be linear: base + lane*16.
static __device__ __forceinline__ void gload16(const unsigned short* g, unsigned short* l) {
    __builtin_amdgcn_global_load_lds(
        (const __attribute__((address_space(1))) unsigned*)g,
        (__attribute__((address_space(3))) unsigned*)l, 16, 0, 0);
}

// ---------------- generic fp32 -> (hi,lo) bf16 split ----------------
__global__ __launch_bounds__(256)
void split_kernel(const float* __restrict__ x, unsigned short* __restrict__ hi,
                  unsigned short* __restrict__ lo, int n4)
{
    int i = blockIdx.x * blockDim.x + threadIdx.x;
    if (i >= n4) return;
    float4 v = ((const float4*)x)[i];
    unsigned short h0,h1,h2,h3,l0,l1,l2,l3;
    split_bf(v.x,h0,l0); split_bf(v.y,h1,l1); split_bf(v.z,h2,l2); split_bf(v.w,h3,l3);
    ((uint2*)hi)[i] = make_uint2((unsigned)h0 | ((unsigned)h1 << 16), (unsigned)h2 | ((unsigned)h3 << 16));
    ((uint2*)lo)[i] = make_uint2((unsigned)l0 | ((unsigned)l1 << 16), (unsigned)l2 | ((unsigned)l3 << 16));
}

// ---------------- concat cls + query -> h (fp32 + splits) ----------------
__global__ __launch_bounds__(128)
void concat_cls(const float* __restrict__ query, const float* __restrict__ cls,
                float* __restrict__ h, unsigned short* __restrict__ h_hi,
                unsigned short* __restrict__ h_lo)
{
    int row = blockIdx.x;
    int t = threadIdx.x;
    int b = row / LC, r = row - b * LC;
    const float* src = (r == 0) ? cls : (query + ((size_t)b * LQ + (r - 1)) * DD);
    float4 v = *(const float4*)(src + t * 4);
    *(float4*)(h + (size_t)row * DD + t * 4) = v;
    unsigned short hs[4], ls[4];
    split_bf(v.x, hs[0], ls[0]); split_bf(v.y, hs[1], ls[1]);
    split_bf(v.z, hs[2], ls[2]); split_bf(v.w, hs[3], ls[3]);
    size_t o = (size_t)row * DD + t * 4;
    ((uint2*)(h_hi))[o >> 2] = make_uint2((unsigned)hs[0] | ((unsigned)hs[1]<<16),
                                          (unsigned)hs[2] | ((unsigned)hs[3]<<16));
    ((uint2*)(h_lo))[o >> 2] = make_uint2((unsigned)ls[0] | ((unsigned)ls[1]<<16),
                                          (unsigned)ls[2] | ((unsigned)ls[3]<<16));
}

// ---------------- split-bf16 MFMA GEMM: C = A @ W^T + bias (+res)(+gelu) ----
// MODE 0: C fp32 = acc + bias
// MODE 1: C fp32 = acc + bias + res
// MODE 2: (hi,lo) bf16 = gelu(acc + bias)
// MODE 3: QKV epilogue: c<1024 -> qk hi/lo [row][1024]; c>=1024 -> transposed V
//
// Staging: global_load_lds width=16 into linear [128][32]-short LDS.
// Swizzle (both-sides involution): 16B-block index g XOR'd with (row>>1)&3
// on BOTH the global source at stage time and the ds_read address.
// Read sets become 2-way bank aliasing (free); staging writes stay linear.
#define BM 128
#define BN 128
#define BK 32

#define MFMA16(a, b, c) __builtin_amdgcn_mfma_f32_16x16x32_bf16(a, b, c, 0, 0, 0)

template<int MODE>
__global__ __launch_bounds__(256)
void gemm3(const unsigned short* __restrict__ Ahi, const unsigned short* __restrict__ Alo,
           const unsigned short* __restrict__ Whi, const unsigned short* __restrict__ Wlo,
           const float* __restrict__ bias, const float* __restrict__ res,
           float* __restrict__ Cf, unsigned short* __restrict__ Chi,
           unsigned short* __restrict__ Clo, unsigned short* __restrict__ Vhi,
           unsigned short* __restrict__ Vlo, int M, int N, int K)
{
    __shared__ __align__(16) unsigned short LAh[4096];  // 128 rows x 32 shorts
    __shared__ __align__(16) unsigned short LAl[4096];
    __shared__ __align__(16) unsigned short LBh[4096];
    __shared__ __align__(16) unsigned short LBl[4096];

    const int t = threadIdx.x;
    const int lane = t & 63, w = t >> 6;
    const int wr = w >> 1, wc = w & 1;
    const int row0 = blockIdx.x * BM, col0 = blockIdx.y * BN;

    // staging coords: thread t covers (row t>>2 and t>>2+64, 16B block t&3)
    const int srow = t >> 2;
    const int sg   = t & 3;
    const int glog = sg ^ ((srow >> 1) & 3);   // same for srow and srow+64
    int ar0 = row0 + srow;      if (ar0 >= M) ar0 = M - 1;
    int ar1 = row0 + srow + 64; if (ar1 >= M) ar1 = M - 1;
    const size_t aoff0 = (size_t)ar0 * K + glog * 8;
    const size_t aoff1 = (size_t)ar1 * K + glog * 8;
    const size_t boff0 = (size_t)(col0 + srow) * K + glog * 8;
    const size_t boff1 = (size_t)(col0 + srow + 64) * K + glog * 8;
    const int ldso0 = t * 8;          // shorts (t*16 bytes)
    const int ldso1 = t * 8 + 2048;   // second half (rows 64..127)

    f32x4 acc[4][4];
    #pragma unroll
    for (int m = 0; m < 4; m++)
        #pragma unroll
        for (int n = 0; n < 4; n++) { acc[m][n][0]=0.f; acc[m][n][1]=0.f; acc[m][n][2]=0.f; acc[m][n][3]=0.f; }

    // fragment read coords
    const int c = lane & 15;
    const int g = lane >> 4;
    const int gs = (g ^ ((c >> 1) & 3)) * 8;   // swizzled 16B-block (in shorts)

    const int KT = K / BK;
    for (int kt = 0; kt < KT; kt++) {
        const int k0 = kt * BK;
        __syncthreads();   // protect LDS from previous iteration's readers
        gload16(Ahi + aoff0 + k0, &LAh[ldso0]);
        gload16(Ahi + aoff1 + k0, &LAh[ldso1]);
        gload16(Alo + aoff0 + k0, &LAl[ldso0]);
        gload16(Alo + aoff1 + k0, &LAl[ldso1]);
        gload16(Whi + boff0 + k0, &LBh[ldso0]);
        gload16(Whi + boff1 + k0, &LBh[ldso1]);
        gload16(Wlo + boff0 + k0, &LBl[ldso0]);
        gload16(Wlo + boff1 + k0, &LBl[ldso1]);
        __syncthreads();   // compiler drains vmcnt(0) before barrier

        short8v ah[4], al[4], bh[4], bl[4];
        #pragma unroll
        for (int m = 0; m < 4; m++) {
            int off = (wr * 64 + m * 16 + c) * 32 + gs;
            ah[m] = *(const short8v*)&LAh[off];
            al[m] = *(const short8v*)&LAl[off];
        }
        #pragma unroll
        for (int n = 0; n < 4; n++) {
            int off = (wc * 64 + n * 16 + c) * 32 + gs;
            bh[n] = *(const short8v*)&LBh[off];
            bl[n] = *(const short8v*)&LBl[off];
        }

        #pragma unroll
        for (int m = 0; m < 4; m++)
            #pragma unroll
            for (int n = 0; n < 4; n++) {
                acc[m][n] = MFMA16(ah[m], bh[n], acc[m][n]);
                acc[m][n] = MFMA16(al[m], bh[n], acc[m][n]);
                acc[m][n] = MFMA16(ah[m], bl[n], acc[m][n]);
            }
    }

    // epilogue: C/D layout col=lane&15, row=(lane>>4)*4+reg
    #pragma unroll
    for (int m = 0; m < 4; m++) {
        int rb = row0 + wr * 64 + m * 16 + (lane >> 4) * 4;
        #pragma unroll
        for (int n = 0; n < 4; n++) {
            int cc = col0 + wc * 64 + n * 16 + c;
            float bcol = bias[cc];
            #pragma unroll
            for (int r = 0; r < 4; r++) {
                int row = rb + r;
                if (row < M) {
                    float v = acc[m][n][r] + bcol;
                    if (MODE == 1) v += res[(size_t)row * N + cc];
                    if (MODE == 2) {
                        v = gelu_exact(v);
                        unsigned short hv, lv;
                        split_bf(v, hv, lv);
                        Chi[(size_t)row * N + cc] = hv;
                        Clo[(size_t)row * N + cc] = lv;
                    } else if (MODE == 3) {
                        unsigned short hv, lv;
                        split_bf(v, hv, lv);
                        if (cc < 1024) {
                            Chi[(size_t)row * 1024 + cc] = hv;
                            Clo[(size_t)row * 1024 + cc] = lv;
                        } else {
                            int da = cc - 1024, hh = da >> 7, dd = da & 127;
                            int bb = row / LC, ll = row - bb * LC;
                            size_t vi = ((size_t)((bb * HH + hh) * DH + dd)) * VTSTRIDE + ll;
                            Vhi[vi] = hv; Vlo[vi] = lv;
                        }
                    } else {
                        Cf[(size_t)row * N + cc] = v;
                    }
                }
            }
        }
    }
}

// ---------------- MFMA flash attention, split-bf16 ----------------
// qk:  [MROWS][1024] hi/lo (q cols 0..511, k cols 512..1023; head h at h*128)
// vt:  [(b*4+h)*128 + d][VTSTRIDE] hi/lo  (transposed V)
// out: [MROWS][512] hi/lo splits
#define AQT 64
#define AKT 32
#define NKT2 17
__global__ __launch_bounds__(256)
void attn_mfma(const unsigned short* __restrict__ qkhi, const unsigned short* __restrict__ qklo,
               const unsigned short* __restrict__ vthi, const unsigned short* __restrict__ vtlo,
               unsigned short* __restrict__ ohi, unsigned short* __restrict__ olo)
{
    __shared__ __align__(16) unsigned short SM[24064];
    #define KH(r,d) SM[(r)*136 + (d)]
    #define KL(r,d) SM[4352 + (r)*136 + (d)]
    #define VH(d,k) SM[8704 + (d)*40 + (k)]
    #define VL(d,k) SM[13824 + (d)*40 + (k)]
    #define PH(r,k) SM[18944 + (r)*40 + (k)]
    #define PL(r,k) SM[21504 + (r)*40 + (k)]
    #define OS(r,d) SM[(r)*136 + (d)]

    const int t = threadIdx.x;
    const int lane = t & 63, w = t >> 6;
    const int qt = blockIdx.x, h = blockIdx.y, b = blockIdx.z;
    const int q0 = qt * AQT;
    const int c = lane & 15, g = lane >> 4;
    const float SCALE = 0.08838834764831845f; // 1/sqrt(128)

    short8v qh[4], ql[4];
    {
        int qrow = b * LC + q0 + w * 16 + c;
        if (qrow > MROWS - 1) qrow = MROWS - 1;
        const unsigned short* bh_ = qkhi + (size_t)qrow * 1024 + h * DH;
        const unsigned short* bl_ = qklo + (size_t)qrow * 1024 + h * DH;
        #pragma unroll
        for (int ks = 0; ks < 4; ks++) {
            qh[ks] = *(const short8v*)(bh_ + ks * 32 + g * 8);
            ql[ks] = *(const short8v*)(bl_ + ks * 32 + g * 8);
        }
    }

    float m_r[4], l_r[4];
    #pragma unroll
    for (int r = 0; r < 4; r++) { m_r[r] = -INFINITY; l_r[r] = 0.f; }
    f32x4 acc_o[8];
    #pragma unroll
    for (int n = 0; n < 8; n++) { acc_o[n][0]=0.f; acc_o[n][1]=0.f; acc_o[n][2]=0.f; acc_o[n][3]=0.f; }

    const int skr = t >> 3, skd = (t & 7) * 16;
    const int svd = t >> 1, svk = (t & 1) * 16;

    for (int kt = 0; kt < NKT2; kt++) {
        __syncthreads();
        {
            int krow = b * LC + kt * AKT + skr;
            if (krow > MROWS - 1) krow = MROWS - 1;
            const unsigned short* kb  = qkhi + (size_t)krow * 1024 + 512 + h * DH + skd;
            const unsigned short* kbl = qklo + (size_t)krow * 1024 + 512 + h * DH + skd;
            *(short8v*)&KH(skr, skd)     = *(const short8v*)kb;
            *(short8v*)&KH(skr, skd + 8) = *(const short8v*)(kb + 8);
            *(short8v*)&KL(skr, skd)     = *(const short8v*)kbl;
            *(short8v*)&KL(skr, skd + 8) = *(const short8v*)(kbl + 8);
            const unsigned short* vb  = vthi + ((size_t)((b * HH + h) * DH + svd)) * VTSTRIDE + kt * AKT + svk;
            const unsigned short* vbl = vtlo + ((size_t)((b * HH + h) * DH + svd)) * VTSTRIDE + kt * AKT + svk;
            *(short8v*)&VH(svd, svk)     = *(const short8v*)vb;
            *(short8v*)&VH(svd, svk + 8) = *(const short8v*)(vb + 8);
            *(short8v*)&VL(svd, svk)     = *(const short8v*)vbl;
            *(short8v*)&VL(svd, svk + 8) = *(const short8v*)(vbl + 8);
        }
        __syncthreads();

        f32x4 s[2];
        s[0][0]=s[0][1]=s[0][2]=s[0][3]=0.f;
        s[1][0]=s[1][1]=s[1][2]=s[1][3]=0.f;
        #pragma unroll
        for (int n = 0; n < 2; n++) {
            #pragma unroll
            for (int ks = 0; ks < 4; ks++) {
                short8v kh = *(const short8v*)&KH(n * 16 + c, ks * 32 + g * 8);
                short8v kl = *(const short8v*)&KL(n * 16 + c, ks * 32 + g * 8);
                s[n] = MFMA16(qh[ks], kh, s[n]);
                s[n] = MFMA16(ql[ks], kh, s[n]);
                s[n] = MFMA16(qh[ks], kl, s[n]);
            }
        }

        #pragma unroll
        for (int n = 0; n < 2; n++) {
            bool oob = (kt * 32 + n * 16 + c) >= LC;
            #pragma unroll
            for (int r = 0; r < 4; r++) {
                float sv = s[n][r] * SCALE;
                s[n][r] = oob ? -INFINITY : sv;
            }
        }

        float alpha[4], p0v[4], p1v[4];
        #pragma unroll
        for (int r = 0; r < 4; r++) {
            float rm = fmaxf(s[0][r], s[1][r]);
            #pragma unroll
            for (int off = 1; off < 16; off <<= 1) rm = fmaxf(rm, __shfl_xor(rm, off));
            float mn = fmaxf(m_r[r], rm);
            float p0 = expf(s[0][r] - mn);
            float p1 = expf(s[1][r] - mn);
            float ts = p0 + p1;
            #pragma unroll
            for (int off = 1; off < 16; off <<= 1) ts += __shfl_xor(ts, off);
            float al = expf(m_r[r] - mn);
            m_r[r] = mn;
            l_r[r] = al * l_r[r] + ts;
            alpha[r] = al;
            p0v[r] = p0; p1v[r] = p1;
        }

        #pragma unroll
        for (int n = 0; n < 8; n++)
            #pragma unroll
            for (int r = 0; r < 4; r++) acc_o[n][r] *= alpha[r];

        #pragma unroll
        for (int r = 0; r < 4; r++) {
            unsigned short ph, pl;
            split_bf(p0v[r], ph, pl);
            PH(w * 16 + g * 4 + r, c) = ph;
            PL(w * 16 + g * 4 + r, c) = pl;
            split_bf(p1v[r], ph, pl);
            PH(w * 16 + g * 4 + r, 16 + c) = ph;
            PL(w * 16 + g * 4 + r, 16 + c) = pl;
        }
        __syncthreads();

        short8v pah = *(const short8v*)&PH(w * 16 + c, g * 8);
        short8v pal = *(const short8v*)&PL(w * 16 + c, g * 8);
        #pragma unroll
        for (int n = 0; n < 8; n++) {
            short8v vh = *(const short8v*)&VH(n * 16 + c, g * 8);
            short8v vl = *(const short8v*)&VL(n * 16 + c, g * 8);
            acc_o[n] = MFMA16(pah, vh, acc_o[n]);
            acc_o[n] = MFMA16(pal, vh, acc_o[n]);
            acc_o[n] = MFMA16(pah, vl, acc_o[n]);
        }
    }

    float inv[4];
    #pragma unroll
    for (int r = 0; r < 4; r++) inv[r] = 1.0f / l_r[r];

    const int orow = t >> 2, oc0 = (t & 3) * 32;
    #pragma unroll
    for (int pass = 0; pass < 2; pass++) {
        __syncthreads();
        #pragma unroll
        for (int n = 0; n < 8; n++)
            #pragma unroll
            for (int r = 0; r < 4; r++) {
                float v = acc_o[n][r] * inv[r];
                unsigned short hv, lv;
                split_bf(v, hv, lv);
                OS(w * 16 + g * 4 + r, n * 16 + c) = pass ? lv : hv;
            }
        __syncthreads();
        int grow = q0 + orow;
        if (grow < LC) {
            unsigned short* dst = (pass ? olo : ohi) + ((size_t)(b * LC + grow)) * DD + h * DH + oc0;
            #pragma unroll
            for (int u = 0; u < 4; u++)
                *(short8v*)(dst + u * 8) = *(const short8v*)&OS(orow, oc0 + u * 8);
        }
    }
    #undef KH
    #undef KL
    #undef VH
    #undef VL
    #undef PH
    #undef PL
    #undef OS
}

// ---------------- LayerNorm over 512, writes fp32 + splits ----------------
__global__ __launch_bounds__(128)
void ln512(const float* __restrict__ X, const float* __restrict__ g,
           const float* __restrict__ bb, float* __restrict__ Y,
           unsigned short* __restrict__ Yhi, unsigned short* __restrict__ Ylo)
{
    __shared__ float red[2];
    int row = blockIdx.x, t = threadIdx.x;
    const float* x = X + (size_t)row * DD;
    float4 v = *(const float4*)(x + t * 4);
    float s = v.x + v.y + v.z + v.w;
    #pragma unroll
    for (int off = 1; off < 64; off <<= 1) s += __shfl_xor(s, off);
    if ((t & 63) == 0) red[t >> 6] = s;
    __syncthreads();
    float mean = (red[0] + red[1]) * (1.0f / 512.0f);
    __syncthreads();
    float d0 = v.x - mean, d1 = v.y - mean, d2 = v.z - mean, d3 = v.w - mean;
    float s2 = d0 * d0 + d1 * d1 + d2 * d2 + d3 * d3;
    #pragma unroll
    for (int off = 1; off < 64; off <<= 1) s2 += __shfl_xor(s2, off);
    if ((t & 63) == 0) red[t >> 6] = s2;
    __syncthreads();
    float var = (red[0] + red[1]) * (1.0f / 512.0f);
    float rstd = 1.0f / sqrtf(var + 1e-5f);
    float4 gv = *(const float4*)(g + t * 4);
    float4 bv = *(const float4*)(bb + t * 4);
    float4 ov;
    ov.x = d0 * rstd * gv.x + bv.x;
    ov.y = d1 * rstd * gv.y + bv.y;
    ov.z = d2 * rstd * gv.z + bv.z;
    ov.w = d3 * rstd * gv.w + bv.w;
    size_t o = (size_t)row * DD + t * 4;
    *(float4*)(Y + o) = ov;
    unsigned short hs[4], ls[4];
    split_bf(ov.x, hs[0], ls[0]); split_bf(ov.y, hs[1], ls[1]);
    split_bf(ov.z, hs[2], ls[2]); split_bf(ov.w, hs[3], ls[3]);
    ((uint2*)Yhi)[o >> 2] = make_uint2((unsigned)hs[0] | ((unsigned)hs[1]<<16),
                                       (unsigned)hs[2] | ((unsigned)hs[3]<<16));
    ((uint2*)Ylo)[o >> 2] = make_uint2((unsigned)ls[0] | ((unsigned)ls[1]<<16),
                                       (unsigned)ls[2] | ((unsigned)ls[3]<<16));
}

// ---------------- mean over L (two-pass) ----------------
__global__ __launch_bounds__(128)
void mean_part(const float* __restrict__ query, float* __restrict__ part)
{
    int b = blockIdx.x, ch = blockIdx.y, t = threadIdx.x;
    const float* base = query + ((size_t)b * LQ + ch * 64) * DD + t * 4;
    float ax = 0.f, ay = 0.f, az = 0.f, aw = 0.f;
    for (int l = 0; l < 64; l++) {
        float4 v = *(const float4*)(base + (size_t)l * DD);
        ax += v.x; ay += v.y; az += v.z; aw += v.w;
    }
    *(float4*)(part + ((size_t)(b * 8 + ch)) * DD + t * 4) = make_float4(ax, ay, az, aw);
}

__global__ __launch_bounds__(128)
void mean_fin(const float* __restrict__ part, float* __restrict__ xm)
{
    int b = blockIdx.x, t = threadIdx.x;
    float ax = 0.f, ay = 0.f, az = 0.f, aw = 0.f;
    #pragma unroll
    for (int ch = 0; ch < 8; ch++) {
        float4 v = *(const float4*)(part + ((size_t)(b * 8 + ch)) * DD + t * 4);
        ax += v.x; ay += v.y; az += v.z; aw += v.w;
    }
    *(float4*)(xm + (size_t)b * DD + t * 4) =
        make_float4(ax * (1.f/512.f), ay * (1.f/512.f), az * (1.f/512.f), aw * (1.f/512.f));
}

static __device__ __forceinline__ float block128_sum(float x, float* red, int t) {
    #pragma unroll
    for (int off = 1; off < 64; off <<= 1) x += __shfl_xor(x, off);
    if ((t & 63) == 0) red[t >> 6] = x;
    __syncthreads();
    float r = red[0] + red[1];
    __syncthreads();
    return r;
}

// ---------------- proj + LN -> q_repr ----------------
__global__ __launch_bounds__(128)
void proj_ln(const float* __restrict__ h, const float* __restrict__ pW, const float* __restrict__ pb,
             const float* __restrict__ pg, const float* __restrict__ pbb, float* __restrict__ q_repr)
{
    __shared__ float xs[DD];
    __shared__ float red[2];
    int b = blockIdx.x, t = threadIdx.x;
    *(float4*)&xs[t * 4] = *(const float4*)(h + (size_t)(b * LC) * DD + t * 4);
    __syncthreads();
    const float* w = pW + (size_t)t * DD;
    float acc = pb[t];
    for (int k = 0; k < DD; k += 4) {
        float4 a = *(const float4*)&xs[k];
        float4 ww = *(const float4*)(w + k);
        acc += a.x * ww.x + a.y * ww.y + a.z * ww.z + a.w * ww.w;
    }
    float mean = block128_sum(acc, red, t) * (1.f / 128.f);
    float dx = acc - mean;
    float var = block128_sum(dx * dx, red, t) * (1.f / 128.f);
    float rstd = 1.0f / sqrtf(var + 1e-5f);
    q_repr[(size_t)b * DRr + t] = dx * rstd * pg[t] + pbb[t];
}

// ---------------- value encoder (fused) -> q_val ----------------
__global__ __launch_bounds__(128)
void venc(const float* __restrict__ xm, const float* __restrict__ vW1, const float* __restrict__ vb1,
          const float* __restrict__ vg, const float* __restrict__ vb,
          const float* __restrict__ vW2, const float* __restrict__ vb2,
          float* __restrict__ q_val)
{
    __shared__ float xs[DD];
    __shared__ float hg[DRr];
    __shared__ float red[2];
    int b = blockIdx.x, t = threadIdx.x;
    *(float4*)&xs[t * 4] = *(const float4*)(xm + (size_t)b * DD + t * 4);
    __syncthreads();
    const float* w = vW1 + (size_t)t * DD;
    float acc = vb1[t];
    for (int k = 0; k < DD; k += 4) {
        float4 a = *(const float4*)&xs[k];
        float4 ww = *(const float4*)(w + k);
        acc += a.x * ww.x + a.y * ww.y + a.z * ww.z + a.w * ww.w;
    }
    float mean = block128_sum(acc, red, t) * (1.f / 128.f);
    float dx = acc - mean;
    float var = block128_sum(dx * dx, red, t) * (1.f / 128.f);
    float rstd = 1.0f / sqrtf(var + 1e-5f);
    float hn = dx * rstd * vg[t] + vb[t];
    hg[t] = gelu_exact(hn);
    __syncthreads();
    const float* w2 = vW2 + (size_t)t * DRr;
    float acc2 = vb2[t];
    for (int k = 0; k < DRr; k += 4) {
        float4 a = *(const float4*)&hg[k];
        float4 ww = *(const float4*)(w2 + k);
        acc2 += a.x * ww.x + a.y * ww.y + a.z * ww.z + a.w * ww.w;
    }
    q_val[(size_t)b * DRr + t] = acc2;
}

// ---------------- combine ----------------
__global__ void combine_qk(const float* __restrict__ qr, const float* __restrict__ qv,
                           const float* __restrict__ swp, float* __restrict__ qk)
{
    int i = blockIdx.x * blockDim.x + threadIdx.x;
    if (i < B_ * DRr) {
        float sw = swp[0];
        qk[i] = sw * qr[i] + (1.f - sw) * qv[i];
    }
}

// ---------------- sim ----------------
#define SIMCH 10
__global__ __launch_bounds__(256)
void sim_kernel(const float* __restrict__ qk, const float* __restrict__ mkeys, float* __restrict__ sim)
{
    __shared__ float qs[DRr];
    int b = blockIdx.x, ch = blockIdx.y, t = threadIdx.x;
    if (t < DRr) qs[t] = qk[(size_t)b * DRr + t];
    __syncthreads();
    float qn = 0.f;
    #pragma unroll 8
    for (int i = 0; i < DRr; i++) qn += qs[i] * qs[i];
    int n0 = ch * (NKEYS / SIMCH), n1 = n0 + (NKEYS / SIMCH);
    for (int n = n0 + t; n < n1; n += 256) {
        const float* kr = mkeys + (size_t)n * DRr;
        float dot = 0.f, kn = 0.f;
        #pragma unroll 8
        for (int i = 0; i < DRr; i += 4) {
            float4 kv = *(const float4*)(kr + i);
            dot += qs[i] * kv.x + qs[i + 1] * kv.y + qs[i + 2] * kv.z + qs[i + 3] * kv.w;
            kn  += kv.x * kv.x + kv.y * kv.y + kv.z * kv.z + kv.w * kv.w;
        }
        float d = qn - 2.f * dot + kn;
        sim[(size_t)b * NKEYS + n] = -d / 0.1f;
    }
}

// ---------------- top-k (jax semantics: value desc, ties -> lower index) ----
static __device__ __forceinline__ void topk_insert(float* v, int* id, float x, int n) {
    bool better = (x > v[TOPK - 1]) || (x == v[TOPK - 1] && n < id[TOPK - 1]);
    if (better) {
        v[TOPK - 1] = x; id[TOPK - 1] = n;
        #pragma unroll
        for (int k = TOPK - 1; k > 0; k--) {
            bool sw = (v[k] > v[k - 1]) || (v[k] == v[k - 1] && id[k] < id[k - 1]);
            if (!sw) break;
            float tv = v[k]; v[k] = v[k - 1]; v[k - 1] = tv;
            int ti = id[k]; id[k] = id[k - 1]; id[k - 1] = ti;
        }
    }
}

__global__ __launch_bounds__(256)
void topk_kernel(const float* __restrict__ sim, int* __restrict__ topidx, float* __restrict__ wout)
{
    __shared__ float sv[256][TOPK];
    __shared__ int   si[256][TOPK];
    int b = blockIdx.x, t = threadIdx.x;
    float v[TOPK]; int id[TOPK];
    #pragma unroll
    for (int k = 0; k < TOPK; k++) { v[k] = -INFINITY; id[k] = 0x7fffffff; }
    for (int n = t; n < NKEYS; n += 256) {
        topk_insert(v, id, sim[(size_t)b * NKEYS + n], n);
    }
    #pragma unroll
    for (int k = 0; k < TOPK; k++) { sv[t][k] = v[k]; si[t][k] = id[k]; }
    for (int strd = 128; strd >= 1; strd >>= 1) {
        __syncthreads();
        if (t < strd) {
            #pragma unroll
            for (int k = 0; k < TOPK; k++) topk_insert(v, id, sv[t + strd][k], si[t + strd][k]);
            #pragma unroll
            for (int k = 0; k < TOPK; k++) { sv[t][k] = v[k]; si[t][k] = id[k]; }
        }
    }
    if (t == 0) {
        float m = v[0];
        float e[TOPK]; float sum = 0.f;
        #pragma unroll
        for (int k = 0; k < TOPK; k++) { e[k] = expf(v[k] - m); sum += e[k]; }
        #pragma unroll
        for (int k = 0; k < TOPK; k++) {
            wout[(size_t)b * TOPK + k] = e[k] / sum;
            topidx[b * TOPK + k] = id[k];
        }
    }
}

// ---------------- gather ----------------
__global__ __launch_bounds__(128)
void gather_kernel(const float* __restrict__ mv, const int* __restrict__ topidx, float* __restrict__ out)
{
    int blk = blockIdx.x;
    int b = blk / (TOPK * PP);
    int rem = blk - b * (TOPK * PP);
    int k = rem / PP;
    int p = rem - k * PP;
    int idx = topidx[b * TOPK + k];
    const float4* src = (const float4*)(mv + ((size_t)idx * PP + p) * DD);
    float4* dst = (float4*)(out + (size_t)blk * DD);
    dst[threadIdx.x] = src[threadIdx.x];
}

// ---------------- launch ----------------
extern "C" void kernel_launch(void* const* d_in, const int* in_sizes, int n_in,
                              void* d_out, int out_size, void* d_ws, size_t ws_size,
                              hipStream_t stream) {
    const float* query = (const float*)d_in[0];
    const float* mkeys = (const float*)d_in[1];
    const float* mvals = (const float*)d_in[2];
    const float* cls   = (const float*)d_in[3];
    const float* Wqkv  = (const float*)d_in[4];
    const float* bqkv  = (const float*)d_in[5];
    const float* Wo    = (const float*)d_in[6];
    const float* bo    = (const float*)d_in[7];
    const float* ln1g  = (const float*)d_in[8];
    const float* ln1b  = (const float*)d_in[9];
    const float* W1    = (const float*)d_in[10];
    const float* b1    = (const float*)d_in[11];
    const float* W2    = (const float*)d_in[12];
    const float* b2    = (const float*)d_in[13];
    const float* ln2g  = (const float*)d_in[14];
    const float* ln2b  = (const float*)d_in[15];
    const float* pW    = (const float*)d_in[16];
    const float* pb    = (const float*)d_in[17];
    const float* pg    = (const float*)d_in[18];
    const float* pbb   = (const float*)d_in[19];
    const float* vW1   = (const float*)d_in[20];
    const float* vb1   = (const float*)d_in[21];
    const float* vg    = (const float*)d_in[22];
    const float* vb    = (const float*)d_in[23];
    const float* vW2   = (const float*)d_in[24];
    const float* vb2   = (const float*)d_in[25];
    const float* swp   = (const float*)d_in[26];
    float* out = (float*)d_out;

    // ---- workspace layout ----
    float* ws    = (float*)d_ws;
    float* h     = ws;                                   // MROWS*512 fp32 residual
    float* preln = h + (size_t)MROWS * DD;               // MROWS*512 fp32
    unsigned short* h_hi  = (unsigned short*)(preln + (size_t)MROWS * DD);
    unsigned short* h_lo  = h_hi  + (size_t)MROWS * DD;
    unsigned short* mid_hi = h_lo + (size_t)MROWS * DD;  // MROWS*1024
    unsigned short* mid_lo = mid_hi + (size_t)MROWS * 1024;
    unsigned short* qkhi  = mid_lo + (size_t)MROWS * 1024;
    unsigned short* qklo  = qkhi  + (size_t)MROWS * 1024;
    unsigned short* vthi  = qklo  + (size_t)MROWS * 1024;   // 32768*VTSTRIDE
    unsigned short* vtlo  = vthi  + (size_t)32768 * VTSTRIDE;
    unsigned short* wq_hi = vtlo  + (size_t)32768 * VTSTRIDE;
    unsigned short* wq_lo = wq_hi + (size_t)2 * 1536 * DD;
    unsigned short* wo_hi = wq_lo + (size_t)2 * 1536 * DD;
    unsigned short* wo_lo = wo_hi + (size_t)2 * DD * DD;
    unsigned short* w1_hi = wo_lo + (size_t)2 * DD * DD;
    unsigned short* w1_lo = w1_hi + (size_t)2 * 1024 * DD;
    unsigned short* w2_hi = w1_lo + (size_t)2 * 1024 * DD;
    unsigned short* w2_lo = w2_hi + (size_t)2 * DD * 1024;
    float* xm   = (float*)(w2_lo + (size_t)2 * DD * 1024);
    float* qval = xm   + (size_t)B_ * DD;
    float* qrep = qval + (size_t)B_ * DRr;
    float* qkc  = qrep + (size_t)B_ * DRr;
    float* simb = qkc  + (size_t)B_ * DRr;
    int*   tidx = (int*)(simb + (size_t)B_ * NKEYS);
    float* mpart = (float*)(tidx + 512);                 // 64*8*512 fp32
    (void)ws_size; (void)in_sizes; (void)n_in; (void)out_size;

    // ---- weight splits ----
    {
        int n4;
        n4 = 2 * 1536 * DD / 4;
        split_kernel<<<(n4 + 255) / 256, 256, 0, stream>>>(Wqkv, wq_hi, wq_lo, n4);
        n4 = 2 * DD * DD / 4;
        split_kernel<<<(n4 + 255) / 256, 256, 0, stream>>>(Wo, wo_hi, wo_lo, n4);
        n4 = 2 * 1024 * DD / 4;
        split_kernel<<<(n4 + 255) / 256, 256, 0, stream>>>(W1, w1_hi, w1_lo, n4);
        n4 = 2 * DD * 1024 / 4;
        split_kernel<<<(n4 + 255) / 256, 256, 0, stream>>>(W2, w2_hi, w2_lo, n4);
    }

    concat_cls<<<MROWS, 128, 0, stream>>>(query, cls, h, h_hi, h_lo);

    for (int l = 0; l < 2; l++) {
        const unsigned short* wqh = wq_hi + (size_t)l * 1536 * DD;
        const unsigned short* wql = wq_lo + (size_t)l * 1536 * DD;
        const unsigned short* woh = wo_hi + (size_t)l * DD * DD;
        const unsigned short* wol = wo_lo + (size_t)l * DD * DD;
        const unsigned short* w1h = w1_hi + (size_t)l * 1024 * DD;
        const unsigned short* w1l = w1_lo + (size_t)l * 1024 * DD;
        const unsigned short* w2h = w2_hi + (size_t)l * DD * 1024;
        const unsigned short* w2l = w2_lo + (size_t)l * DD * 1024;
        const float* bq  = bqkv + (size_t)l * 1536;
        const float* bol = bo   + (size_t)l * DD;
        const float* g1  = ln1g + (size_t)l * DD;
        const float* be1 = ln1b + (size_t)l * DD;
        const float* b1l = b1   + (size_t)l * 1024;
        const float* b2l = b2   + (size_t)l * DD;
        const float* g2  = ln2g + (size_t)l * DD;
        const float* be2 = ln2b + (size_t)l * DD;

        // QKV -> qk splits + transposed V splits
        gemm3<3><<<dim3(257, 12), 256, 0, stream>>>(h_hi, h_lo, wqh, wql, bq, nullptr,
                                                    nullptr, qkhi, qklo, vthi, vtlo,
                                                    MROWS, 1536, DD);
        // MFMA attention -> h_hi/h_lo (attn-out splits)
        attn_mfma<<<dim3(9, HH, B_), 256, 0, stream>>>(qkhi, qklo, vthi, vtlo, h_hi, h_lo);
        // Wo + residual -> preln fp32
        gemm3<1><<<dim3(257, 4), 256, 0, stream>>>(h_hi, h_lo, woh, wol, bol, h,
                                                   preln, nullptr, nullptr, nullptr, nullptr,
                                                   MROWS, DD, DD);
        ln512<<<MROWS, 128, 0, stream>>>(preln, g1, be1, h, h_hi, h_lo);
        // FFN1 + gelu -> mid splits
        gemm3<2><<<dim3(257, 8), 256, 0, stream>>>(h_hi, h_lo, w1h, w1l, b1l, nullptr,
                                                   nullptr, mid_hi, mid_lo, nullptr, nullptr,
                                                   MROWS, 1024, DD);
        // FFN2 + residual -> preln fp32
        gemm3<1><<<dim3(257, 4), 256, 0, stream>>>(mid_hi, mid_lo, w2h, w2l, b2l, h,
                                                   preln, nullptr, nullptr, nullptr, nullptr,
                                                   MROWS, DD, 1024);
        ln512<<<MROWS, 128, 0, stream>>>(preln, g2, be2, h, h_hi, h_lo);
    }

    proj_ln<<<B_, 128, 0, stream>>>(h, pW, pb, pg, pbb, qrep);
    mean_part<<<dim3(B_, 8), 128, 0, stream>>>(query, mpart);
    mean_fin<<<B_, 128, 0, stream>>>(mpart, xm);
    venc<<<B_, 128, 0, stream>>>(xm, vW1, vb1, vg, vb, vW2, vb2, qval);
    combine_qk<<<(B_ * DRr + 255) / 256, 256, 0, stream>>>(qrep, qval, swp, qkc);
    sim_kernel<<<dim3(B_, SIMCH), 256, 0, stream>>>(qkc, mkeys, simb);
    topk_kernel<<<B_, 256, 0, stream>>>(simb, tidx, out + (size_t)B_ * TOPK * PP * DD);
    gather_kernel<<<B_ * TOPK * PP, 128, 0, stream>>>(mvals, tidx, out);
}

// Round 5
// 2429.959 us; speedup vs baseline: 2.3838x; 1.0284x over previous
//
#include <hip/hip_runtime.h>
#include <math.h>

// Problem dims
#define B_    64
#define LQ    512
#define LC    513          // with CLS
#define DD    512
#define HH    4
#define DH    128
#define DRr   128
#define NKEYS 10000
#define PP    96
#define TOPK  5
#define MROWS (B_*LC)      // 32832
#define VTSTRIDE 544       // padded LC for transposed V (multiple of 16)

typedef __attribute__((ext_vector_type(8))) short short8v;
typedef __attribute__((ext_vector_type(4))) float f32x4;
typedef __attribute__((ext_vector_type(16))) float f32x16;

static __device__ __forceinline__ float gelu_exact(float x) {
    return 0.5f * x * (1.0f + erff(x * 0.70710678118654752440f));
}

static __device__ __forceinline__ unsigned short f2bf(float x) {
    union { float f; unsigned u; } v; v.f = x;
    unsigned r = v.u + 0x7fff + ((v.u >> 16) & 1);
    return (unsigned short)(r >> 16);
}
static __device__ __forceinline__ float bf2f(unsigned short h) {
    union { float f; unsigned u; } v; v.u = ((unsigned)h) << 16;
    return v.f;
}
static __device__ __forceinline__ void split_bf(float x, unsigned short& hi, unsigned short& lo) {
    hi = f2bf(x);
    lo = f2bf(x - bf2f(hi));
}

// async global->LDS, 16B per lane. LDS dest must be linear: base + lane*16.
static __device__ __forceinline__ void gload16(const unsigned short* g, unsigned short* l) {
    __builtin_amdgcn_global_load_lds(
        (const __attribute__((address_space(1))) unsigned*)g,
        (__attribute__((address_space(3))) unsigned*)l, 16, 0, 0);
}

// ---------------- generic fp32 -> (hi,lo) bf16 split ----------------
__global__ __launch_bounds__(256)
void split_kernel(const float* __restrict__ x, unsigned short* __restrict__ hi,
                  unsigned short* __restrict__ lo, int n4)
{
    int i = blockIdx.x * blockDim.x + threadIdx.x;
    if (i >= n4) return;
    float4 v = ((const float4*)x)[i];
    unsigned short h0,h1,h2,h3,l0,l1,l2,l3;
    split_bf(v.x,h0,l0); split_bf(v.y,h1,l1); split_bf(v.z,h2,l2); split_bf(v.w,h3,l3);
    ((uint2*)hi)[i] = make_uint2((unsigned)h0 | ((unsigned)h1 << 16), (unsigned)h2 | ((unsigned)h3 << 16));
    ((uint2*)lo)[i] = make_uint2((unsigned)l0 | ((unsigned)l1 << 16), (unsigned)l2 | ((unsigned)l3 << 16));
}

// ---------------- concat cls + query -> h (fp32 + splits) ----------------
__global__ __launch_bounds__(128)
void concat_cls(const float* __restrict__ query, const float* __restrict__ cls,
                float* __restrict__ h, unsigned short* __restrict__ h_hi,
                unsigned short* __restrict__ h_lo)
{
    int row = blockIdx.x;
    int t = threadIdx.x;
    int b = row / LC, r = row - b * LC;
    const float* src = (r == 0) ? cls : (query + ((size_t)b * LQ + (r - 1)) * DD);
    float4 v = *(const float4*)(src + t * 4);
    *(float4*)(h + (size_t)row * DD + t * 4) = v;
    unsigned short hs[4], ls[4];
    split_bf(v.x, hs[0], ls[0]); split_bf(v.y, hs[1], ls[1]);
    split_bf(v.z, hs[2], ls[2]); split_bf(v.w, hs[3], ls[3]);
    size_t o = (size_t)row * DD + t * 4;
    ((uint2*)(h_hi))[o >> 2] = make_uint2((unsigned)hs[0] | ((unsigned)hs[1]<<16),
                                          (unsigned)hs[2] | ((unsigned)hs[3]<<16));
    ((uint2*)(h_lo))[o >> 2] = make_uint2((unsigned)ls[0] | ((unsigned)ls[1]<<16),
                                          (unsigned)ls[2] | ((unsigned)ls[3]<<16));
}

// ---------------- split-bf16 MFMA GEMM (32x32x16): C = A @ W^T + ... -------
// MODE 0: C fp32 = acc + bias
// MODE 1: C fp32 = acc + bias + res
// MODE 2: (hi,lo) bf16 = gelu(acc + bias)
// MODE 3: QKV epilogue: c<1024 -> qk hi/lo [row][1024]; c>=1024 -> transposed
//         V, interleaved (hi | lo<<16) uint at vtx[ddidx*VTSTRIDE + ll]
//
// Staging: global_load_lds w16 into linear [128 rows][32 shorts] LDS.
// Swizzle involution: 16B-block bp = bl ^ (row&3), applied on the global
// source at stage time and on the ds_read address. Slot histogram over a
// wave's 64 b128 reads: uniform 8 lanes per 16B-slot (b128 floor).
#define BM 128
#define BN 128
#define BK 32

#define MFMA32(a, b, c) __builtin_amdgcn_mfma_f32_32x32x16_bf16(a, b, c, 0, 0, 0)

template<int MODE>
__global__ __launch_bounds__(256)
void gemm3(const unsigned short* __restrict__ Ahi, const unsigned short* __restrict__ Alo,
           const unsigned short* __restrict__ Whi, const unsigned short* __restrict__ Wlo,
           const float* __restrict__ bias, const float* __restrict__ res,
           float* __restrict__ Cf, unsigned short* __restrict__ Chi,
           unsigned short* __restrict__ Clo, unsigned* __restrict__ Vix,
           int M, int N, int K)
{
    __shared__ __align__(16) unsigned short LAh[4096];  // 128 rows x 32 shorts
    __shared__ __align__(16) unsigned short LAl[4096];
    __shared__ __align__(16) unsigned short LBh[4096];
    __shared__ __align__(16) unsigned short LBl[4096];

    const int t = threadIdx.x;
    const int lane = t & 63, w = t >> 6;
    const int wr = w >> 1, wc = w & 1;
    const int row0 = blockIdx.x * BM, col0 = blockIdx.y * BN;

    // staging coords: thread t covers (rows t>>2 and t>>2+64, 16B block t&3)
    const int srow = t >> 2;
    const int sg   = t & 3;
    const int glog = sg ^ (srow & 3);   // same for srow and srow+64
    int ar0 = row0 + srow;      if (ar0 >= M) ar0 = M - 1;
    int ar1 = row0 + srow + 64; if (ar1 >= M) ar1 = M - 1;
    const size_t aoff0 = (size_t)ar0 * K + glog * 8;
    const size_t aoff1 = (size_t)ar1 * K + glog * 8;
    const size_t boff0 = (size_t)(col0 + srow) * K + glog * 8;
    const size_t boff1 = (size_t)(col0 + srow + 64) * K + glog * 8;
    const int ldso0 = t * 8;          // shorts (t*16 bytes)
    const int ldso1 = t * 8 + 2048;

    f32x16 acc[2][2];
    #pragma unroll
    for (int m = 0; m < 2; m++)
        #pragma unroll
        for (int n = 0; n < 2; n++)
            #pragma unroll
            for (int i = 0; i < 16; i++) acc[m][n][i] = 0.f;

    // fragment read coords: row-in-tile = lane&31, k-group = lane>>5
    const int cl = lane & 31;
    const int kg = lane >> 5;
    const int cl3 = cl & 3;

    const int KT = K / BK;
    for (int kt = 0; kt < KT; kt++) {
        const int k0 = kt * BK;
        __syncthreads();
        gload16(Ahi + aoff0 + k0, &LAh[ldso0]);
        gload16(Ahi + aoff1 + k0, &LAh[ldso1]);
        gload16(Alo + aoff0 + k0, &LAl[ldso0]);
        gload16(Alo + aoff1 + k0, &LAl[ldso1]);
        gload16(Whi + boff0 + k0, &LBh[ldso0]);
        gload16(Whi + boff1 + k0, &LBh[ldso1]);
        gload16(Wlo + boff0 + k0, &LBl[ldso0]);
        gload16(Wlo + boff1 + k0, &LBl[ldso1]);
        __syncthreads();

        #pragma unroll
        for (int ks = 0; ks < 2; ks++) {
            const int blkswz = ((ks * 2 + kg) ^ cl3) * 8;
            short8v ah[2], al[2], bh[2], bl[2];
            #pragma unroll
            for (int m = 0; m < 2; m++) {
                int off = (wr * 64 + m * 32 + cl) * 32 + blkswz;
                ah[m] = *(const short8v*)&LAh[off];
                al[m] = *(const short8v*)&LAl[off];
            }
            #pragma unroll
            for (int n = 0; n < 2; n++) {
                int off = (wc * 64 + n * 32 + cl) * 32 + blkswz;
                bh[n] = *(const short8v*)&LBh[off];
                bl[n] = *(const short8v*)&LBl[off];
            }
            #pragma unroll
            for (int m = 0; m < 2; m++)
                #pragma unroll
                for (int n = 0; n < 2; n++) {
                    acc[m][n] = MFMA32(ah[m], bh[n], acc[m][n]);
                    acc[m][n] = MFMA32(al[m], bh[n], acc[m][n]);
                    acc[m][n] = MFMA32(ah[m], bl[n], acc[m][n]);
                }
        }
    }

    // epilogue: C/D layout col=lane&31, row=(reg&3)+8*(reg>>2)+4*(lane>>5)
    #pragma unroll
    for (int m = 0; m < 2; m++) {
        const int rb = row0 + wr * 64 + m * 32 + 4 * kg;
        #pragma unroll
        for (int n = 0; n < 2; n++) {
            const int cc = col0 + wc * 64 + n * 32 + cl;
            const float bcol = bias[cc];
            #pragma unroll
            for (int q = 0; q < 4; q++) {
                #pragma unroll
                for (int r = 0; r < 4; r++) {
                    int row = rb + 8 * q + r;
                    if (row < M) {
                        float v = acc[m][n][q * 4 + r] + bcol;
                        if (MODE == 1) v += res[(size_t)row * N + cc];
                        if (MODE == 2) {
                            v = gelu_exact(v);
                            unsigned short hv, lv;
                            split_bf(v, hv, lv);
                            Chi[(size_t)row * N + cc] = hv;
                            Clo[(size_t)row * N + cc] = lv;
                        } else if (MODE == 3) {
                            unsigned short hv, lv;
                            split_bf(v, hv, lv);
                            if (cc < 1024) {
                                Chi[(size_t)row * 1024 + cc] = hv;
                                Clo[(size_t)row * 1024 + cc] = lv;
                            } else {
                                int da = cc - 1024, hh = da >> 7, dd = da & 127;
                                int bb = row / LC, ll = row - bb * LC;
                                size_t vi = ((size_t)((bb * HH + hh) * DH + dd)) * VTSTRIDE + ll;
                                Vix[vi] = (unsigned)hv | ((unsigned)lv << 16);
                            }
                        } else {
                            Cf[(size_t)row * N + cc] = v;
                        }
                    }
                }
            }
        }
    }
}

// ---------------- MFMA flash attention, split-bf16 ----------------
// qk:  [MROWS][1024] hi/lo (q cols 0..511, k cols 512..1023; head h at h*128)
// vtx: [(b*4+h)*128 + d][VTSTRIDE] uint (hi | lo<<16)  (transposed V)
// out: [MROWS][512] hi/lo splits
#define AQT 64
#define AKT 32
#define NKT2 17
#define MFMA16(a, b, c) __builtin_amdgcn_mfma_f32_16x16x32_bf16(a, b, c, 0, 0, 0)
__global__ __launch_bounds__(256)
void attn_mfma(const unsigned short* __restrict__ qkhi, const unsigned short* __restrict__ qklo,
               const unsigned* __restrict__ vtx,
               unsigned short* __restrict__ ohi, unsigned short* __restrict__ olo)
{
    __shared__ __align__(16) unsigned short SM[24064];
    #define KH(r,d) SM[(r)*136 + (d)]
    #define KL(r,d) SM[4352 + (r)*136 + (d)]
    #define VH(d,k) SM[8704 + (d)*40 + (k)]
    #define VL(d,k) SM[13824 + (d)*40 + (k)]
    #define PH(r,k) SM[18944 + (r)*40 + (k)]
    #define PL(r,k) SM[21504 + (r)*40 + (k)]
    #define OS(r,d) SM[(r)*136 + (d)]

    const int t = threadIdx.x;
    const int lane = t & 63, w = t >> 6;
    const int qt = blockIdx.x, h = blockIdx.y, b = blockIdx.z;
    const int q0 = qt * AQT;
    const int c = lane & 15, g = lane >> 4;
    const float SCALE = 0.08838834764831845f; // 1/sqrt(128)

    short8v qh[4], ql[4];
    {
        int qrow = b * LC + q0 + w * 16 + c;
        if (qrow > MROWS - 1) qrow = MROWS - 1;
        const unsigned short* bh_ = qkhi + (size_t)qrow * 1024 + h * DH;
        const unsigned short* bl_ = qklo + (size_t)qrow * 1024 + h * DH;
        #pragma unroll
        for (int ks = 0; ks < 4; ks++) {
            qh[ks] = *(const short8v*)(bh_ + ks * 32 + g * 8);
            ql[ks] = *(const short8v*)(bl_ + ks * 32 + g * 8);
        }
    }

    float m_r[4], l_r[4];
    #pragma unroll
    for (int r = 0; r < 4; r++) { m_r[r] = -INFINITY; l_r[r] = 0.f; }
    f32x4 acc_o[8];
    #pragma unroll
    for (int n = 0; n < 8; n++) { acc_o[n][0]=0.f; acc_o[n][1]=0.f; acc_o[n][2]=0.f; acc_o[n][3]=0.f; }

    const int skr = t >> 3, skd = (t & 7) * 16;
    const int svd = t >> 1, svk = (t & 1) * 16;

    for (int kt = 0; kt < NKT2; kt++) {
        __syncthreads();
        {
            int krow = b * LC + kt * AKT + skr;
            if (krow > MROWS - 1) krow = MROWS - 1;
            const unsigned short* kb  = qkhi + (size_t)krow * 1024 + 512 + h * DH + skd;
            const unsigned short* kbl = qklo + (size_t)krow * 1024 + 512 + h * DH + skd;
            *(short8v*)&KH(skr, skd)     = *(const short8v*)kb;
            *(short8v*)&KH(skr, skd + 8) = *(const short8v*)(kb + 8);
            *(short8v*)&KL(skr, skd)     = *(const short8v*)kbl;
            *(short8v*)&KL(skr, skd + 8) = *(const short8v*)(kbl + 8);
            // V staging: read interleaved uints, deinterleave to VH/VL
            const unsigned* vb = vtx + ((size_t)((b * HH + h) * DH + svd)) * VTSTRIDE + kt * AKT + svk;
            uint4 a0 = *(const uint4*)(vb);
            uint4 a1 = *(const uint4*)(vb + 4);
            uint4 a2 = *(const uint4*)(vb + 8);
            uint4 a3 = *(const uint4*)(vb + 12);
            uint4 hA, hB, lA, lB;
            hA.x = (a0.x & 0xffffu) | (a0.y << 16);
            hA.y = (a0.z & 0xffffu) | (a0.w << 16);
            hA.z = (a1.x & 0xffffu) | (a1.y << 16);
            hA.w = (a1.z & 0xffffu) | (a1.w << 16);
            hB.x = (a2.x & 0xffffu) | (a2.y << 16);
            hB.y = (a2.z & 0xffffu) | (a2.w << 16);
            hB.z = (a3.x & 0xffffu) | (a3.y << 16);
            hB.w = (a3.z & 0xffffu) | (a3.w << 16);
            lA.x = (a0.x >> 16) | (a0.y & 0xffff0000u);
            lA.y = (a0.z >> 16) | (a0.w & 0xffff0000u);
            lA.z = (a1.x >> 16) | (a1.y & 0xffff0000u);
            lA.w = (a1.z >> 16) | (a1.w & 0xffff0000u);
            lB.x = (a2.x >> 16) | (a2.y & 0xffff0000u);
            lB.y = (a2.z >> 16) | (a2.w & 0xffff0000u);
            lB.z = (a3.x >> 16) | (a3.y & 0xffff0000u);
            lB.w = (a3.z >> 16) | (a3.w & 0xffff0000u);
            *(uint4*)&VH(svd, svk)     = hA;
            *(uint4*)&VH(svd, svk + 8) = hB;
            *(uint4*)&VL(svd, svk)     = lA;
            *(uint4*)&VL(svd, svk + 8) = lB;
        }
        __syncthreads();

        f32x4 s[2];
        s[0][0]=s[0][1]=s[0][2]=s[0][3]=0.f;
        s[1][0]=s[1][1]=s[1][2]=s[1][3]=0.f;
        #pragma unroll
        for (int n = 0; n < 2; n++) {
            #pragma unroll
            for (int ks = 0; ks < 4; ks++) {
                short8v kh = *(const short8v*)&KH(n * 16 + c, ks * 32 + g * 8);
                short8v kl = *(const short8v*)&KL(n * 16 + c, ks * 32 + g * 8);
                s[n] = MFMA16(qh[ks], kh, s[n]);
                s[n] = MFMA16(ql[ks], kh, s[n]);
                s[n] = MFMA16(qh[ks], kl, s[n]);
            }
        }

        #pragma unroll
        for (int n = 0; n < 2; n++) {
            bool oob = (kt * 32 + n * 16 + c) >= LC;
            #pragma unroll
            for (int r = 0; r < 4; r++) {
                float sv = s[n][r] * SCALE;
                s[n][r] = oob ? -INFINITY : sv;
            }
        }

        float alpha[4], p0v[4], p1v[4];
        #pragma unroll
        for (int r = 0; r < 4; r++) {
            float rm = fmaxf(s[0][r], s[1][r]);
            #pragma unroll
            for (int off = 1; off < 16; off <<= 1) rm = fmaxf(rm, __shfl_xor(rm, off));
            float mn = fmaxf(m_r[r], rm);
            float p0 = expf(s[0][r] - mn);
            float p1 = expf(s[1][r] - mn);
            float ts = p0 + p1;
            #pragma unroll
            for (int off = 1; off < 16; off <<= 1) ts += __shfl_xor(ts, off);
            float al = expf(m_r[r] - mn);
            m_r[r] = mn;
            l_r[r] = al * l_r[r] + ts;
            alpha[r] = al;
            p0v[r] = p0; p1v[r] = p1;
        }

        #pragma unroll
        for (int n = 0; n < 8; n++)
            #pragma unroll
            for (int r = 0; r < 4; r++) acc_o[n][r] *= alpha[r];

        #pragma unroll
        for (int r = 0; r < 4; r++) {
            unsigned short ph, pl;
            split_bf(p0v[r], ph, pl);
            PH(w * 16 + g * 4 + r, c) = ph;
            PL(w * 16 + g * 4 + r, c) = pl;
            split_bf(p1v[r], ph, pl);
            PH(w * 16 + g * 4 + r, 16 + c) = ph;
            PL(w * 16 + g * 4 + r, 16 + c) = pl;
        }
        __syncthreads();

        short8v pah = *(const short8v*)&PH(w * 16 + c, g * 8);
        short8v pal = *(const short8v*)&PL(w * 16 + c, g * 8);
        #pragma unroll
        for (int n = 0; n < 8; n++) {
            short8v vh = *(const short8v*)&VH(n * 16 + c, g * 8);
            short8v vl = *(const short8v*)&VL(n * 16 + c, g * 8);
            acc_o[n] = MFMA16(pah, vh, acc_o[n]);
            acc_o[n] = MFMA16(pal, vh, acc_o[n]);
            acc_o[n] = MFMA16(pah, vl, acc_o[n]);
        }
    }

    float inv[4];
    #pragma unroll
    for (int r = 0; r < 4; r++) inv[r] = 1.0f / l_r[r];

    const int orow = t >> 2, oc0 = (t & 3) * 32;
    #pragma unroll
    for (int pass = 0; pass < 2; pass++) {
        __syncthreads();
        #pragma unroll
        for (int n = 0; n < 8; n++)
            #pragma unroll
            for (int r = 0; r < 4; r++) {
                float v = acc_o[n][r] * inv[r];
                unsigned short hv, lv;
                split_bf(v, hv, lv);
                OS(w * 16 + g * 4 + r, n * 16 + c) = pass ? lv : hv;
            }
        __syncthreads();
        int grow = q0 + orow;
        if (grow < LC) {
            unsigned short* dst = (pass ? olo : ohi) + ((size_t)(b * LC + grow)) * DD + h * DH + oc0;
            #pragma unroll
            for (int u = 0; u < 4; u++)
                *(short8v*)(dst + u * 8) = *(const short8v*)&OS(orow, oc0 + u * 8);
        }
    }
    #undef KH
    #undef KL
    #undef VH
    #undef VL
    #undef PH
    #undef PL
    #undef OS
}

// ---------------- LayerNorm over 512, writes fp32 + splits ----------------
__global__ __launch_bounds__(128)
void ln512(const float* __restrict__ X, const float* __restrict__ g,
           const float* __restrict__ bb, float* __restrict__ Y,
           unsigned short* __restrict__ Yhi, unsigned short* __restrict__ Ylo)
{
    __shared__ float red[2];
    int row = blockIdx.x, t = threadIdx.x;
    const float* x = X + (size_t)row * DD;
    float4 v = *(const float4*)(x + t * 4);
    float s = v.x + v.y + v.z + v.w;
    #pragma unroll
    for (int off = 1; off < 64; off <<= 1) s += __shfl_xor(s, off);
    if ((t & 63) == 0) red[t >> 6] = s;
    __syncthreads();
    float mean = (red[0] + red[1]) * (1.0f / 512.0f);
    __syncthreads();
    float d0 = v.x - mean, d1 = v.y - mean, d2 = v.z - mean, d3 = v.w - mean;
    float s2 = d0 * d0 + d1 * d1 + d2 * d2 + d3 * d3;
    #pragma unroll
    for (int off = 1; off < 64; off <<= 1) s2 += __shfl_xor(s2, off);
    if ((t & 63) == 0) red[t >> 6] = s2;
    __syncthreads();
    float var = (red[0] + red[1]) * (1.0f / 512.0f);
    float rstd = 1.0f / sqrtf(var + 1e-5f);
    float4 gv = *(const float4*)(g + t * 4);
    float4 bv = *(const float4*)(bb + t * 4);
    float4 ov;
    ov.x = d0 * rstd * gv.x + bv.x;
    ov.y = d1 * rstd * gv.y + bv.y;
    ov.z = d2 * rstd * gv.z + bv.z;
    ov.w = d3 * rstd * gv.w + bv.w;
    size_t o = (size_t)row * DD + t * 4;
    *(float4*)(Y + o) = ov;
    unsigned short hs[4], ls[4];
    split_bf(ov.x, hs[0], ls[0]); split_bf(ov.y, hs[1], ls[1]);
    split_bf(ov.z, hs[2], ls[2]); split_bf(ov.w, hs[3], ls[3]);
    ((uint2*)Yhi)[o >> 2] = make_uint2((unsigned)hs[0] | ((unsigned)hs[1]<<16),
                                       (unsigned)hs[2] | ((unsigned)hs[3]<<16));
    ((uint2*)Ylo)[o >> 2] = make_uint2((unsigned)ls[0] | ((unsigned)ls[1]<<16),
                                       (unsigned)ls[2] | ((unsigned)ls[3]<<16));
}

// ---------------- mean over L (two-pass) ----------------
__global__ __launch_bounds__(128)
void mean_part(const float* __restrict__ query, float* __restrict__ part)
{
    int b = blockIdx.x, ch = blockIdx.y, t = threadIdx.x;
    const float* base = query + ((size_t)b * LQ + ch * 64) * DD + t * 4;
    float ax = 0.f, ay = 0.f, az = 0.f, aw = 0.f;
    for (int l = 0; l < 64; l++) {
        float4 v = *(const float4*)(base + (size_t)l * DD);
        ax += v.x; ay += v.y; az += v.z; aw += v.w;
    }
    *(float4*)(part + ((size_t)(b * 8 + ch)) * DD + t * 4) = make_float4(ax, ay, az, aw);
}

__global__ __launch_bounds__(128)
void mean_fin(const float* __restrict__ part, float* __restrict__ xm)
{
    int b = blockIdx.x, t = threadIdx.x;
    float ax = 0.f, ay = 0.f, az = 0.f, aw = 0.f;
    #pragma unroll
    for (int ch = 0; ch < 8; ch++) {
        float4 v = *(const float4*)(part + ((size_t)(b * 8 + ch)) * DD + t * 4);
        ax += v.x; ay += v.y; az += v.z; aw += v.w;
    }
    *(float4*)(xm + (size_t)b * DD + t * 4) =
        make_float4(ax * (1.f/512.f), ay * (1.f/512.f), az * (1.f/512.f), aw * (1.f/512.f));
}

static __device__ __forceinline__ float block128_sum(float x, float* red, int t) {
    #pragma unroll
    for (int off = 1; off < 64; off <<= 1) x += __shfl_xor(x, off);
    if ((t & 63) == 0) red[t >> 6] = x;
    __syncthreads();
    float r = red[0] + red[1];
    __syncthreads();
    return r;
}

// ---------------- proj + LN -> q_repr ----------------
__global__ __launch_bounds__(128)
void proj_ln(const float* __restrict__ h, const float* __restrict__ pW, const float* __restrict__ pb,
             const float* __restrict__ pg, const float* __restrict__ pbb, float* __restrict__ q_repr)
{
    __shared__ float xs[DD];
    __shared__ float red[2];
    int b = blockIdx.x, t = threadIdx.x;
    *(float4*)&xs[t * 4] = *(const float4*)(h + (size_t)(b * LC) * DD + t * 4);
    __syncthreads();
    const float* w = pW + (size_t)t * DD;
    float acc = pb[t];
    for (int k = 0; k < DD; k += 4) {
        float4 a = *(const float4*)&xs[k];
        float4 ww = *(const float4*)(w + k);
        acc += a.x * ww.x + a.y * ww.y + a.z * ww.z + a.w * ww.w;
    }
    float mean = block128_sum(acc, red, t) * (1.f / 128.f);
    float dx = acc - mean;
    float var = block128_sum(dx * dx, red, t) * (1.f / 128.f);
    float rstd = 1.0f / sqrtf(var + 1e-5f);
    q_repr[(size_t)b * DRr + t] = dx * rstd * pg[t] + pbb[t];
}

// ---------------- value encoder (fused) -> q_val ----------------
__global__ __launch_bounds__(128)
void venc(const float* __restrict__ xm, const float* __restrict__ vW1, const float* __restrict__ vb1,
          const float* __restrict__ vg, const float* __restrict__ vb,
          const float* __restrict__ vW2, const float* __restrict__ vb2,
          float* __restrict__ q_val)
{
    __shared__ float xs[DD];
    __shared__ float hg[DRr];
    __shared__ float red[2];
    int b = blockIdx.x, t = threadIdx.x;
    *(float4*)&xs[t * 4] = *(const float4*)(xm + (size_t)b * DD + t * 4);
    __syncthreads();
    const float* w = vW1 + (size_t)t * DD;
    float acc = vb1[t];
    for (int k = 0; k < DD; k += 4) {
        float4 a = *(const float4*)&xs[k];
        float4 ww = *(const float4*)(w + k);
        acc += a.x * ww.x + a.y * ww.y + a.z * ww.z + a.w * ww.w;
    }
    float mean = block128_sum(acc, red, t) * (1.f / 128.f);
    float dx = acc - mean;
    float var = block128_sum(dx * dx, red, t) * (1.f / 128.f);
    float rstd = 1.0f / sqrtf(var + 1e-5f);
    float hn = dx * rstd * vg[t] + vb[t];
    hg[t] = gelu_exact(hn);
    __syncthreads();
    const float* w2 = vW2 + (size_t)t * DRr;
    float acc2 = vb2[t];
    for (int k = 0; k < DRr; k += 4) {
        float4 a = *(const float4*)&hg[k];
        float4 ww = *(const float4*)(w2 + k);
        acc2 += a.x * ww.x + a.y * ww.y + a.z * ww.z + a.w * ww.w;
    }
    q_val[(size_t)b * DRr + t] = acc2;
}

// ---------------- combine ----------------
__global__ void combine_qk(const float* __restrict__ qr, const float* __restrict__ qv,
                           const float* __restrict__ swp, float* __restrict__ qk)
{
    int i = blockIdx.x * blockDim.x + threadIdx.x;
    if (i < B_ * DRr) {
        float sw = swp[0];
        qk[i] = sw * qr[i] + (1.f - sw) * qv[i];
    }
}

// ---------------- sim ----------------
#define SIMCH 10
__global__ __launch_bounds__(256)
void sim_kernel(const float* __restrict__ qk, const float* __restrict__ mkeys, float* __restrict__ sim)
{
    __shared__ float qs[DRr];
    int b = blockIdx.x, ch = blockIdx.y, t = threadIdx.x;
    if (t < DRr) qs[t] = qk[(size_t)b * DRr + t];
    __syncthreads();
    float qn = 0.f;
    #pragma unroll 8
    for (int i = 0; i < DRr; i++) qn += qs[i] * qs[i];
    int n0 = ch * (NKEYS / SIMCH), n1 = n0 + (NKEYS / SIMCH);
    for (int n = n0 + t; n < n1; n += 256) {
        const float* kr = mkeys + (size_t)n * DRr;
        float dot = 0.f, kn = 0.f;
        #pragma unroll 8
        for (int i = 0; i < DRr; i += 4) {
            float4 kv = *(const float4*)(kr + i);
            dot += qs[i] * kv.x + qs[i + 1] * kv.y + qs[i + 2] * kv.z + qs[i + 3] * kv.w;
            kn  += kv.x * kv.x + kv.y * kv.y + kv.z * kv.z + kv.w * kv.w;
        }
        float d = qn - 2.f * dot + kn;
        sim[(size_t)b * NKEYS + n] = -d / 0.1f;
    }
}

// ---------------- top-k (jax semantics: value desc, ties -> lower index) ----
static __device__ __forceinline__ void topk_insert(float* v, int* id, float x, int n) {
    bool better = (x > v[TOPK - 1]) || (x == v[TOPK - 1] && n < id[TOPK - 1]);
    if (better) {
        v[TOPK - 1] = x; id[TOPK - 1] = n;
        #pragma unroll
        for (int k = TOPK - 1; k > 0; k--) {
            bool sw = (v[k] > v[k - 1]) || (v[k] == v[k - 1] && id[k] < id[k - 1]);
            if (!sw) break;
            float tv = v[k]; v[k] = v[k - 1]; v[k - 1] = tv;
            int ti = id[k]; id[k] = id[k - 1]; id[k - 1] = ti;
        }
    }
}

__global__ __launch_bounds__(256)
void topk_kernel(const float* __restrict__ sim, int* __restrict__ topidx, float* __restrict__ wout)
{
    __shared__ float sv[256][TOPK];
    __shared__ int   si[256][TOPK];
    int b = blockIdx.x, t = threadIdx.x;
    float v[TOPK]; int id[TOPK];
    #pragma unroll
    for (int k = 0; k < TOPK; k++) { v[k] = -INFINITY; id[k] = 0x7fffffff; }
    for (int n = t; n < NKEYS; n += 256) {
        topk_insert(v, id, sim[(size_t)b * NKEYS + n], n);
    }
    #pragma unroll
    for (int k = 0; k < TOPK; k++) { sv[t][k] = v[k]; si[t][k] = id[k]; }
    for (int strd = 128; strd >= 1; strd >>= 1) {
        __syncthreads();
        if (t < strd) {
            #pragma unroll
            for (int k = 0; k < TOPK; k++) topk_insert(v, id, sv[t + strd][k], si[t + strd][k]);
            #pragma unroll
            for (int k = 0; k < TOPK; k++) { sv[t][k] = v[k]; si[t][k] = id[k]; }
        }
    }
    if (t == 0) {
        float m = v[0];
        float e[TOPK]; float sum = 0.f;
        #pragma unroll
        for (int k = 0; k < TOPK; k++) { e[k] = expf(v[k] - m); sum += e[k]; }
        #pragma unroll
        for (int k = 0; k < TOPK; k++) {
            wout[(size_t)b * TOPK + k] = e[k] / sum;
            topidx[b * TOPK + k] = id[k];
        }
    }
}

// ---------------- gather ----------------
__global__ __launch_bounds__(128)
void gather_kernel(const float* __restrict__ mv, const int* __restrict__ topidx, float* __restrict__ out)
{
    int blk = blockIdx.x;
    int b = blk / (TOPK * PP);
    int rem = blk - b * (TOPK * PP);
    int k = rem / PP;
    int p = rem - k * PP;
    int idx = topidx[b * TOPK + k];
    const float4* src = (const float4*)(mv + ((size_t)idx * PP + p) * DD);
    float4* dst = (float4*)(out + (size_t)blk * DD);
    dst[threadIdx.x] = src[threadIdx.x];
}

// ---------------- launch ----------------
extern "C" void kernel_launch(void* const* d_in, const int* in_sizes, int n_in,
                              void* d_out, int out_size, void* d_ws, size_t ws_size,
                              hipStream_t stream) {
    const float* query = (const float*)d_in[0];
    const float* mkeys = (const float*)d_in[1];
    const float* mvals = (const float*)d_in[2];
    const float* cls   = (const float*)d_in[3];
    const float* Wqkv  = (const float*)d_in[4];
    const float* bqkv  = (const float*)d_in[5];
    const float* Wo    = (const float*)d_in[6];
    const float* bo    = (const float*)d_in[7];
    const float* ln1g  = (const float*)d_in[8];
    const float* ln1b  = (const float*)d_in[9];
    const float* W1    = (const float*)d_in[10];
    const float* b1    = (const float*)d_in[11];
    const float* W2    = (const float*)d_in[12];
    const float* b2    = (const float*)d_in[13];
    const float* ln2g  = (const float*)d_in[14];
    const float* ln2b  = (const float*)d_in[15];
    const float* pW    = (const float*)d_in[16];
    const float* pb    = (const float*)d_in[17];
    const float* pg    = (const float*)d_in[18];
    const float* pbb   = (const float*)d_in[19];
    const float* vW1   = (const float*)d_in[20];
    const float* vb1   = (const float*)d_in[21];
    const float* vg    = (const float*)d_in[22];
    const float* vb    = (const float*)d_in[23];
    const float* vW2   = (const float*)d_in[24];
    const float* vb2   = (const float*)d_in[25];
    const float* swp   = (const float*)d_in[26];
    float* out = (float*)d_out;

    // ---- workspace layout ----
    float* ws    = (float*)d_ws;
    float* h     = ws;                                   // MROWS*512 fp32 residual
    float* preln = h + (size_t)MROWS * DD;               // MROWS*512 fp32
    unsigned short* h_hi  = (unsigned short*)(preln + (size_t)MROWS * DD);
    unsigned short* h_lo  = h_hi  + (size_t)MROWS * DD;
    unsigned short* mid_hi = h_lo + (size_t)MROWS * DD;  // MROWS*1024
    unsigned short* mid_lo = mid_hi + (size_t)MROWS * 1024;
    unsigned short* qkhi  = mid_lo + (size_t)MROWS * 1024;
    unsigned short* qklo  = qkhi  + (size_t)MROWS * 1024;
    unsigned* vtx         = (unsigned*)(qklo + (size_t)MROWS * 1024); // 32768*VTSTRIDE uints
    unsigned short* wq_hi = (unsigned short*)(vtx + (size_t)32768 * VTSTRIDE);
    unsigned short* wq_lo = wq_hi + (size_t)2 * 1536 * DD;
    unsigned short* wo_hi = wq_lo + (size_t)2 * 1536 * DD;
    unsigned short* wo_lo = wo_hi + (size_t)2 * DD * DD;
    unsigned short* w1_hi = wo_lo + (size_t)2 * DD * DD;
    unsigned short* w1_lo = w1_hi + (size_t)2 * 1024 * DD;
    unsigned short* w2_hi = w1_lo + (size_t)2 * 1024 * DD;
    unsigned short* w2_lo = w2_hi + (size_t)2 * DD * 1024;
    float* xm   = (float*)(w2_lo + (size_t)2 * DD * 1024);
    float* qval = xm   + (size_t)B_ * DD;
    float* qrep = qval + (size_t)B_ * DRr;
    float* qkc  = qrep + (size_t)B_ * DRr;
    float* simb = qkc  + (size_t)B_ * DRr;
    int*   tidx = (int*)(simb + (size_t)B_ * NKEYS);
    float* mpart = (float*)(tidx + 512);                 // 64*8*512 fp32
    (void)ws_size; (void)in_sizes; (void)n_in; (void)out_size;

    // ---- weight splits ----
    {
        int n4;
        n4 = 2 * 1536 * DD / 4;
        split_kernel<<<(n4 + 255) / 256, 256, 0, stream>>>(Wqkv, wq_hi, wq_lo, n4);
        n4 = 2 * DD * DD / 4;
        split_kernel<<<(n4 + 255) / 256, 256, 0, stream>>>(Wo, wo_hi, wo_lo, n4);
        n4 = 2 * 1024 * DD / 4;
        split_kernel<<<(n4 + 255) / 256, 256, 0, stream>>>(W1, w1_hi, w1_lo, n4);
        n4 = 2 * DD * 1024 / 4;
        split_kernel<<<(n4 + 255) / 256, 256, 0, stream>>>(W2, w2_hi, w2_lo, n4);
    }

    concat_cls<<<MROWS, 128, 0, stream>>>(query, cls, h, h_hi, h_lo);

    for (int l = 0; l < 2; l++) {
        const unsigned short* wqh = wq_hi + (size_t)l * 1536 * DD;
        const unsigned short* wql = wq_lo + (size_t)l * 1536 * DD;
        const unsigned short* woh = wo_hi + (size_t)l * DD * DD;
        const unsigned short* wol = wo_lo + (size_t)l * DD * DD;
        const unsigned short* w1h = w1_hi + (size_t)l * 1024 * DD;
        const unsigned short* w1l = w1_lo + (size_t)l * 1024 * DD;
        const unsigned short* w2h = w2_hi + (size_t)l * DD * 1024;
        const unsigned short* w2l = w2_lo + (size_t)l * DD * 1024;
        const float* bq  = bqkv + (size_t)l * 1536;
        const float* bol = bo   + (size_t)l * DD;
        const float* g1  = ln1g + (size_t)l * DD;
        const float* be1 = ln1b + (size_t)l * DD;
        const float* b1l = b1   + (size_t)l * 1024;
        const float* b2l = b2   + (size_t)l * DD;
        const float* g2  = ln2g + (size_t)l * DD;
        const float* be2 = ln2b + (size_t)l * DD;

        // QKV -> qk splits + transposed interleaved V
        gemm3<3><<<dim3(257, 12), 256, 0, stream>>>(h_hi, h_lo, wqh, wql, bq, nullptr,
                                                    nullptr, qkhi, qklo, vtx,
                                                    MROWS, 1536, DD);
        // MFMA attention -> h_hi/h_lo (attn-out splits)
        attn_mfma<<<dim3(9, HH, B_), 256, 0, stream>>>(qkhi, qklo, vtx, h_hi, h_lo);
        // Wo + residual -> preln fp32
        gemm3<1><<<dim3(257, 4), 256, 0, stream>>>(h_hi, h_lo, woh, wol, bol, h,
                                                   preln, nullptr, nullptr, nullptr,
                                                   MROWS, DD, DD);
        ln512<<<MROWS, 128, 0, stream>>>(preln, g1, be1, h, h_hi, h_lo);
        // FFN1 + gelu -> mid splits
        gemm3<2><<<dim3(257, 8), 256, 0, stream>>>(h_hi, h_lo, w1h, w1l, b1l, nullptr,
                                                   nullptr, mid_hi, mid_lo, nullptr,
                                                   MROWS, 1024, DD);
        // FFN2 + residual -> preln fp32
        gemm3<1><<<dim3(257, 4), 256, 0, stream>>>(mid_hi, mid_lo, w2h, w2l, b2l, h,
                                                   preln, nullptr, nullptr, nullptr,
                                                   MROWS, DD, 1024);
        ln512<<<MROWS, 128, 0, stream>>>(preln, g2, be2, h, h_hi, h_lo);
    }

    proj_ln<<<B_, 128, 0, stream>>>(h, pW, pb, pg, pbb, qrep);
    mean_part<<<dim3(B_, 8), 128, 0, stream>>>(query, mpart);
    mean_fin<<<B_, 128, 0, stream>>>(mpart, xm);
    venc<<<B_, 128, 0, stream>>>(xm, vW1, vb1, vg, vb, vW2, vb2, qval);
    combine_qk<<<(B_ * DRr + 255) / 256, 256, 0, stream>>>(qrep, qval, swp, qkc);
    sim_kernel<<<dim3(B_, SIMCH), 256, 0, stream>>>(qkc, mkeys, simb);
    topk_kernel<<<B_, 256, 0, stream>>>(simb, tidx, out + (size_t)B_ * TOPK * PP * DD);
    gather_kernel<<<B_ * TOPK * PP, 128, 0, stream>>>(mvals, tidx, out);
}

// Round 6
// 2415.419 us; speedup vs baseline: 2.3981x; 1.0060x over previous
//
#include <hip/hip_runtime.h>
#include <math.h>

// Problem dims
#define B_    64
#define LQ    512
#define LC    513          // with CLS
#define DD    512
#define HH    4
#define DH    128
#define DRr   128
#define NKEYS 10000
#define PP    96
#define TOPK  5
#define MROWS (B_*LC)      // 32832
#define VTSTRIDE 544       // padded LC for transposed V (multiple of 16)

typedef __attribute__((ext_vector_type(8))) short short8v;
typedef __attribute__((ext_vector_type(4))) float f32x4;
typedef __attribute__((ext_vector_type(16))) float f32x16;

static __device__ __forceinline__ float gelu_exact(float x) {
    return 0.5f * x * (1.0f + erff(x * 0.70710678118654752440f));
}

static __device__ __forceinline__ unsigned short f2bf(float x) {
    union { float f; unsigned u; } v; v.f = x;
    unsigned r = v.u + 0x7fff + ((v.u >> 16) & 1);
    return (unsigned short)(r >> 16);
}
static __device__ __forceinline__ float bf2f(unsigned short h) {
    union { float f; unsigned u; } v; v.u = ((unsigned)h) << 16;
    return v.f;
}
static __device__ __forceinline__ void split_bf(float x, unsigned short& hi, unsigned short& lo) {
    hi = f2bf(x);
    lo = f2bf(x - bf2f(hi));
}

// bijective XCD-aware swizzle (m204): contiguous post-ids per XCD
static __device__ __forceinline__ int xcd_swz(int orig, int nwg) {
    int xcd = orig & 7;
    int lid = orig >> 3;
    int q = nwg >> 3, r = nwg & 7;
    int base = (xcd < r) ? xcd * (q + 1) : r * (q + 1) + (xcd - r) * q;
    return base + lid;
}

// async global->LDS, 16B per lane. LDS dest must be linear: base + lane*16.
static __device__ __forceinline__ void gload16(const unsigned short* g, unsigned short* l) {
    __builtin_amdgcn_global_load_lds(
        (const __attribute__((address_space(1))) unsigned*)g,
        (__attribute__((address_space(3))) unsigned*)l, 16, 0, 0);
}

// ---------------- generic fp32 -> (hi,lo) bf16 split ----------------
__global__ __launch_bounds__(256)
void split_kernel(const float* __restrict__ x, unsigned short* __restrict__ hi,
                  unsigned short* __restrict__ lo, int n4)
{
    int i = blockIdx.x * blockDim.x + threadIdx.x;
    if (i >= n4) return;
    float4 v = ((const float4*)x)[i];
    unsigned short h0,h1,h2,h3,l0,l1,l2,l3;
    split_bf(v.x,h0,l0); split_bf(v.y,h1,l1); split_bf(v.z,h2,l2); split_bf(v.w,h3,l3);
    ((uint2*)hi)[i] = make_uint2((unsigned)h0 | ((unsigned)h1 << 16), (unsigned)h2 | ((unsigned)h3 << 16));
    ((uint2*)lo)[i] = make_uint2((unsigned)l0 | ((unsigned)l1 << 16), (unsigned)l2 | ((unsigned)l3 << 16));
}

// ---------------- concat cls + query -> h (fp32 + splits) ----------------
__global__ __launch_bounds__(128)
void concat_cls(const float* __restrict__ query, const float* __restrict__ cls,
                float* __restrict__ h, unsigned short* __restrict__ h_hi,
                unsigned short* __restrict__ h_lo)
{
    int row = blockIdx.x;
    int t = threadIdx.x;
    int b = row / LC, r = row - b * LC;
    const float* src = (r == 0) ? cls : (query + ((size_t)b * LQ + (r - 1)) * DD);
    float4 v = *(const float4*)(src + t * 4);
    *(float4*)(h + (size_t)row * DD + t * 4) = v;
    unsigned short hs[4], ls[4];
    split_bf(v.x, hs[0], ls[0]); split_bf(v.y, hs[1], ls[1]);
    split_bf(v.z, hs[2], ls[2]); split_bf(v.w, hs[3], ls[3]);
    size_t o = (size_t)row * DD + t * 4;
    ((uint2*)(h_hi))[o >> 2] = make_uint2((unsigned)hs[0] | ((unsigned)hs[1]<<16),
                                          (unsigned)hs[2] | ((unsigned)hs[3]<<16));
    ((uint2*)(h_lo))[o >> 2] = make_uint2((unsigned)ls[0] | ((unsigned)ls[1]<<16),
                                          (unsigned)ls[2] | ((unsigned)ls[3]<<16));
}

// ---------------- split-bf16 MFMA GEMM (32x32x16): C = A @ W^T + ... -------
// MODE 0: C fp32 = acc + bias
// MODE 1: C fp32 = acc + bias + res
// MODE 2: (hi,lo) bf16 = gelu(acc + bias)
// MODE 3: QKV: col0<1024 -> qk hi/lo [row][1024]; col0>=1024 -> transposed V
//         interleaved (hi | lo<<16) via LDS-transpose coalesced stores
#define BM 128
#define BN 128
#define BK 32

#define MFMA32(a, b, c) __builtin_amdgcn_mfma_f32_32x32x16_bf16(a, b, c, 0, 0, 0)

template<int MODE>
__global__ __launch_bounds__(256)
void gemm3(const unsigned short* __restrict__ Ahi, const unsigned short* __restrict__ Alo,
           const unsigned short* __restrict__ Whi, const unsigned short* __restrict__ Wlo,
           const float* __restrict__ bias, const float* __restrict__ res,
           float* __restrict__ Cf, unsigned short* __restrict__ Chi,
           unsigned short* __restrict__ Clo, unsigned* __restrict__ Vix,
           int M, int N, int K, int NBN)
{
    __shared__ __align__(16) unsigned short POOL[16384];   // 32KB
    unsigned short* LAh = POOL;            // 128 rows x 32 shorts
    unsigned short* LAl = POOL + 4096;
    unsigned short* LBh = POOL + 8192;
    unsigned short* LBl = POOL + 12288;

    const int t = threadIdx.x;
    const int lane = t & 63, w = t >> 6;
    const int wr = w >> 1, wc = w & 1;
    const int wg = xcd_swz(blockIdx.x, gridDim.x);
    const int bm = wg / NBN, bn = wg - bm * NBN;
    const int row0 = bm * BM, col0 = bn * BN;

    // staging coords: thread t covers (rows t>>2 and t>>2+64, 16B block t&3)
    const int srow = t >> 2;
    const int sg   = t & 3;
    const int glog = sg ^ (srow & 3);   // same for srow and srow+64
    int ar0 = row0 + srow;      if (ar0 >= M) ar0 = M - 1;
    int ar1 = row0 + srow + 64; if (ar1 >= M) ar1 = M - 1;
    const size_t aoff0 = (size_t)ar0 * K + glog * 8;
    const size_t aoff1 = (size_t)ar1 * K + glog * 8;
    const size_t boff0 = (size_t)(col0 + srow) * K + glog * 8;
    const size_t boff1 = (size_t)(col0 + srow + 64) * K + glog * 8;
    const int ldso0 = t * 8;          // shorts (t*16 bytes)
    const int ldso1 = t * 8 + 2048;

    f32x16 acc[2][2];
    #pragma unroll
    for (int m = 0; m < 2; m++)
        #pragma unroll
        for (int n = 0; n < 2; n++)
            #pragma unroll
            for (int i = 0; i < 16; i++) acc[m][n][i] = 0.f;

    // fragment read coords: row-in-tile = lane&31, k-group = lane>>5
    const int cl = lane & 31;
    const int kg = lane >> 5;
    const int cl3 = cl & 3;

    const int KT = K / BK;
    for (int kt = 0; kt < KT; kt++) {
        const int k0 = kt * BK;
        __syncthreads();
        gload16(Ahi + aoff0 + k0, &LAh[ldso0]);
        gload16(Ahi + aoff1 + k0, &LAh[ldso1]);
        gload16(Alo + aoff0 + k0, &LAl[ldso0]);
        gload16(Alo + aoff1 + k0, &LAl[ldso1]);
        gload16(Whi + boff0 + k0, &LBh[ldso0]);
        gload16(Whi + boff1 + k0, &LBh[ldso1]);
        gload16(Wlo + boff0 + k0, &LBl[ldso0]);
        gload16(Wlo + boff1 + k0, &LBl[ldso1]);
        __syncthreads();

        #pragma unroll
        for (int ks = 0; ks < 2; ks++) {
            const int blkswz = ((ks * 2 + kg) ^ cl3) * 8;
            short8v ah[2], al[2], bh[2], bl[2];
            #pragma unroll
            for (int m = 0; m < 2; m++) {
                int off = (wr * 64 + m * 32 + cl) * 32 + blkswz;
                ah[m] = *(const short8v*)&LAh[off];
                al[m] = *(const short8v*)&LAl[off];
            }
            #pragma unroll
            for (int n = 0; n < 2; n++) {
                int off = (wc * 64 + n * 32 + cl) * 32 + blkswz;
                bh[n] = *(const short8v*)&LBh[off];
                bl[n] = *(const short8v*)&LBl[off];
            }
            #pragma unroll
            for (int m = 0; m < 2; m++)
                #pragma unroll
                for (int n = 0; n < 2; n++) {
                    acc[m][n] = MFMA32(ah[m], bh[n], acc[m][n]);
                    acc[m][n] = MFMA32(al[m], bh[n], acc[m][n]);
                    acc[m][n] = MFMA32(ah[m], bl[n], acc[m][n]);
                }
        }
    }

    // ---- V-transpose epilogue (MODE3 blocks with col0 >= 1024) ----
    if (MODE == 3 && col0 >= 1024) {
        const int hh = (col0 - 1024) >> 7;
        unsigned* VS = (unsigned*)POOL;       // [32 dd][129] uints, reuses staging
        const int bb0 = row0 / LC;
        const int bound = (bb0 + 1) * LC;
        const int ddl = t >> 3, j0 = (t & 7) * 16;
        #pragma unroll
        for (int p = 0; p < 4; p++) {
            __syncthreads();   // VS free (prev pass stores done / staging reads done)
            if (wc == (p >> 1)) {
                const int ccl = col0 + wc * 64 + (p & 1) * 32 + cl;
                const float bcol = bias[ccl];
                #pragma unroll
                for (int m = 0; m < 2; m++) {
                    const int lrb = wr * 64 + m * 32 + 4 * kg;
                    #pragma unroll
                    for (int q = 0; q < 4; q++)
                        #pragma unroll
                        for (int r = 0; r < 4; r++) {
                            float v = ((p & 1) ? acc[m][1][q * 4 + r]
                                               : acc[m][0][q * 4 + r]) + bcol;
                            unsigned short hv, lv;
                            split_bf(v, hv, lv);
                            VS[cl * 129 + lrb + 8 * q + r] =
                                (unsigned)hv | ((unsigned)lv << 16);
                        }
                }
            }
            __syncthreads();
            long long vb0 = (long long)((bb0 * HH + hh) * DH + p * 32 + ddl) * VTSTRIDE
                            - (long long)bb0 * LC;
            long long vb1 = (long long)(((bb0 + 1) * HH + hh) * DH + p * 32 + ddl) * VTSTRIDE
                            - (long long)(bb0 + 1) * LC;
            #pragma unroll
            for (int j = 0; j < 16; j++) {
                int row = row0 + j0 + j;
                if (row < M) {
                    long long vi = (row < bound ? vb0 : vb1) + row;
                    Vix[vi] = VS[ddl * 129 + j0 + j];
                }
            }
        }
        return;
    }

    // ---- normal epilogue: C/D layout col=lane&31, row=(reg&3)+8*(reg>>2)+4*(lane>>5)
    #pragma unroll
    for (int m = 0; m < 2; m++) {
        const int rb = row0 + wr * 64 + m * 32 + 4 * kg;
        #pragma unroll
        for (int n = 0; n < 2; n++) {
            const int cc = col0 + wc * 64 + n * 32 + cl;
            const float bcol = bias[cc];
            #pragma unroll
            for (int q = 0; q < 4; q++) {
                #pragma unroll
                for (int r = 0; r < 4; r++) {
                    int row = rb + 8 * q + r;
                    if (row < M) {
                        float v = acc[m][n][q * 4 + r] + bcol;
                        if (MODE == 1) v += res[(size_t)row * N + cc];
                        if (MODE == 2) {
                            v = gelu_exact(v);
                            unsigned short hv, lv;
                            split_bf(v, hv, lv);
                            Chi[(size_t)row * N + cc] = hv;
                            Clo[(size_t)row * N + cc] = lv;
                        } else if (MODE == 3) {
                            unsigned short hv, lv;
                            split_bf(v, hv, lv);
                            Chi[(size_t)row * 1024 + cc] = hv;
                            Clo[(size_t)row * 1024 + cc] = lv;
                        } else {
                            Cf[(size_t)row * N + cc] = v;
                        }
                    }
                }
            }
        }
    }
}

// ---------------- MFMA flash attention, split-bf16 ----------------
// qk:  [MROWS][1024] hi/lo (q cols 0..511, k cols 512..1023; head h at h*128)
// vtx: [(b*4+h)*128 + d][VTSTRIDE] uint (hi | lo<<16)  (transposed V)
// out: [MROWS][512] hi/lo splits
#define AQT 64
#define AKT 32
#define NKT2 17
#define MFMA16(a, b, c) __builtin_amdgcn_mfma_f32_16x16x32_bf16(a, b, c, 0, 0, 0)
__global__ __launch_bounds__(256)
void attn_mfma(const unsigned short* __restrict__ qkhi, const unsigned short* __restrict__ qklo,
               const unsigned* __restrict__ vtx,
               unsigned short* __restrict__ ohi, unsigned short* __restrict__ olo)
{
    __shared__ __align__(16) unsigned short SM[24064];
    #define KH(r,d) SM[(r)*136 + (d)]
    #define KL(r,d) SM[4352 + (r)*136 + (d)]
    #define VH(d,k) SM[8704 + (d)*40 + (k)]
    #define VL(d,k) SM[13824 + (d)*40 + (k)]
    #define PH(r,k) SM[18944 + (r)*40 + (k)]
    #define PL(r,k) SM[21504 + (r)*40 + (k)]
    #define OS(r,d) SM[(r)*136 + (d)]

    const int t = threadIdx.x;
    const int lane = t & 63, w = t >> 6;
    // swizzled decode: 9 q-tiles of one (b,h) contiguous on one XCD
    const int id = xcd_swz(blockIdx.x, gridDim.x);
    const int qt = id % 9;
    const int hb = id / 9;
    const int h = hb & 3, b = hb >> 2;
    const int q0 = qt * AQT;
    const int c = lane & 15, g = lane >> 4;
    const float SCALE = 0.08838834764831845f; // 1/sqrt(128)

    short8v qh[4], ql[4];
    {
        int qrow = b * LC + q0 + w * 16 + c;
        if (qrow > MROWS - 1) qrow = MROWS - 1;
        const unsigned short* bh_ = qkhi + (size_t)qrow * 1024 + h * DH;
        const unsigned short* bl_ = qklo + (size_t)qrow * 1024 + h * DH;
        #pragma unroll
        for (int ks = 0; ks < 4; ks++) {
            qh[ks] = *(const short8v*)(bh_ + ks * 32 + g * 8);
            ql[ks] = *(const short8v*)(bl_ + ks * 32 + g * 8);
        }
    }

    float m_r[4], l_r[4];
    #pragma unroll
    for (int r = 0; r < 4; r++) { m_r[r] = -INFINITY; l_r[r] = 0.f; }
    f32x4 acc_o[8];
    #pragma unroll
    for (int n = 0; n < 8; n++) { acc_o[n][0]=0.f; acc_o[n][1]=0.f; acc_o[n][2]=0.f; acc_o[n][3]=0.f; }

    const int skr = t >> 3, skd = (t & 7) * 16;
    const int svd = t >> 1, svk = (t & 1) * 16;

    for (int kt = 0; kt < NKT2; kt++) {
        __syncthreads();
        {
            int krow = b * LC + kt * AKT + skr;
            if (krow > MROWS - 1) krow = MROWS - 1;
            const unsigned short* kb  = qkhi + (size_t)krow * 1024 + 512 + h * DH + skd;
            const unsigned short* kbl = qklo + (size_t)krow * 1024 + 512 + h * DH + skd;
            *(short8v*)&KH(skr, skd)     = *(const short8v*)kb;
            *(short8v*)&KH(skr, skd + 8) = *(const short8v*)(kb + 8);
            *(short8v*)&KL(skr, skd)     = *(const short8v*)kbl;
            *(short8v*)&KL(skr, skd + 8) = *(const short8v*)(kbl + 8);
            // V staging: read interleaved uints, deinterleave to VH/VL
            const unsigned* vb = vtx + ((size_t)((b * HH + h) * DH + svd)) * VTSTRIDE + kt * AKT + svk;
            uint4 a0 = *(const uint4*)(vb);
            uint4 a1 = *(const uint4*)(vb + 4);
            uint4 a2 = *(const uint4*)(vb + 8);
            uint4 a3 = *(const uint4*)(vb + 12);
            uint4 hA, hB, lA, lB;
            hA.x = (a0.x & 0xffffu) | (a0.y << 16);
            hA.y = (a0.z & 0xffffu) | (a0.w << 16);
            hA.z = (a1.x & 0xffffu) | (a1.y << 16);
            hA.w = (a1.z & 0xffffu) | (a1.w << 16);
            hB.x = (a2.x & 0xffffu) | (a2.y << 16);
            hB.y = (a2.z & 0xffffu) | (a2.w << 16);
            hB.z = (a3.x & 0xffffu) | (a3.y << 16);
            hB.w = (a3.z & 0xffffu) | (a3.w << 16);
            lA.x = (a0.x >> 16) | (a0.y & 0xffff0000u);
            lA.y = (a0.z >> 16) | (a0.w & 0xffff0000u);
            lA.z = (a1.x >> 16) | (a1.y & 0xffff0000u);
            lA.w = (a1.z >> 16) | (a1.w & 0xffff0000u);
            lB.x = (a2.x >> 16) | (a2.y & 0xffff0000u);
            lB.y = (a2.z >> 16) | (a2.w & 0xffff0000u);
            lB.z = (a3.x >> 16) | (a3.y & 0xffff0000u);
            lB.w = (a3.z >> 16) | (a3.w & 0xffff0000u);
            *(uint4*)&VH(svd, svk)     = hA;
            *(uint4*)&VH(svd, svk + 8) = hB;
            *(uint4*)&VL(svd, svk)     = lA;
            *(uint4*)&VL(svd, svk + 8) = lB;
        }
        __syncthreads();

        f32x4 s[2];
        s[0][0]=s[0][1]=s[0][2]=s[0][3]=0.f;
        s[1][0]=s[1][1]=s[1][2]=s[1][3]=0.f;
        #pragma unroll
        for (int n = 0; n < 2; n++) {
            #pragma unroll
            for (int ks = 0; ks < 4; ks++) {
                short8v kh = *(const short8v*)&KH(n * 16 + c, ks * 32 + g * 8);
                short8v kl = *(const short8v*)&KL(n * 16 + c, ks * 32 + g * 8);
                s[n] = MFMA16(qh[ks], kh, s[n]);
                s[n] = MFMA16(ql[ks], kh, s[n]);
                s[n] = MFMA16(qh[ks], kl, s[n]);
            }
        }

        #pragma unroll
        for (int n = 0; n < 2; n++) {
            bool oob = (kt * 32 + n * 16 + c) >= LC;
            #pragma unroll
            for (int r = 0; r < 4; r++) {
                float sv = s[n][r] * SCALE;
                s[n][r] = oob ? -INFINITY : sv;
            }
        }

        float alpha[4], p0v[4], p1v[4];
        #pragma unroll
        for (int r = 0; r < 4; r++) {
            float rm = fmaxf(s[0][r], s[1][r]);
            #pragma unroll
            for (int off = 1; off < 16; off <<= 1) rm = fmaxf(rm, __shfl_xor(rm, off));
            float mn = fmaxf(m_r[r], rm);
            float p0 = expf(s[0][r] - mn);
            float p1 = expf(s[1][r] - mn);
            float ts = p0 + p1;
            #pragma unroll
            for (int off = 1; off < 16; off <<= 1) ts += __shfl_xor(ts, off);
            float al = expf(m_r[r] - mn);
            m_r[r] = mn;
            l_r[r] = al * l_r[r] + ts;
            alpha[r] = al;
            p0v[r] = p0; p1v[r] = p1;
        }

        #pragma unroll
        for (int n = 0; n < 8; n++)
            #pragma unroll
            for (int r = 0; r < 4; r++) acc_o[n][r] *= alpha[r];

        #pragma unroll
        for (int r = 0; r < 4; r++) {
            unsigned short ph, pl;
            split_bf(p0v[r], ph, pl);
            PH(w * 16 + g * 4 + r, c) = ph;
            PL(w * 16 + g * 4 + r, c) = pl;
            split_bf(p1v[r], ph, pl);
            PH(w * 16 + g * 4 + r, 16 + c) = ph;
            PL(w * 16 + g * 4 + r, 16 + c) = pl;
        }
        __syncthreads();

        short8v pah = *(const short8v*)&PH(w * 16 + c, g * 8);
        short8v pal = *(const short8v*)&PL(w * 16 + c, g * 8);
        #pragma unroll
        for (int n = 0; n < 8; n++) {
            short8v vh = *(const short8v*)&VH(n * 16 + c, g * 8);
            short8v vl = *(const short8v*)&VL(n * 16 + c, g * 8);
            acc_o[n] = MFMA16(pah, vh, acc_o[n]);
            acc_o[n] = MFMA16(pal, vh, acc_o[n]);
            acc_o[n] = MFMA16(pah, vl, acc_o[n]);
        }
    }

    float inv[4];
    #pragma unroll
    for (int r = 0; r < 4; r++) inv[r] = 1.0f / l_r[r];

    const int orow = t >> 2, oc0 = (t & 3) * 32;
    #pragma unroll
    for (int pass = 0; pass < 2; pass++) {
        __syncthreads();
        #pragma unroll
        for (int n = 0; n < 8; n++)
            #pragma unroll
            for (int r = 0; r < 4; r++) {
                float v = acc_o[n][r] * inv[r];
                unsigned short hv, lv;
                split_bf(v, hv, lv);
                OS(w * 16 + g * 4 + r, n * 16 + c) = pass ? lv : hv;
            }
        __syncthreads();
        int grow = q0 + orow;
        if (grow < LC) {
            unsigned short* dst = (pass ? olo : ohi) + ((size_t)(b * LC + grow)) * DD + h * DH + oc0;
            #pragma unroll
            for (int u = 0; u < 4; u++)
                *(short8v*)(dst + u * 8) = *(const short8v*)&OS(orow, oc0 + u * 8);
        }
    }
    #undef KH
    #undef KL
    #undef VH
    #undef VL
    #undef PH
    #undef PL
    #undef OS
}

// ---------------- LayerNorm over 512, writes fp32 + splits ----------------
__global__ __launch_bounds__(128)
void ln512(const float* __restrict__ X, const float* __restrict__ g,
           const float* __restrict__ bb, float* __restrict__ Y,
           unsigned short* __restrict__ Yhi, unsigned short* __restrict__ Ylo)
{
    __shared__ float red[2];
    int row = blockIdx.x, t = threadIdx.x;
    const float* x = X + (size_t)row * DD;
    float4 v = *(const float4*)(x + t * 4);
    float s = v.x + v.y + v.z + v.w;
    #pragma unroll
    for (int off = 1; off < 64; off <<= 1) s += __shfl_xor(s, off);
    if ((t & 63) == 0) red[t >> 6] = s;
    __syncthreads();
    float mean = (red[0] + red[1]) * (1.0f / 512.0f);
    __syncthreads();
    float d0 = v.x - mean, d1 = v.y - mean, d2 = v.z - mean, d3 = v.w - mean;
    float s2 = d0 * d0 + d1 * d1 + d2 * d2 + d3 * d3;
    #pragma unroll
    for (int off = 1; off < 64; off <<= 1) s2 += __shfl_xor(s2, off);
    if ((t & 63) == 0) red[t >> 6] = s2;
    __syncthreads();
    float var = (red[0] + red[1]) * (1.0f / 512.0f);
    float rstd = 1.0f / sqrtf(var + 1e-5f);
    float4 gv = *(const float4*)(g + t * 4);
    float4 bv = *(const float4*)(bb + t * 4);
    float4 ov;
    ov.x = d0 * rstd * gv.x + bv.x;
    ov.y = d1 * rstd * gv.y + bv.y;
    ov.z = d2 * rstd * gv.z + bv.z;
    ov.w = d3 * rstd * gv.w + bv.w;
    size_t o = (size_t)row * DD + t * 4;
    *(float4*)(Y + o) = ov;
    unsigned short hs[4], ls[4];
    split_bf(ov.x, hs[0], ls[0]); split_bf(ov.y, hs[1], ls[1]);
    split_bf(ov.z, hs[2], ls[2]); split_bf(ov.w, hs[3], ls[3]);
    ((uint2*)Yhi)[o >> 2] = make_uint2((unsigned)hs[0] | ((unsigned)hs[1]<<16),
                                       (unsigned)hs[2] | ((unsigned)hs[3]<<16));
    ((uint2*)Ylo)[o >> 2] = make_uint2((unsigned)ls[0] | ((unsigned)ls[1]<<16),
                                       (unsigned)ls[2] | ((unsigned)ls[3]<<16));
}

// ---------------- mean over L (two-pass) ----------------
__global__ __launch_bounds__(128)
void mean_part(const float* __restrict__ query, float* __restrict__ part)
{
    int b = blockIdx.x, ch = blockIdx.y, t = threadIdx.x;
    const float* base = query + ((size_t)b * LQ + ch * 64) * DD + t * 4;
    float ax = 0.f, ay = 0.f, az = 0.f, aw = 0.f;
    for (int l = 0; l < 64; l++) {
        float4 v = *(const float4*)(base + (size_t)l * DD);
        ax += v.x; ay += v.y; az += v.z; aw += v.w;
    }
    *(float4*)(part + ((size_t)(b * 8 + ch)) * DD + t * 4) = make_float4(ax, ay, az, aw);
}

__global__ __launch_bounds__(128)
void mean_fin(const float* __restrict__ part, float* __restrict__ xm)
{
    int b = blockIdx.x, t = threadIdx.x;
    float ax = 0.f, ay = 0.f, az = 0.f, aw = 0.f;
    #pragma unroll
    for (int ch = 0; ch < 8; ch++) {
        float4 v = *(const float4*)(part + ((size_t)(b * 8 + ch)) * DD + t * 4);
        ax += v.x; ay += v.y; az += v.z; aw += v.w;
    }
    *(float4*)(xm + (size_t)b * DD + t * 4) =
        make_float4(ax * (1.f/512.f), ay * (1.f/512.f), az * (1.f/512.f), aw * (1.f/512.f));
}

static __device__ __forceinline__ float block128_sum(float x, float* red, int t) {
    #pragma unroll
    for (int off = 1; off < 64; off <<= 1) x += __shfl_xor(x, off);
    if ((t & 63) == 0) red[t >> 6] = x;
    __syncthreads();
    float r = red[0] + red[1];
    __syncthreads();
    return r;
}

// ---------------- proj + LN -> q_repr ----------------
__global__ __launch_bounds__(128)
void proj_ln(const float* __restrict__ h, const float* __restrict__ pW, const float* __restrict__ pb,
             const float* __restrict__ pg, const float* __restrict__ pbb, float* __restrict__ q_repr)
{
    __shared__ float xs[DD];
    __shared__ float red[2];
    int b = blockIdx.x, t = threadIdx.x;
    *(float4*)&xs[t * 4] = *(const float4*)(h + (size_t)(b * LC) * DD + t * 4);
    __syncthreads();
    const float* w = pW + (size_t)t * DD;
    float acc = pb[t];
    for (int k = 0; k < DD; k += 4) {
        float4 a = *(const float4*)&xs[k];
        float4 ww = *(const float4*)(w + k);
        acc += a.x * ww.x + a.y * ww.y + a.z * ww.z + a.w * ww.w;
    }
    float mean = block128_sum(acc, red, t) * (1.f / 128.f);
    float dx = acc - mean;
    float var = block128_sum(dx * dx, red, t) * (1.f / 128.f);
    float rstd = 1.0f / sqrtf(var + 1e-5f);
    q_repr[(size_t)b * DRr + t] = dx * rstd * pg[t] + pbb[t];
}

// ---------------- value encoder (fused) -> q_val ----------------
__global__ __launch_bounds__(128)
void venc(const float* __restrict__ xm, const float* __restrict__ vW1, const float* __restrict__ vb1,
          const float* __restrict__ vg, const float* __restrict__ vb,
          const float* __restrict__ vW2, const float* __restrict__ vb2,
          float* __restrict__ q_val)
{
    __shared__ float xs[DD];
    __shared__ float hg[DRr];
    __shared__ float red[2];
    int b = blockIdx.x, t = threadIdx.x;
    *(float4*)&xs[t * 4] = *(const float4*)(xm + (size_t)b * DD + t * 4);
    __syncthreads();
    const float* w = vW1 + (size_t)t * DD;
    float acc = vb1[t];
    for (int k = 0; k < DD; k += 4) {
        float4 a = *(const float4*)&xs[k];
        float4 ww = *(const float4*)(w + k);
        acc += a.x * ww.x + a.y * ww.y + a.z * ww.z + a.w * ww.w;
    }
    float mean = block128_sum(acc, red, t) * (1.f / 128.f);
    float dx = acc - mean;
    float var = block128_sum(dx * dx, red, t) * (1.f / 128.f);
    float rstd = 1.0f / sqrtf(var + 1e-5f);
    float hn = dx * rstd * vg[t] + vb[t];
    hg[t] = gelu_exact(hn);
    __syncthreads();
    const float* w2 = vW2 + (size_t)t * DRr;
    float acc2 = vb2[t];
    for (int k = 0; k < DRr; k += 4) {
        float4 a = *(const float4*)&hg[k];
        float4 ww = *(const float4*)(w2 + k);
        acc2 += a.x * ww.x + a.y * ww.y + a.z * ww.z + a.w * ww.w;
    }
    q_val[(size_t)b * DRr + t] = acc2;
}

// ---------------- combine ----------------
__global__ void combine_qk(const float* __restrict__ qr, const float* __restrict__ qv,
                           const float* __restrict__ swp, float* __restrict__ qk)
{
    int i = blockIdx.x * blockDim.x + threadIdx.x;
    if (i < B_ * DRr) {
        float sw = swp[0];
        qk[i] = sw * qr[i] + (1.f - sw) * qv[i];
    }
}

// ---------------- sim ----------------
#define SIMCH 10
__global__ __launch_bounds__(256)
void sim_kernel(const float* __restrict__ qk, const float* __restrict__ mkeys, float* __restrict__ sim)
{
    __shared__ float qs[DRr];
    int b = blockIdx.x, ch = blockIdx.y, t = threadIdx.x;
    if (t < DRr) qs[t] = qk[(size_t)b * DRr + t];
    __syncthreads();
    float qn = 0.f;
    #pragma unroll 8
    for (int i = 0; i < DRr; i++) qn += qs[i] * qs[i];
    int n0 = ch * (NKEYS / SIMCH), n1 = n0 + (NKEYS / SIMCH);
    for (int n = n0 + t; n < n1; n += 256) {
        const float* kr = mkeys + (size_t)n * DRr;
        float dot = 0.f, kn = 0.f;
        #pragma unroll 8
        for (int i = 0; i < DRr; i += 4) {
            float4 kv = *(const float4*)(kr + i);
            dot += qs[i] * kv.x + qs[i + 1] * kv.y + qs[i + 2] * kv.z + qs[i + 3] * kv.w;
            kn  += kv.x * kv.x + kv.y * kv.y + kv.z * kv.z + kv.w * kv.w;
        }
        float d = qn - 2.f * dot + kn;
        sim[(size_t)b * NKEYS + n] = -d / 0.1f;
    }
}

// ---------------- top-k (jax semantics: value desc, ties -> lower index) ----
static __device__ __forceinline__ void topk_insert(float* v, int* id, float x, int n) {
    bool better = (x > v[TOPK - 1]) || (x == v[TOPK - 1] && n < id[TOPK - 1]);
    if (better) {
        v[TOPK - 1] = x; id[TOPK - 1] = n;
        #pragma unroll
        for (int k = TOPK - 1; k > 0; k--) {
            bool sw = (v[k] > v[k - 1]) || (v[k] == v[k - 1] && id[k] < id[k - 1]);
            if (!sw) break;
            float tv = v[k]; v[k] = v[k - 1]; v[k - 1] = tv;
            int ti = id[k]; id[k] = id[k - 1]; id[k - 1] = ti;
        }
    }
}

__global__ __launch_bounds__(256)
void topk_kernel(const float* __restrict__ sim, int* __restrict__ topidx, float* __restrict__ wout)
{
    __shared__ float sv[256][TOPK];
    __shared__ int   si[256][TOPK];
    int b = blockIdx.x, t = threadIdx.x;
    float v[TOPK]; int id[TOPK];
    #pragma unroll
    for (int k = 0; k < TOPK; k++) { v[k] = -INFINITY; id[k] = 0x7fffffff; }
    for (int n = t; n < NKEYS; n += 256) {
        topk_insert(v, id, sim[(size_t)b * NKEYS + n], n);
    }
    #pragma unroll
    for (int k = 0; k < TOPK; k++) { sv[t][k] = v[k]; si[t][k] = id[k]; }
    for (int strd = 128; strd >= 1; strd >>= 1) {
        __syncthreads();
        if (t < strd) {
            #pragma unroll
            for (int k = 0; k < TOPK; k++) topk_insert(v, id, sv[t + strd][k], si[t + strd][k]);
            #pragma unroll
            for (int k = 0; k < TOPK; k++) { sv[t][k] = v[k]; si[t][k] = id[k]; }
        }
    }
    if (t == 0) {
        float m = v[0];
        float e[TOPK]; float sum = 0.f;
        #pragma unroll
        for (int k = 0; k < TOPK; k++) { e[k] = expf(v[k] - m); sum += e[k]; }
        #pragma unroll
        for (int k = 0; k < TOPK; k++) {
            wout[(size_t)b * TOPK + k] = e[k] / sum;
            topidx[b * TOPK + k] = id[k];
        }
    }
}

// ---------------- gather ----------------
__global__ __launch_bounds__(128)
void gather_kernel(const float* __restrict__ mv, const int* __restrict__ topidx, float* __restrict__ out)
{
    int blk = blockIdx.x;
    int b = blk / (TOPK * PP);
    int rem = blk - b * (TOPK * PP);
    int k = rem / PP;
    int p = rem - k * PP;
    int idx = topidx[b * TOPK + k];
    const float4* src = (const float4*)(mv + ((size_t)idx * PP + p) * DD);
    float4* dst = (float4*)(out + (size_t)blk * DD);
    dst[threadIdx.x] = src[threadIdx.x];
}

// ---------------- launch ----------------
extern "C" void kernel_launch(void* const* d_in, const int* in_sizes, int n_in,
                              void* d_out, int out_size, void* d_ws, size_t ws_size,
                              hipStream_t stream) {
    const float* query = (const float*)d_in[0];
    const float* mkeys = (const float*)d_in[1];
    const float* mvals = (const float*)d_in[2];
    const float* cls   = (const float*)d_in[3];
    const float* Wqkv  = (const float*)d_in[4];
    const float* bqkv  = (const float*)d_in[5];
    const float* Wo    = (const float*)d_in[6];
    const float* bo    = (const float*)d_in[7];
    const float* ln1g  = (const float*)d_in[8];
    const float* ln1b  = (const float*)d_in[9];
    const float* W1    = (const float*)d_in[10];
    const float* b1    = (const float*)d_in[11];
    const float* W2    = (const float*)d_in[12];
    const float* b2    = (const float*)d_in[13];
    const float* ln2g  = (const float*)d_in[14];
    const float* ln2b  = (const float*)d_in[15];
    const float* pW    = (const float*)d_in[16];
    const float* pb    = (const float*)d_in[17];
    const float* pg    = (const float*)d_in[18];
    const float* pbb   = (const float*)d_in[19];
    const float* vW1   = (const float*)d_in[20];
    const float* vb1   = (const float*)d_in[21];
    const float* vg    = (const float*)d_in[22];
    const float* vb    = (const float*)d_in[23];
    const float* vW2   = (const float*)d_in[24];
    const float* vb2   = (const float*)d_in[25];
    const float* swp   = (const float*)d_in[26];
    float* out = (float*)d_out;

    // ---- workspace layout ----
    float* ws    = (float*)d_ws;
    float* h     = ws;                                   // MROWS*512 fp32 residual
    float* preln = h + (size_t)MROWS * DD;               // MROWS*512 fp32
    unsigned short* h_hi  = (unsigned short*)(preln + (size_t)MROWS * DD);
    unsigned short* h_lo  = h_hi  + (size_t)MROWS * DD;
    unsigned short* mid_hi = h_lo + (size_t)MROWS * DD;  // MROWS*1024
    unsigned short* mid_lo = mid_hi + (size_t)MROWS * 1024;
    unsigned short* qkhi  = mid_lo + (size_t)MROWS * 1024;
    unsigned short* qklo  = qkhi  + (size_t)MROWS * 1024;
    unsigned* vtx         = (unsigned*)(qklo + (size_t)MROWS * 1024); // 32768*VTSTRIDE uints
    unsigned short* wq_hi = (unsigned short*)(vtx + (size_t)32768 * VTSTRIDE);
    unsigned short* wq_lo = wq_hi + (size_t)2 * 1536 * DD;
    unsigned short* wo_hi = wq_lo + (size_t)2 * 1536 * DD;
    unsigned short* wo_lo = wo_hi + (size_t)2 * DD * DD;
    unsigned short* w1_hi = wo_lo + (size_t)2 * DD * DD;
    unsigned short* w1_lo = w1_hi + (size_t)2 * 1024 * DD;
    unsigned short* w2_hi = w1_lo + (size_t)2 * 1024 * DD;
    unsigned short* w2_lo = w2_hi + (size_t)2 * DD * 1024;
    float* xm   = (float*)(w2_lo + (size_t)2 * DD * 1024);
    float* qval = xm   + (size_t)B_ * DD;
    float* qrep = qval + (size_t)B_ * DRr;
    float* qkc  = qrep + (size_t)B_ * DRr;
    float* simb = qkc  + (size_t)B_ * DRr;
    int*   tidx = (int*)(simb + (size_t)B_ * NKEYS);
    float* mpart = (float*)(tidx + 512);                 // 64*8*512 fp32
    (void)ws_size; (void)in_sizes; (void)n_in; (void)out_size;

    // ---- weight splits ----
    {
        int n4;
        n4 = 2 * 1536 * DD / 4;
        split_kernel<<<(n4 + 255) / 256, 256, 0, stream>>>(Wqkv, wq_hi, wq_lo, n4);
        n4 = 2 * DD * DD / 4;
        split_kernel<<<(n4 + 255) / 256, 256, 0, stream>>>(Wo, wo_hi, wo_lo, n4);
        n4 = 2 * 1024 * DD / 4;
        split_kernel<<<(n4 + 255) / 256, 256, 0, stream>>>(W1, w1_hi, w1_lo, n4);
        n4 = 2 * DD * 1024 / 4;
        split_kernel<<<(n4 + 255) / 256, 256, 0, stream>>>(W2, w2_hi, w2_lo, n4);
    }

    concat_cls<<<MROWS, 128, 0, stream>>>(query, cls, h, h_hi, h_lo);

    for (int l = 0; l < 2; l++) {
        const unsigned short* wqh = wq_hi + (size_t)l * 1536 * DD;
        const unsigned short* wql = wq_lo + (size_t)l * 1536 * DD;
        const unsigned short* woh = wo_hi + (size_t)l * DD * DD;
        const unsigned short* wol = wo_lo + (size_t)l * DD * DD;
        const unsigned short* w1h = w1_hi + (size_t)l * 1024 * DD;
        const unsigned short* w1l = w1_lo + (size_t)l * 1024 * DD;
        const unsigned short* w2h = w2_hi + (size_t)l * DD * 1024;
        const unsigned short* w2l = w2_lo + (size_t)l * DD * 1024;
        const float* bq  = bqkv + (size_t)l * 1536;
        const float* bol = bo   + (size_t)l * DD;
        const float* g1  = ln1g + (size_t)l * DD;
        const float* be1 = ln1b + (size_t)l * DD;
        const float* b1l = b1   + (size_t)l * 1024;
        const float* b2l = b2   + (size_t)l * DD;
        const float* g2  = ln2g + (size_t)l * DD;
        const float* be2 = ln2b + (size_t)l * DD;

        // QKV -> qk splits + transposed interleaved V
        gemm3<3><<<257 * 12, 256, 0, stream>>>(h_hi, h_lo, wqh, wql, bq, nullptr,
                                               nullptr, qkhi, qklo, vtx,
                                               MROWS, 1536, DD, 12);
        // MFMA attention -> h_hi/h_lo (attn-out splits)
        attn_mfma<<<9 * HH * B_, 256, 0, stream>>>(qkhi, qklo, vtx, h_hi, h_lo);
        // Wo + residual -> preln fp32
        gemm3<1><<<257 * 4, 256, 0, stream>>>(h_hi, h_lo, woh, wol, bol, h,
                                              preln, nullptr, nullptr, nullptr,
                                              MROWS, DD, DD, 4);
        ln512<<<MROWS, 128, 0, stream>>>(preln, g1, be1, h, h_hi, h_lo);
        // FFN1 + gelu -> mid splits
        gemm3<2><<<257 * 8, 256, 0, stream>>>(h_hi, h_lo, w1h, w1l, b1l, nullptr,
                                              nullptr, mid_hi, mid_lo, nullptr,
                                              MROWS, 1024, DD, 8);
        // FFN2 + residual -> preln fp32
        gemm3<1><<<257 * 4, 256, 0, stream>>>(mid_hi, mid_lo, w2h, w2l, b2l, h,
                                              preln, nullptr, nullptr, nullptr,
                                              MROWS, DD, 1024, 4);
        ln512<<<MROWS, 128, 0, stream>>>(preln, g2, be2, h, h_hi, h_lo);
    }

    proj_ln<<<B_, 128, 0, stream>>>(h, pW, pb, pg, pbb, qrep);
    mean_part<<<dim3(B_, 8), 128, 0, stream>>>(query, mpart);
    mean_fin<<<B_, 128, 0, stream>>>(mpart, xm);
    venc<<<B_, 128, 0, stream>>>(xm, vW1, vb1, vg, vb, vW2, vb2, qval);
    combine_qk<<<(B_ * DRr + 255) / 256, 256, 0, stream>>>(qrep, qval, swp, qkc);
    sim_kernel<<<dim3(B_, SIMCH), 256, 0, stream>>>(qkc, mkeys, simb);
    topk_kernel<<<B_, 256, 0, stream>>>(simb, tidx, out + (size_t)B_ * TOPK * PP * DD);
    gather_kernel<<<B_ * TOPK * PP, 128, 0, stream>>>(mvals, tidx, out);
}